// Round 5
// baseline (501.236 us; speedup 1.0000x reference)
//
#include <hip/hip_runtime.h>
#include <hip/hip_bf16.h>

typedef __hip_bfloat16 bf16;

static __device__ __forceinline__ float us2f(unsigned short u) {
    union { unsigned int i; float f; } c; c.i = ((unsigned int)u) << 16; return c.f;
}
static __device__ __forceinline__ unsigned short f2us(float f) {
    union { float f; unsigned int i; } c; c.f = f;
    unsigned int r = c.i + 0x7FFF + ((c.i >> 16) & 1);   // round-to-nearest-even
    return (unsigned short)(r >> 16);
}

// ---------------- dtype probe + canonicalization ----------------
// flags[0] = 1 if float tensors are stored as f32 (else bf16)
// flags[1] = 1 if edge_index is stored as int64 (else int32)

__global__ __launch_bounds__(256) void k_detect(const unsigned short* __restrict__ xr,
                                                const int* __restrict__ er,
                                                int* __restrict__ flags) {
    __shared__ int sbad, snz;
    int tid = threadIdx.x;
    if (tid == 0) { sbad = 0; snz = 0; }
    __syncthreads();
    int bad = 0, nz = 0;
    for (int i = tid; i < 1024; i += 256) {
        unsigned short w = xr[2 * i];          // f32 storage: low mantissa half (uniform); bf16: real value
        int ex = (w >> 7) & 0xFF;
        if (ex < 110 || ex > 135) bad++;
        if (er[2 * i + 1] != 0) nz++;          // int64 storage: high words of small values == 0
    }
    atomicAdd(&sbad, bad);
    atomicAdd(&snz, nz);
    __syncthreads();
    if (tid == 0) {
        flags[0] = (sbad > 256) ? 1 : 0;
        flags[1] = (snz < 512) ? 1 : 0;
    }
}

struct CvtArgs { const void* p[19]; int sz[19]; };

__global__ __launch_bounds__(256) void k_convert(CvtArgs a, const int* __restrict__ flags,
                                                 float* __restrict__ dst, int total) {
    int t = blockIdx.x * 256 + threadIdx.x;
    if (t >= total) return;
    int isf32 = flags[0];
    int base = 0, seg = -1, off = 0;
#pragma unroll
    for (int i = 0; i < 19; i++) {
        if (seg < 0 && t < base + a.sz[i]) { seg = i; off = t - base; }
        base += a.sz[i];
    }
    const void* p = a.p[seg];
    float v = isf32 ? ((const float*)p)[off] : __bfloat162float(((const bf16*)p)[off]);
    dst[t] = v;
}

static __device__ __forceinline__ int ld_edge(const int* er, size_t i, int idx64) {
    return idx64 ? er[2 * i] : er[i];
}

// ---------------- bucketed CSR build ----------------
// bucket b = dst >> 10 (1024 nodes per bucket), NB <= 256 assumed (N <= 262144)

// Pass A: global per-bucket edge counts
__global__ __launch_bounds__(1024) void k_bhist(const int* __restrict__ er, const int* __restrict__ flags,
                                                int* __restrict__ bcnt, int E, int NB) {
    __shared__ int cnt[256];
    int tid = threadIdx.x;
    if (tid < 256) cnt[tid] = 0;
    __syncthreads();
    int idx64 = flags[1];
    int base = blockIdx.x * 4096 + tid;
#pragma unroll
    for (int k = 0; k < 4; ++k) {
        int e = base + k * 1024;
        if (e < E) {
            int d = ld_edge(er, (size_t)E + e, idx64);
            atomicAdd(&cnt[d >> 10], 1);
        }
    }
    __syncthreads();
    if (tid < NB && cnt[tid]) atomicAdd(&bcnt[tid], cnt[tid]);
}

// Pass B: scan bucket counts -> bbase (exclusive), init bcur, csr_off[N]=E
__global__ __launch_bounds__(256) void k_bscan(const int* __restrict__ bcnt, int* __restrict__ bbase,
                                               int* __restrict__ bcur, int* __restrict__ csr_off,
                                               int NB, int N, int E) {
    __shared__ int sm[256];
    int tid = threadIdx.x;
    int v = (tid < NB) ? bcnt[tid] : 0;
    sm[tid] = v;
    __syncthreads();
    for (int d = 1; d < 256; d <<= 1) {
        int t = (tid >= d) ? sm[tid - d] : 0;
        __syncthreads();
        sm[tid] += t;
        __syncthreads();
    }
    int excl = sm[tid] - v;
    if (tid < NB) { bbase[tid] = excl; bcur[tid] = excl; }
    if (tid == 0) { bbase[NB] = E; csr_off[N] = E; }
}

// Pass C: scatter (src,dst) into bucket-contiguous regions with per-block reservations
__global__ __launch_bounds__(1024) void k_bscatter(const int* __restrict__ er, const int* __restrict__ flags,
                                                   int* __restrict__ bcur, int2* __restrict__ bkt,
                                                   int E, int NB) {
    __shared__ int cnt[256];
    __shared__ int res[256];
    int tid = threadIdx.x;
    if (tid < 256) cnt[tid] = 0;
    __syncthreads();
    int idx64 = flags[1];
    int base = blockIdx.x * 4096 + tid;
    int sv[4], dv[4], bv[4];
    bool val[4];
#pragma unroll
    for (int k = 0; k < 4; ++k) {
        int e = base + k * 1024;
        val[k] = (e < E);
        if (val[k]) {
            sv[k] = ld_edge(er, (size_t)e, idx64);
            dv[k] = ld_edge(er, (size_t)E + e, idx64);
            bv[k] = dv[k] >> 10;
            atomicAdd(&cnt[bv[k]], 1);
        }
    }
    __syncthreads();
    if (tid < NB) {
        int c = cnt[tid];
        res[tid] = c ? atomicAdd(&bcur[tid], c) : 0;
        cnt[tid] = 0;
    }
    __syncthreads();
#pragma unroll
    for (int k = 0; k < 4; ++k) {
        if (val[k]) {
            int r = atomicAdd(&cnt[bv[k]], 1);
            bkt[res[bv[k]] + r] = make_int2(sv[k], dv[k]);
        }
    }
}

// Pass D: per-bucket indeg count + scan -> csr_off; scatter src -> csr
__global__ __launch_bounds__(1024) void k_bbuild(const int2* __restrict__ bkt, const int* __restrict__ bbase,
                                                 int* __restrict__ csr_off, int* __restrict__ csr, int N) {
    __shared__ int sm[1024];
    int b = blockIdx.x, tid = threadIdx.x;
    int node0 = b << 10;
    int n0 = bbase[b], n1 = bbase[b + 1];
    int m = n1 - n0;
    sm[tid] = 0;
    __syncthreads();
    const int2* bp = bkt + n0;
    for (int i = tid; i < m; i += 1024) atomicAdd(&sm[bp[i].y - node0], 1);
    __syncthreads();
    int v = sm[tid];
    for (int d = 1; d < 1024; d <<= 1) {
        int t = (tid >= d) ? sm[tid - d] : 0;
        __syncthreads();
        sm[tid] += t;
        __syncthreads();
    }
    int excl = sm[tid] - v;
    int node = node0 + tid;
    if (node < N) csr_off[node] = n0 + excl;
    __syncthreads();
    sm[tid] = excl;
    __syncthreads();
    for (int i = tid; i < m; i += 1024) {
        int2 sd = bp[i];
        int r = atomicAdd(&sm[sd.y - node0], 1);
        csr[n0 + r] = sd.x;
    }
}

// ---------------- Layer 1: GATConv(3, 16, heads=4) ----------------

// one wave (64 lanes) per node; lane = head*16 + chan; packs x into x4 (L2-resident gather payload)
__global__ __launch_bounds__(256) void k_l1_transform(const float* __restrict__ x, const float* __restrict__ W1,
                                                      const float* __restrict__ att_s, const float* __restrict__ att_d,
                                                      float4* __restrict__ x4, float* __restrict__ as1,
                                                      float* __restrict__ ad1, int N) {
    int tid = threadIdx.x;
    int node = blockIdx.x * 4 + (tid >> 6);
    if (node >= N) return;
    int lane = tid & 63;
    float x0 = x[node * 3 + 0];
    float x1 = x[node * 3 + 1];
    float x2 = x[node * 3 + 2];
    float h = x0 * W1[lane] + x1 * W1[64 + lane] + x2 * W1[128 + lane];
    if (lane == 0) x4[node] = make_float4(x0, x1, x2, 0.f);
    float ts = h * att_s[lane];   // att_src1 is (4,16) flat == lane
    float td = h * att_d[lane];
    for (int m = 8; m >= 1; m >>= 1) { ts += __shfl_xor(ts, m); td += __shfl_xor(td, m); }
    if ((lane & 15) == 0) {
        as1[node * 4 + (lane >> 4)] = ts;
        ad1[node * 4 + (lane >> 4)] = td;
    }
}

// one wave per node. Phase 1: lane (e<<2)+h' computes weight for (edge e, head h') -> exp count /16.
// Phase 2: shfl-broadcast (s, w); h[s] reconstructed on the fly from L2-resident x4 (3 FMAs).
__global__ __launch_bounds__(256) void k_l1_agg(const float4* __restrict__ x4, const float* __restrict__ as1,
                                                const float* __restrict__ ad1, const int* __restrict__ off,
                                                const int* __restrict__ csr, const float* __restrict__ W1,
                                                const float* __restrict__ b1,
                                                float* __restrict__ x1, int N) {
    int tid = threadIdx.x;
    int node = blockIdx.x * 4 + (tid >> 6);
    if (node >= N) return;
    int lane = tid & 63;
    int h = lane >> 4;          // output head
    int hp = lane & 3;          // phase-1 head
    int eo = lane >> 2;         // phase-1 edge slot 0..15
    float w10 = W1[lane], w11 = W1[64 + lane], w12 = W1[128 + lane];
    float ad_p = ad1[node * 4 + hp];
    int e0 = off[node], e1 = off[node + 1];

    float den_part = 0.f;       // partial denominator for head hp over this lane's edge slots
    float acc = 0.f;            // numerator for (h, chan)

    for (int jj = e0; jj < e1; jj += 16) {
        int rem = e1 - jj; if (rem > 16) rem = 16;
        int s_r = 0; float w_r = 0.f;
        if (eo < rem) {
            s_r = csr[jj + eo];
            float z = as1[s_r * 4 + hp] + ad_p;
            z = (z > 0.f) ? z : 0.2f * z;
            w_r = __expf(z);
        }
        den_part += w_r;
        int rem4 = (rem + 3) & ~3;
        for (int k = 0; k < rem4; k += 4) {
            int s0 = __shfl(s_r, (k + 0) << 2);
            int s1 = __shfl(s_r, (k + 1) << 2);
            int s2 = __shfl(s_r, (k + 2) << 2);
            int s3 = __shfl(s_r, (k + 3) << 2);
            float w0 = __shfl(w_r, ((k + 0) << 2) + h);
            float w1 = __shfl(w_r, ((k + 1) << 2) + h);
            float w2 = __shfl(w_r, ((k + 2) << 2) + h);
            float w3 = __shfl(w_r, ((k + 3) << 2) + h);
            float4 v0 = x4[s0];
            float4 v1 = x4[s1];
            float4 v2 = x4[s2];
            float4 v3 = x4[s3];
            acc += w0 * (v0.x * w10 + v0.y * w11 + v0.z * w12);
            acc += w1 * (v1.x * w10 + v1.y * w11 + v1.z * w12);
            acc += w2 * (v2.x * w10 + v2.y * w11 + v2.z * w12);
            acc += w3 * (v3.x * w10 + v3.y * w11 + v3.z * w12);
        }
    }
    // full denominator for head hp lands in every lane; pick head h from lane h (lane h has hp==h)
    den_part += __shfl_xor(den_part, 4);
    den_part += __shfl_xor(den_part, 8);
    den_part += __shfl_xor(den_part, 16);
    den_part += __shfl_xor(den_part, 32);
    float den = __shfl(den_part, h);
    // self-loop (s = node)
    {
        float z = as1[node * 4 + h] + ad1[node * 4 + h];
        z = (z > 0.f) ? z : 0.2f * z;
        float w = __expf(z);
        float4 v = x4[node];
        acc += w * (v.x * w10 + v.y * w11 + v.z * w12);
        den += w;
    }
    float o = acc / (den + 1e-16f) + b1[lane];
    x1[(size_t)node * 64 + lane] = (o > 0.f) ? o : 0.f;   // relu
}

// ---------------- Layer 2: GATv2Conv(64, 16, heads=2) ----------------

// one wave per node; lanes 0..31 -> hl (bf16 out), 32..63 -> hr (f32 out)
__global__ __launch_bounds__(256) void k_l2_transform(const float* __restrict__ x1,
                                                      const float* __restrict__ W2l, const float* __restrict__ b2l,
                                                      const float* __restrict__ W2r, const float* __restrict__ b2r,
                                                      unsigned short* __restrict__ hlb, float* __restrict__ hr, int N) {
    __shared__ float xs[4][64];
    int tid = threadIdx.x;
    int r = tid >> 6, c64 = tid & 63;
    int node = blockIdx.x * 4 + r;
    xs[r][c64] = (node < N) ? x1[(size_t)node * 64 + c64] : 0.f;
    __syncthreads();
    if (node >= N) return;
    int half = (tid >> 5) & 1;
    int j = tid & 31;
    const float* W = half ? W2r : W2l;
    float acc = half ? b2r[j] : b2l[j];
#pragma unroll
    for (int k = 0; k < 64; ++k) acc += xs[r][k] * W[k * 32 + j];
    if (half) hr[(size_t)node * 32 + j] = acc;
    else      hlb[(size_t)node * 32 + j] = f2us(acc);
}

// 32 lanes per node (2 nodes per wave); lane = head*16 + chan
__global__ __launch_bounds__(256) void k_l2_agg(const unsigned short* __restrict__ hlb, const float* __restrict__ hr,
                                                const float* __restrict__ att2, const float* __restrict__ b2,
                                                const int* __restrict__ off, const int* __restrict__ csr,
                                                float* __restrict__ x2, int N) {
    int tid = threadIdx.x;
    int node = blockIdx.x * 8 + (tid >> 5);
    if (node >= N) return;
    int sl = tid & 31;
    float hrd = hr[(size_t)node * 32 + sl];
    float a2 = att2[sl];          // att2 is (2,16) flat == sl
    int e0 = off[node], e1 = off[node + 1];
    // self-loop
    float hsf = us2f(hlb[(size_t)node * 32 + sl]);
    float e = hsf + hrd;
    e = (e > 0.f) ? e : 0.2f * e;
    float t = e * a2;
    t += __shfl_xor(t, 1); t += __shfl_xor(t, 2);
    t += __shfl_xor(t, 4); t += __shfl_xor(t, 8);
    float w = __expf(t);
    float den0 = w, den1 = 0.f;
    float acc0 = w * hsf, acc1 = 0.f;
    int jj = e0;
    for (; jj + 2 <= e1; jj += 2) {
        int s0 = csr[jj], s1 = csr[jj + 1];
        float h0 = us2f(hlb[(size_t)s0 * 32 + sl]);
        float h1v = us2f(hlb[(size_t)s1 * 32 + sl]);
        float e0v = h0 + hrd, e1v = h1v + hrd;
        e0v = (e0v > 0.f) ? e0v : 0.2f * e0v;
        e1v = (e1v > 0.f) ? e1v : 0.2f * e1v;
        float t0 = e0v * a2, t1 = e1v * a2;
        t0 += __shfl_xor(t0, 1); t1 += __shfl_xor(t1, 1);
        t0 += __shfl_xor(t0, 2); t1 += __shfl_xor(t1, 2);
        t0 += __shfl_xor(t0, 4); t1 += __shfl_xor(t1, 4);
        t0 += __shfl_xor(t0, 8); t1 += __shfl_xor(t1, 8);
        float w0 = __expf(t0), w1 = __expf(t1);
        den0 += w0; acc0 += w0 * h0;
        den1 += w1; acc1 += w1 * h1v;
    }
    if (jj < e1) {
        int s0 = csr[jj];
        float h0 = us2f(hlb[(size_t)s0 * 32 + sl]);
        float e0v = h0 + hrd;
        e0v = (e0v > 0.f) ? e0v : 0.2f * e0v;
        float t0 = e0v * a2;
        t0 += __shfl_xor(t0, 1); t0 += __shfl_xor(t0, 2);
        t0 += __shfl_xor(t0, 4); t0 += __shfl_xor(t0, 8);
        float w0 = __expf(t0);
        den0 += w0; acc0 += w0 * h0;
    }
    x2[(size_t)node * 32 + sl] = (acc0 + acc1) / (den0 + den1 + 1e-16f) + b2[sl];
}

// ---------------- Layer 3: TransformerConv(32, 7, heads=1) ----------------

// 32 lanes per node; j<28 active: m = j/7 selects q/k/v/skip, c = j%7
__global__ __launch_bounds__(256) void k_l3_transform(const float* __restrict__ x2,
                                                      const float* __restrict__ Wq, const float* __restrict__ bq,
                                                      const float* __restrict__ Wk, const float* __restrict__ bk,
                                                      const float* __restrict__ Wv, const float* __restrict__ bv,
                                                      const float* __restrict__ Wsk, const float* __restrict__ bsk,
                                                      float* __restrict__ Q, float* __restrict__ K,
                                                      float* __restrict__ V, float* __restrict__ SK, int N) {
    __shared__ float xs[8][32];
    int tid = threadIdx.x;
    int r = tid >> 5, cc = tid & 31;
    int node = blockIdx.x * 8 + r;
    xs[r][cc] = (node < N) ? x2[(size_t)node * 32 + cc] : 0.f;
    __syncthreads();
    if (node >= N) return;
    int j = tid & 31;
    if (j >= 28) return;
    int m = j / 7, c = j - m * 7;
    const float* W = (m == 0) ? Wq : (m == 1) ? Wk : (m == 2) ? Wv : Wsk;
    const float* B = (m == 0) ? bq : (m == 1) ? bk : (m == 2) ? bv : bsk;
    float acc = B[c];
#pragma unroll
    for (int k = 0; k < 32; ++k) acc += xs[r][k] * W[k * 7 + c];
    float* outp = (m == 0) ? Q : (m == 1) ? K : (m == 2) ? V : SK;
    outp[(size_t)node * 7 + c] = acc;
}

// 8 lanes per node (8 nodes per wave); no self-loops in layer 3
__global__ __launch_bounds__(256) void k_l3_agg(const float* __restrict__ Q, const float* __restrict__ K,
                                                const float* __restrict__ V, const float* __restrict__ SK,
                                                const int* __restrict__ off, const int* __restrict__ csr,
                                                float* __restrict__ out, int N) {
    int tid = threadIdx.x;
    int node = blockIdx.x * 32 + (tid >> 3);
    if (node >= N) return;
    int sl = tid & 7;
    bool act = sl < 7;
    float qd = act ? Q[(size_t)node * 7 + sl] : 0.f;
    float acc = 0.f, den = 0.f;
    int e0 = off[node], e1 = off[node + 1];
    const float scale = 0.3779644730092272f;  // 1/sqrt(7)
    for (int jj = e0; jj < e1; ++jj) {
        int s = csr[jj];
        float t = act ? qd * K[(size_t)s * 7 + sl] : 0.f;
        t += __shfl_xor(t, 1); t += __shfl_xor(t, 2); t += __shfl_xor(t, 4);
        float w = __expf(t * scale);
        den += w;
        if (act) acc += w * V[(size_t)s * 7 + sl];
    }
    if (act) out[(size_t)node * 7 + sl] = acc / (den + 1e-16f) + SK[(size_t)node * 7 + sl];
}

// ---------------- launcher ----------------

extern "C" void kernel_launch(void* const* d_in, const int* in_sizes, int n_in,
                              void* d_out, int out_size, void* d_ws, size_t ws_size,
                              hipStream_t stream) {
    const int* ei = (const int*)d_in[1];
    float* out = (float*)d_out;

    int N = in_sizes[0] / 3;
    int E = in_sizes[1] / 2;
    int NB = (N + 1023) >> 10;   // assumed <= 256 (N <= 262144)

    char* ws = (char*)d_ws;
    size_t o = 0;
    auto take = [&](size_t bytes) -> char* {
        char* p = ws + o;
        o = (o + bytes + 255) & ~(size_t)255;
        return p;
    };
    int*   flags   = (int*)take(64);
    int total_f = 0;
    for (int i = 0; i < 20; ++i) if (i != 1) total_f += in_sizes[i];
    float* canon   = (float*)take((size_t)total_f * 4);
    int*   csr_off = (int*)take((size_t)(N + 1) * 4);
    int*   bcnt    = (int*)take(256 * 4);
    int*   bbase   = (int*)take(257 * 4);
    int*   bcur    = (int*)take(256 * 4);
    int*   csr     = (int*)take((size_t)E * 4);
    float* bufA    = (float*)take((size_t)N * 64 * 4);  // x4 -> hlb|hr -> q|k|v|skip
    float* as1     = (float*)take((size_t)N * 4 * 4);
    float* ad1     = (float*)take((size_t)N * 4 * 4);
    float* bufB    = (float*)take((size_t)N * 64 * 4);  // bkt -> x1 -> x2
    (void)ws_size; (void)n_in; (void)out_size;

    CvtArgs ca;
    const float* cp[20];
    {
        int off_ = 0, k = 0;
        for (int i = 0; i < 20; ++i) {
            if (i == 1) { cp[i] = nullptr; continue; }
            ca.p[k] = d_in[i];
            ca.sz[k] = in_sizes[i];
            cp[i] = canon + off_;
            off_ += in_sizes[i];
            ++k;
        }
    }

    hipMemsetAsync(bcnt, 0, 256 * 4, stream);
    k_detect<<<1, 256, 0, stream>>>((const unsigned short*)d_in[0], ei, flags);
    k_convert<<<(total_f + 255) / 256, 256, 0, stream>>>(ca, flags, canon, total_f);

    // bkt aliases bufB (E*8 bytes <= N*256 bytes for E <= 32N); x1 written only after k_bbuild
    int2* bkt = (int2*)bufB;
    int gb = (E + 4095) / 4096;
    k_bhist<<<gb, 1024, 0, stream>>>(ei, flags, bcnt, E, NB);
    k_bscan<<<1, 256, 0, stream>>>(bcnt, bbase, bcur, csr_off, NB, N, E);
    k_bscatter<<<gb, 1024, 0, stream>>>(ei, flags, bcur, bkt, E, NB);
    k_bbuild<<<NB, 1024, 0, stream>>>(bkt, bbase, csr_off, csr, N);

    float4* x4 = (float4*)bufA;                                  // N*16B = 1.6 MB, L2-resident
    k_l1_transform<<<(N + 3) / 4, 256, 0, stream>>>(cp[0], cp[2], cp[3], cp[4], x4, as1, ad1, N);
    float* x1 = bufB;
    k_l1_agg<<<(N + 3) / 4, 256, 0, stream>>>(x4, as1, ad1, csr_off, csr, cp[2], cp[5], x1, N);

    unsigned short* hlb = (unsigned short*)bufA;                 // N*32 bf16 = 6.4 MB
    float* hr = bufA + (size_t)N * 16;                           // after hlb (N*32*2B = N*16 floats)
    k_l2_transform<<<(N + 3) / 4, 256, 0, stream>>>(x1, cp[6], cp[7], cp[8], cp[9], hlb, hr, N);
    float* x2 = bufB;
    k_l2_agg<<<(N + 7) / 8, 256, 0, stream>>>(hlb, hr, cp[10], cp[11], csr_off, csr, x2, N);

    float* Q  = bufA;
    float* K  = bufA + (size_t)N * 7;
    float* V  = bufA + (size_t)N * 14;
    float* SK = bufA + (size_t)N * 21;
    k_l3_transform<<<(N + 7) / 8, 256, 0, stream>>>(x2, cp[12], cp[13], cp[14], cp[15], cp[16], cp[17],
                                                    cp[18], cp[19], Q, K, V, SK, N);
    k_l3_agg<<<(N + 31) / 32, 256, 0, stream>>>(Q, K, V, SK, csr_off, csr, out, N);
}

// Round 6
// 442.200 us; speedup vs baseline: 1.1335x; 1.1335x over previous
//
#include <hip/hip_runtime.h>
#include <hip/hip_bf16.h>

typedef __hip_bfloat16 bf16;

static __device__ __forceinline__ float us2f(unsigned short u) {
    union { unsigned int i; float f; } c; c.i = ((unsigned int)u) << 16; return c.f;
}
static __device__ __forceinline__ unsigned short f2us(float f) {
    union { float f; unsigned int i; } c; c.f = f;
    unsigned int r = c.i + 0x7FFF + ((c.i >> 16) & 1);   // round-to-nearest-even
    return (unsigned short)(r >> 16);
}

// ---------------- dtype probe + canonicalization ----------------

__global__ __launch_bounds__(256) void k_detect(const unsigned short* __restrict__ xr,
                                                const int* __restrict__ er,
                                                int* __restrict__ flags) {
    __shared__ int sbad, snz;
    int tid = threadIdx.x;
    if (tid == 0) { sbad = 0; snz = 0; }
    __syncthreads();
    int bad = 0, nz = 0;
    for (int i = tid; i < 1024; i += 256) {
        unsigned short w = xr[2 * i];
        int ex = (w >> 7) & 0xFF;
        if (ex < 110 || ex > 135) bad++;
        if (er[2 * i + 1] != 0) nz++;
    }
    atomicAdd(&sbad, bad);
    atomicAdd(&snz, nz);
    __syncthreads();
    if (tid == 0) {
        flags[0] = (sbad > 256) ? 1 : 0;
        flags[1] = (snz < 512) ? 1 : 0;
    }
}

struct CvtArgs { const void* p[19]; int sz[19]; };

__global__ __launch_bounds__(256) void k_convert(CvtArgs a, const int* __restrict__ flags,
                                                 float* __restrict__ dst, int total) {
    int t = blockIdx.x * 256 + threadIdx.x;
    if (t >= total) return;
    int isf32 = flags[0];
    int base = 0, seg = -1, off = 0;
#pragma unroll
    for (int i = 0; i < 19; i++) {
        if (seg < 0 && t < base + a.sz[i]) { seg = i; off = t - base; }
        base += a.sz[i];
    }
    const void* p = a.p[seg];
    float v = isf32 ? ((const float*)p)[off] : __bfloat162float(((const bf16*)p)[off]);
    dst[t] = v;
}

static __device__ __forceinline__ int ld_edge(const int* er, size_t i, int idx64) {
    return idx64 ? er[2 * i] : er[i];
}

// ---------------- bucketed CSR build ----------------
// bucket b = dst >> 10 (1024 nodes per bucket), NB <= 256 assumed (N <= 262144)

__global__ __launch_bounds__(1024) void k_bhist(const int* __restrict__ er, const int* __restrict__ flags,
                                                int* __restrict__ bcnt, int E, int NB) {
    __shared__ int cnt[256];
    int tid = threadIdx.x;
    if (tid < 256) cnt[tid] = 0;
    __syncthreads();
    int idx64 = flags[1];
    int base = blockIdx.x * 4096 + tid;
#pragma unroll
    for (int k = 0; k < 4; ++k) {
        int e = base + k * 1024;
        if (e < E) {
            int d = ld_edge(er, (size_t)E + e, idx64);
            atomicAdd(&cnt[d >> 10], 1);
        }
    }
    __syncthreads();
    if (tid < NB && cnt[tid]) atomicAdd(&bcnt[tid], cnt[tid]);
}

__global__ __launch_bounds__(256) void k_bscan(const int* __restrict__ bcnt, int* __restrict__ bbase,
                                               int* __restrict__ bcur, int* __restrict__ csr_off,
                                               int NB, int N, int E) {
    __shared__ int sm[256];
    int tid = threadIdx.x;
    int v = (tid < NB) ? bcnt[tid] : 0;
    sm[tid] = v;
    __syncthreads();
    for (int d = 1; d < 256; d <<= 1) {
        int t = (tid >= d) ? sm[tid - d] : 0;
        __syncthreads();
        sm[tid] += t;
        __syncthreads();
    }
    int excl = sm[tid] - v;
    if (tid < NB) { bbase[tid] = excl; bcur[tid] = excl; }
    if (tid == 0) { bbase[NB] = E; csr_off[N] = E; }
}

__global__ __launch_bounds__(1024) void k_bscatter(const int* __restrict__ er, const int* __restrict__ flags,
                                                   int* __restrict__ bcur, int2* __restrict__ bkt,
                                                   int E, int NB) {
    __shared__ int cnt[256];
    __shared__ int res[256];
    int tid = threadIdx.x;
    if (tid < 256) cnt[tid] = 0;
    __syncthreads();
    int idx64 = flags[1];
    int base = blockIdx.x * 4096 + tid;
    int sv[4], dv[4], bv[4];
    bool val[4];
#pragma unroll
    for (int k = 0; k < 4; ++k) {
        int e = base + k * 1024;
        val[k] = (e < E);
        if (val[k]) {
            sv[k] = ld_edge(er, (size_t)e, idx64);
            dv[k] = ld_edge(er, (size_t)E + e, idx64);
            bv[k] = dv[k] >> 10;
            atomicAdd(&cnt[bv[k]], 1);
        }
    }
    __syncthreads();
    if (tid < NB) {
        int c = cnt[tid];
        res[tid] = c ? atomicAdd(&bcur[tid], c) : 0;
        cnt[tid] = 0;
    }
    __syncthreads();
#pragma unroll
    for (int k = 0; k < 4; ++k) {
        if (val[k]) {
            int r = atomicAdd(&cnt[bv[k]], 1);
            bkt[res[bv[k]] + r] = make_int2(sv[k], dv[k]);
        }
    }
}

__global__ __launch_bounds__(1024) void k_bbuild(const int2* __restrict__ bkt, const int* __restrict__ bbase,
                                                 int* __restrict__ csr_off, int* __restrict__ csr, int N) {
    __shared__ int sm[1024];
    int b = blockIdx.x, tid = threadIdx.x;
    int node0 = b << 10;
    int n0 = bbase[b], n1 = bbase[b + 1];
    int m = n1 - n0;
    sm[tid] = 0;
    __syncthreads();
    const int2* bp = bkt + n0;
    for (int i = tid; i < m; i += 1024) atomicAdd(&sm[bp[i].y - node0], 1);
    __syncthreads();
    int v = sm[tid];
    for (int d = 1; d < 1024; d <<= 1) {
        int t = (tid >= d) ? sm[tid - d] : 0;
        __syncthreads();
        sm[tid] += t;
        __syncthreads();
    }
    int excl = sm[tid] - v;
    int node = node0 + tid;
    if (node < N) csr_off[node] = n0 + excl;
    __syncthreads();
    sm[tid] = excl;
    __syncthreads();
    for (int i = tid; i < m; i += 1024) {
        int2 sd = bp[i];
        int r = atomicAdd(&sm[sd.y - node0], 1);
        csr[n0 + r] = sd.x;
    }
}

// ---------------- Layer 1: GATConv(3, 16, heads=4) ----------------

// one wave (64 lanes) per node; lane = head*16 + chan; packs x into x4 (L2-resident gather payload)
__global__ __launch_bounds__(256) void k_l1_transform(const float* __restrict__ x, const float* __restrict__ W1,
                                                      const float* __restrict__ att_s, const float* __restrict__ att_d,
                                                      float4* __restrict__ x4, float* __restrict__ as1,
                                                      float* __restrict__ ad1, int N) {
    int tid = threadIdx.x;
    int node = blockIdx.x * 4 + (tid >> 6);
    if (node >= N) return;
    int lane = tid & 63;
    float x0 = x[node * 3 + 0];
    float x1 = x[node * 3 + 1];
    float x2 = x[node * 3 + 2];
    float h = x0 * W1[lane] + x1 * W1[64 + lane] + x2 * W1[128 + lane];
    if (lane == 0) x4[node] = make_float4(x0, x1, x2, 0.f);
    float ts = h * att_s[lane];
    float td = h * att_d[lane];
    for (int m = 8; m >= 1; m >>= 1) { ts += __shfl_xor(ts, m); td += __shfl_xor(td, m); }
    if ((lane & 15) == 0) {
        as1[node * 4 + (lane >> 4)] = ts;
        ad1[node * 4 + (lane >> 4)] = td;
    }
}

// Edge-parallel: 16 lanes per node (sl = edge slot). Aggregation is linear in x, so we
// accumulate per-head weighted 3-vector + denominator (16 values), reduce across 16 lanes
// with a value-splitting butterfly (15 shfl), then each lane emits 4 output channels.
__global__ __launch_bounds__(256) void k_l1_agg(const float4* __restrict__ x4, const float4* __restrict__ as4,
                                                const float4* __restrict__ ad4p, const int* __restrict__ off,
                                                const int* __restrict__ csr, const float* __restrict__ W1,
                                                const float* __restrict__ b1,
                                                float* __restrict__ x1, int N) {
    int tid = threadIdx.x;
    int node = blockIdx.x * 16 + (tid >> 4);
    if (node >= N) return;
    int sl = tid & 15;
    int lane = tid & 63;
    int lb = lane & 48;            // subgroup base within wave

    float4 ad = ad4p[node];
    int e0 = off[node], e1 = off[node + 1];

    // v[4h+c]: c=0..2 -> weighted x accumulation, c=3 -> denominator, head h
    float v[16];
#pragma unroll
    for (int i = 0; i < 16; ++i) v[i] = 0.f;

    for (int jj = e0 + sl; jj < e1; jj += 16) {
        int s = csr[jj];
        float4 a = as4[s];
        float4 xv = x4[s];
        float z0 = a.x + ad.x, z1 = a.y + ad.y, z2 = a.z + ad.z, z3 = a.w + ad.w;
        z0 = (z0 > 0.f) ? z0 : 0.2f * z0;
        z1 = (z1 > 0.f) ? z1 : 0.2f * z1;
        z2 = (z2 > 0.f) ? z2 : 0.2f * z2;
        z3 = (z3 > 0.f) ? z3 : 0.2f * z3;
        float w0 = __expf(z0), w1 = __expf(z1), w2 = __expf(z2), w3 = __expf(z3);
        v[0] += w0 * xv.x; v[1] += w0 * xv.y; v[2]  += w0 * xv.z; v[3]  += w0;
        v[4] += w1 * xv.x; v[5] += w1 * xv.y; v[6]  += w1 * xv.z; v[7]  += w1;
        v[8] += w2 * xv.x; v[9] += w2 * xv.y; v[10] += w2 * xv.z; v[11] += w2;
        v[12] += w3 * xv.x; v[13] += w3 * xv.y; v[14] += w3 * xv.z; v[15] += w3;
    }

    // value-splitting butterfly: after stages d=8,4,2,1, v[0] = value index sl, fully summed
#pragma unroll
    for (int d = 8; d >= 1; d >>= 1) {
#pragma unroll
        for (int i = 0; i < 16; ++i) {
            if (i < d) {
                float a = v[i], b = v[i + d];
                float send = (sl & d) ? a : b;
                float recv = __shfl_xor(send, d);
                v[i] = ((sl & d) ? b : a) + recv;
            }
        }
    }
    float r = v[0];   // reduced value index sl

    // broadcast all 16 reduced values to every lane of the subgroup
    float agx[4], agy[4], agz[4], dn[4];
#pragma unroll
    for (int h = 0; h < 4; ++h) {
        agx[h] = __shfl(r, lb + 4 * h + 0);
        agy[h] = __shfl(r, lb + 4 * h + 1);
        agz[h] = __shfl(r, lb + 4 * h + 2);
        dn[h]  = __shfl(r, lb + 4 * h + 3);
    }

    // self-loop (uniform across lanes)
    {
        float4 a = as4[node];
        float4 xv = x4[node];
        float z0 = a.x + ad.x, z1 = a.y + ad.y, z2 = a.z + ad.z, z3 = a.w + ad.w;
        z0 = (z0 > 0.f) ? z0 : 0.2f * z0;
        z1 = (z1 > 0.f) ? z1 : 0.2f * z1;
        z2 = (z2 > 0.f) ? z2 : 0.2f * z2;
        z3 = (z3 > 0.f) ? z3 : 0.2f * z3;
        float w0 = __expf(z0), w1 = __expf(z1), w2 = __expf(z2), w3 = __expf(z3);
        agx[0] += w0 * xv.x; agy[0] += w0 * xv.y; agz[0] += w0 * xv.z; dn[0] += w0;
        agx[1] += w1 * xv.x; agy[1] += w1 * xv.y; agz[1] += w1 * xv.z; dn[1] += w1;
        agx[2] += w2 * xv.x; agy[2] += w2 * xv.y; agz[2] += w2 * xv.z; dn[2] += w2;
        agx[3] += w3 * xv.x; agy[3] += w3 * xv.y; agz[3] += w3 * xv.z; dn[3] += w3;
    }

    // epilogue: lane sl emits channels j = h*16 + sl, h = 0..3
#pragma unroll
    for (int h = 0; h < 4; ++h) {
        int j = h * 16 + sl;
        float inv = 1.f / (dn[h] + 1e-16f);
        float o = (agx[h] * W1[j] + agy[h] * W1[64 + j] + agz[h] * W1[128 + j]) * inv + b1[j];
        x1[(size_t)node * 64 + j] = (o > 0.f) ? o : 0.f;
    }
}

// ---------------- Layer 2: GATv2Conv(64, 16, heads=2) ----------------

__global__ __launch_bounds__(256) void k_l2_transform(const float* __restrict__ x1,
                                                      const float* __restrict__ W2l, const float* __restrict__ b2l,
                                                      const float* __restrict__ W2r, const float* __restrict__ b2r,
                                                      unsigned short* __restrict__ hlb, float* __restrict__ hr, int N) {
    __shared__ float xs[4][64];
    int tid = threadIdx.x;
    int r = tid >> 6, c64 = tid & 63;
    int node = blockIdx.x * 4 + r;
    xs[r][c64] = (node < N) ? x1[(size_t)node * 64 + c64] : 0.f;
    __syncthreads();
    if (node >= N) return;
    int half = (tid >> 5) & 1;
    int j = tid & 31;
    const float* W = half ? W2r : W2l;
    float acc = half ? b2r[j] : b2l[j];
#pragma unroll
    for (int k = 0; k < 64; ++k) acc += xs[r][k] * W[k * 32 + j];
    if (half) hr[(size_t)node * 32 + j] = acc;
    else      hlb[(size_t)node * 32 + j] = f2us(acc);
}

// 32 lanes per node (2 nodes per wave); lane = head*16 + chan; 4-deep unroll
__global__ __launch_bounds__(256) void k_l2_agg(const unsigned short* __restrict__ hlb, const float* __restrict__ hr,
                                                const float* __restrict__ att2, const float* __restrict__ b2,
                                                const int* __restrict__ off, const int* __restrict__ csr,
                                                float* __restrict__ x2, int N) {
    int tid = threadIdx.x;
    int node = blockIdx.x * 8 + (tid >> 5);
    if (node >= N) return;
    int sl = tid & 31;
    float hrd = hr[(size_t)node * 32 + sl];
    float a2 = att2[sl];
    int e0 = off[node], e1 = off[node + 1];
    // self-loop
    float hsf = us2f(hlb[(size_t)node * 32 + sl]);
    float e = hsf + hrd;
    e = (e > 0.f) ? e : 0.2f * e;
    float t = e * a2;
    t += __shfl_xor(t, 1); t += __shfl_xor(t, 2);
    t += __shfl_xor(t, 4); t += __shfl_xor(t, 8);
    float w = __expf(t);
    float den0 = w, den1 = 0.f, den2 = 0.f, den3 = 0.f;
    float acc0 = w * hsf, acc1 = 0.f, acc2 = 0.f, acc3 = 0.f;
    int jj = e0;
    for (; jj + 4 <= e1; jj += 4) {
        int s0 = csr[jj], s1 = csr[jj + 1], s2 = csr[jj + 2], s3 = csr[jj + 3];
        float h0 = us2f(hlb[(size_t)s0 * 32 + sl]);
        float h1v = us2f(hlb[(size_t)s1 * 32 + sl]);
        float h2v = us2f(hlb[(size_t)s2 * 32 + sl]);
        float h3v = us2f(hlb[(size_t)s3 * 32 + sl]);
        float e0v = h0 + hrd, e1v = h1v + hrd, e2v = h2v + hrd, e3v = h3v + hrd;
        e0v = (e0v > 0.f) ? e0v : 0.2f * e0v;
        e1v = (e1v > 0.f) ? e1v : 0.2f * e1v;
        e2v = (e2v > 0.f) ? e2v : 0.2f * e2v;
        e3v = (e3v > 0.f) ? e3v : 0.2f * e3v;
        float t0 = e0v * a2, t1 = e1v * a2, t2 = e2v * a2, t3 = e3v * a2;
        t0 += __shfl_xor(t0, 1); t1 += __shfl_xor(t1, 1); t2 += __shfl_xor(t2, 1); t3 += __shfl_xor(t3, 1);
        t0 += __shfl_xor(t0, 2); t1 += __shfl_xor(t1, 2); t2 += __shfl_xor(t2, 2); t3 += __shfl_xor(t3, 2);
        t0 += __shfl_xor(t0, 4); t1 += __shfl_xor(t1, 4); t2 += __shfl_xor(t2, 4); t3 += __shfl_xor(t3, 4);
        t0 += __shfl_xor(t0, 8); t1 += __shfl_xor(t1, 8); t2 += __shfl_xor(t2, 8); t3 += __shfl_xor(t3, 8);
        float w0 = __expf(t0), w1 = __expf(t1), w2 = __expf(t2), w3 = __expf(t3);
        den0 += w0; acc0 += w0 * h0;
        den1 += w1; acc1 += w1 * h1v;
        den2 += w2; acc2 += w2 * h2v;
        den3 += w3; acc3 += w3 * h3v;
    }
    for (; jj < e1; ++jj) {
        int s0 = csr[jj];
        float h0 = us2f(hlb[(size_t)s0 * 32 + sl]);
        float e0v = h0 + hrd;
        e0v = (e0v > 0.f) ? e0v : 0.2f * e0v;
        float t0 = e0v * a2;
        t0 += __shfl_xor(t0, 1); t0 += __shfl_xor(t0, 2);
        t0 += __shfl_xor(t0, 4); t0 += __shfl_xor(t0, 8);
        float w0 = __expf(t0);
        den0 += w0; acc0 += w0 * h0;
    }
    x2[(size_t)node * 32 + sl] = (acc0 + acc1 + acc2 + acc3) / (den0 + den1 + den2 + den3 + 1e-16f) + b2[sl];
}

// ---------------- Layer 3: TransformerConv(32, 7, heads=1) ----------------

__global__ __launch_bounds__(256) void k_l3_transform(const float* __restrict__ x2,
                                                      const float* __restrict__ Wq, const float* __restrict__ bq,
                                                      const float* __restrict__ Wk, const float* __restrict__ bk,
                                                      const float* __restrict__ Wv, const float* __restrict__ bv,
                                                      const float* __restrict__ Wsk, const float* __restrict__ bsk,
                                                      float* __restrict__ Q, float* __restrict__ K,
                                                      float* __restrict__ V, float* __restrict__ SK, int N) {
    __shared__ float xs[8][32];
    int tid = threadIdx.x;
    int r = tid >> 5, cc = tid & 31;
    int node = blockIdx.x * 8 + r;
    xs[r][cc] = (node < N) ? x2[(size_t)node * 32 + cc] : 0.f;
    __syncthreads();
    if (node >= N) return;
    int j = tid & 31;
    if (j >= 28) return;
    int m = j / 7, c = j - m * 7;
    const float* W = (m == 0) ? Wq : (m == 1) ? Wk : (m == 2) ? Wv : Wsk;
    const float* B = (m == 0) ? bq : (m == 1) ? bk : (m == 2) ? bv : bsk;
    float acc = B[c];
#pragma unroll
    for (int k = 0; k < 32; ++k) acc += xs[r][k] * W[k * 7 + c];
    float* outp = (m == 0) ? Q : (m == 1) ? K : (m == 2) ? V : SK;
    outp[(size_t)node * 7 + c] = acc;
}

__global__ __launch_bounds__(256) void k_l3_agg(const float* __restrict__ Q, const float* __restrict__ K,
                                                const float* __restrict__ V, const float* __restrict__ SK,
                                                const int* __restrict__ off, const int* __restrict__ csr,
                                                float* __restrict__ out, int N) {
    int tid = threadIdx.x;
    int node = blockIdx.x * 32 + (tid >> 3);
    if (node >= N) return;
    int sl = tid & 7;
    bool act = sl < 7;
    float qd = act ? Q[(size_t)node * 7 + sl] : 0.f;
    float acc = 0.f, den = 0.f;
    int e0 = off[node], e1 = off[node + 1];
    const float scale = 0.3779644730092272f;  // 1/sqrt(7)
    for (int jj = e0; jj < e1; ++jj) {
        int s = csr[jj];
        float t = act ? qd * K[(size_t)s * 7 + sl] : 0.f;
        t += __shfl_xor(t, 1); t += __shfl_xor(t, 2); t += __shfl_xor(t, 4);
        float w = __expf(t * scale);
        den += w;
        if (act) acc += w * V[(size_t)s * 7 + sl];
    }
    if (act) out[(size_t)node * 7 + sl] = acc / (den + 1e-16f) + SK[(size_t)node * 7 + sl];
}

// ---------------- launcher ----------------

extern "C" void kernel_launch(void* const* d_in, const int* in_sizes, int n_in,
                              void* d_out, int out_size, void* d_ws, size_t ws_size,
                              hipStream_t stream) {
    const int* ei = (const int*)d_in[1];
    float* out = (float*)d_out;

    int N = in_sizes[0] / 3;
    int E = in_sizes[1] / 2;
    int NB = (N + 1023) >> 10;   // assumed <= 256 (N <= 262144)

    char* ws = (char*)d_ws;
    size_t o = 0;
    auto take = [&](size_t bytes) -> char* {
        char* p = ws + o;
        o = (o + bytes + 255) & ~(size_t)255;
        return p;
    };
    int*   flags   = (int*)take(64);
    int total_f = 0;
    for (int i = 0; i < 20; ++i) if (i != 1) total_f += in_sizes[i];
    float* canon   = (float*)take((size_t)total_f * 4);
    int*   csr_off = (int*)take((size_t)(N + 1) * 4);
    int*   bcnt    = (int*)take(256 * 4);
    int*   bbase   = (int*)take(257 * 4);
    int*   bcur    = (int*)take(256 * 4);
    int*   csr     = (int*)take((size_t)E * 4);
    float* bufA    = (float*)take((size_t)N * 64 * 4);  // x4 -> hlb|hr -> q|k|v|skip
    float* as1     = (float*)take((size_t)N * 4 * 4);
    float* ad1     = (float*)take((size_t)N * 4 * 4);
    float* bufB    = (float*)take((size_t)N * 64 * 4);  // bkt -> x1 -> x2
    (void)ws_size; (void)n_in; (void)out_size;

    CvtArgs ca;
    const float* cp[20];
    {
        int off_ = 0, k = 0;
        for (int i = 0; i < 20; ++i) {
            if (i == 1) { cp[i] = nullptr; continue; }
            ca.p[k] = d_in[i];
            ca.sz[k] = in_sizes[i];
            cp[i] = canon + off_;
            off_ += in_sizes[i];
            ++k;
        }
    }

    hipMemsetAsync(bcnt, 0, 256 * 4, stream);
    k_detect<<<1, 256, 0, stream>>>((const unsigned short*)d_in[0], ei, flags);
    k_convert<<<(total_f + 255) / 256, 256, 0, stream>>>(ca, flags, canon, total_f);

    int2* bkt = (int2*)bufB;
    int gb = (E + 4095) / 4096;
    k_bhist<<<gb, 1024, 0, stream>>>(ei, flags, bcnt, E, NB);
    k_bscan<<<1, 256, 0, stream>>>(bcnt, bbase, bcur, csr_off, NB, N, E);
    k_bscatter<<<gb, 1024, 0, stream>>>(ei, flags, bcur, bkt, E, NB);
    k_bbuild<<<NB, 1024, 0, stream>>>(bkt, bbase, csr_off, csr, N);

    float4* x4 = (float4*)bufA;                                  // N*16B = 1.6 MB, L2-resident
    k_l1_transform<<<(N + 3) / 4, 256, 0, stream>>>(cp[0], cp[2], cp[3], cp[4], x4, as1, ad1, N);
    float* x1 = bufB;
    k_l1_agg<<<(N + 15) / 16, 256, 0, stream>>>(x4, (const float4*)as1, (const float4*)ad1,
                                                csr_off, csr, cp[2], cp[5], x1, N);

    unsigned short* hlb = (unsigned short*)bufA;                 // N*32 bf16 = 6.4 MB
    float* hr = bufA + (size_t)N * 16;
    k_l2_transform<<<(N + 3) / 4, 256, 0, stream>>>(x1, cp[6], cp[7], cp[8], cp[9], hlb, hr, N);
    float* x2 = bufB;
    k_l2_agg<<<(N + 7) / 8, 256, 0, stream>>>(hlb, hr, cp[10], cp[11], csr_off, csr, x2, N);

    float* Q  = bufA;
    float* K  = bufA + (size_t)N * 7;
    float* V  = bufA + (size_t)N * 14;
    float* SK = bufA + (size_t)N * 21;
    k_l3_transform<<<(N + 7) / 8, 256, 0, stream>>>(x2, cp[12], cp[13], cp[14], cp[15], cp[16], cp[17],
                                                    cp[18], cp[19], Q, K, V, SK, N);
    k_l3_agg<<<(N + 31) / 32, 256, 0, stream>>>(Q, K, V, SK, csr_off, csr, out, N);
}

// Round 7
// 384.759 us; speedup vs baseline: 1.3027x; 1.1493x over previous
//
#include <hip/hip_runtime.h>
#include <hip/hip_bf16.h>

typedef __hip_bfloat16 bf16;

static __device__ __forceinline__ float us2f(unsigned short u) {
    union { unsigned int i; float f; } c; c.i = ((unsigned int)u) << 16; return c.f;
}
static __device__ __forceinline__ unsigned short f2us(float f) {
    union { float f; unsigned int i; } c; c.f = f;
    unsigned int r = c.i + 0x7FFF + ((c.i >> 16) & 1);   // round-to-nearest-even
    return (unsigned short)(r >> 16);
}

// ---------------- dtype probe + canonicalization ----------------

__global__ __launch_bounds__(256) void k_detect(const unsigned short* __restrict__ xr,
                                                const int* __restrict__ er,
                                                int* __restrict__ flags) {
    __shared__ int sbad, snz;
    int tid = threadIdx.x;
    if (tid == 0) { sbad = 0; snz = 0; }
    __syncthreads();
    int bad = 0, nz = 0;
    for (int i = tid; i < 1024; i += 256) {
        unsigned short w = xr[2 * i];
        int ex = (w >> 7) & 0xFF;
        if (ex < 110 || ex > 135) bad++;
        if (er[2 * i + 1] != 0) nz++;
    }
    atomicAdd(&sbad, bad);
    atomicAdd(&snz, nz);
    __syncthreads();
    if (tid == 0) {
        flags[0] = (sbad > 256) ? 1 : 0;
        flags[1] = (snz < 512) ? 1 : 0;
    }
}

struct CvtArgs { const void* p[19]; int sz[19]; };

__global__ __launch_bounds__(256) void k_convert(CvtArgs a, const int* __restrict__ flags,
                                                 float* __restrict__ dst, int total) {
    int t = blockIdx.x * 256 + threadIdx.x;
    if (t >= total) return;
    int isf32 = flags[0];
    int base = 0, seg = -1, off = 0;
#pragma unroll
    for (int i = 0; i < 19; i++) {
        if (seg < 0 && t < base + a.sz[i]) { seg = i; off = t - base; }
        base += a.sz[i];
    }
    const void* p = a.p[seg];
    float v = isf32 ? ((const float*)p)[off] : __bfloat162float(((const bf16*)p)[off]);
    dst[t] = v;
}

static __device__ __forceinline__ int ld_edge(const int* er, size_t i, int idx64) {
    return idx64 ? er[2 * i] : er[i];
}

// ---------------- bucketed CSR build ----------------
// bucket b = dst >> 10 (1024 nodes per bucket), NB <= 256 assumed (N <= 262144)

__global__ __launch_bounds__(1024) void k_bhist(const int* __restrict__ er, const int* __restrict__ flags,
                                                int* __restrict__ bcnt, int E, int NB) {
    __shared__ int cnt[256];
    int tid = threadIdx.x;
    if (tid < 256) cnt[tid] = 0;
    __syncthreads();
    int idx64 = flags[1];
    int base = blockIdx.x * 4096 + tid;
#pragma unroll
    for (int k = 0; k < 4; ++k) {
        int e = base + k * 1024;
        if (e < E) {
            int d = ld_edge(er, (size_t)E + e, idx64);
            atomicAdd(&cnt[d >> 10], 1);
        }
    }
    __syncthreads();
    if (tid < NB && cnt[tid]) atomicAdd(&bcnt[tid], cnt[tid]);
}

__global__ __launch_bounds__(256) void k_bscan(const int* __restrict__ bcnt, int* __restrict__ bbase,
                                               int* __restrict__ bcur, int* __restrict__ csr_off,
                                               int NB, int N, int E) {
    __shared__ int sm[256];
    int tid = threadIdx.x;
    int v = (tid < NB) ? bcnt[tid] : 0;
    sm[tid] = v;
    __syncthreads();
    for (int d = 1; d < 256; d <<= 1) {
        int t = (tid >= d) ? sm[tid - d] : 0;
        __syncthreads();
        sm[tid] += t;
        __syncthreads();
    }
    int excl = sm[tid] - v;
    if (tid < NB) { bbase[tid] = excl; bcur[tid] = excl; }
    if (tid == 0) { bbase[NB] = E; csr_off[N] = E; }
}

__global__ __launch_bounds__(1024) void k_bscatter(const int* __restrict__ er, const int* __restrict__ flags,
                                                   int* __restrict__ bcur, int2* __restrict__ bkt,
                                                   int E, int NB) {
    __shared__ int cnt[256];
    __shared__ int res[256];
    int tid = threadIdx.x;
    if (tid < 256) cnt[tid] = 0;
    __syncthreads();
    int idx64 = flags[1];
    int base = blockIdx.x * 4096 + tid;
    int sv[4], dv[4], bv[4];
    bool val[4];
#pragma unroll
    for (int k = 0; k < 4; ++k) {
        int e = base + k * 1024;
        val[k] = (e < E);
        if (val[k]) {
            sv[k] = ld_edge(er, (size_t)e, idx64);
            dv[k] = ld_edge(er, (size_t)E + e, idx64);
            bv[k] = dv[k] >> 10;
            atomicAdd(&cnt[bv[k]], 1);
        }
    }
    __syncthreads();
    if (tid < NB) {
        int c = cnt[tid];
        res[tid] = c ? atomicAdd(&bcur[tid], c) : 0;
        cnt[tid] = 0;
    }
    __syncthreads();
#pragma unroll
    for (int k = 0; k < 4; ++k) {
        if (val[k]) {
            int r = atomicAdd(&cnt[bv[k]], 1);
            bkt[res[bv[k]] + r] = make_int2(sv[k], dv[k]);
        }
    }
}

__global__ __launch_bounds__(1024) void k_bbuild(const int2* __restrict__ bkt, const int* __restrict__ bbase,
                                                 int* __restrict__ csr_off, int* __restrict__ csr, int N) {
    __shared__ int sm[1024];
    int b = blockIdx.x, tid = threadIdx.x;
    int node0 = b << 10;
    int n0 = bbase[b], n1 = bbase[b + 1];
    int m = n1 - n0;
    sm[tid] = 0;
    __syncthreads();
    const int2* bp = bkt + n0;
    for (int i = tid; i < m; i += 1024) atomicAdd(&sm[bp[i].y - node0], 1);
    __syncthreads();
    int v = sm[tid];
    for (int d = 1; d < 1024; d <<= 1) {
        int t = (tid >= d) ? sm[tid - d] : 0;
        __syncthreads();
        sm[tid] += t;
        __syncthreads();
    }
    int excl = sm[tid] - v;
    int node = node0 + tid;
    if (node < N) csr_off[node] = n0 + excl;
    __syncthreads();
    sm[tid] = excl;
    __syncthreads();
    for (int i = tid; i < m; i += 1024) {
        int2 sd = bp[i];
        int r = atomicAdd(&sm[sd.y - node0], 1);
        csr[n0 + r] = sd.x;
    }
}

// ---------------- Layer 1: GATConv(3, 16, heads=4) ----------------

__global__ __launch_bounds__(256) void k_l1_transform(const float* __restrict__ x, const float* __restrict__ W1,
                                                      const float* __restrict__ att_s, const float* __restrict__ att_d,
                                                      float4* __restrict__ x4, float* __restrict__ as1,
                                                      float* __restrict__ ad1, int N) {
    int tid = threadIdx.x;
    int node = blockIdx.x * 4 + (tid >> 6);
    if (node >= N) return;
    int lane = tid & 63;
    float x0 = x[node * 3 + 0];
    float x1 = x[node * 3 + 1];
    float x2 = x[node * 3 + 2];
    float h = x0 * W1[lane] + x1 * W1[64 + lane] + x2 * W1[128 + lane];
    if (lane == 0) x4[node] = make_float4(x0, x1, x2, 0.f);
    float ts = h * att_s[lane];
    float td = h * att_d[lane];
    for (int m = 8; m >= 1; m >>= 1) { ts += __shfl_xor(ts, m); td += __shfl_xor(td, m); }
    if ((lane & 15) == 0) {
        as1[node * 4 + (lane >> 4)] = ts;
        ad1[node * 4 + (lane >> 4)] = td;
    }
}

// Edge-parallel: 16 lanes per node; accumulate per-head weighted x-3vec + denom, butterfly-reduce.
__global__ __launch_bounds__(256) void k_l1_agg(const float4* __restrict__ x4, const float4* __restrict__ as4,
                                                const float4* __restrict__ ad4p, const int* __restrict__ off,
                                                const int* __restrict__ csr, const float* __restrict__ W1,
                                                const float* __restrict__ b1,
                                                float* __restrict__ x1, int N) {
    int tid = threadIdx.x;
    int node = blockIdx.x * 16 + (tid >> 4);
    if (node >= N) return;
    int sl = tid & 15;
    int lane = tid & 63;
    int lb = lane & 48;

    float4 ad = ad4p[node];
    int e0 = off[node], e1 = off[node + 1];

    float v[16];
#pragma unroll
    for (int i = 0; i < 16; ++i) v[i] = 0.f;

    for (int jj = e0 + sl; jj < e1; jj += 16) {
        int s = csr[jj];
        float4 a = as4[s];
        float4 xv = x4[s];
        float z0 = a.x + ad.x, z1 = a.y + ad.y, z2 = a.z + ad.z, z3 = a.w + ad.w;
        z0 = (z0 > 0.f) ? z0 : 0.2f * z0;
        z1 = (z1 > 0.f) ? z1 : 0.2f * z1;
        z2 = (z2 > 0.f) ? z2 : 0.2f * z2;
        z3 = (z3 > 0.f) ? z3 : 0.2f * z3;
        float w0 = __expf(z0), w1 = __expf(z1), w2 = __expf(z2), w3 = __expf(z3);
        v[0] += w0 * xv.x; v[1] += w0 * xv.y; v[2]  += w0 * xv.z; v[3]  += w0;
        v[4] += w1 * xv.x; v[5] += w1 * xv.y; v[6]  += w1 * xv.z; v[7]  += w1;
        v[8] += w2 * xv.x; v[9] += w2 * xv.y; v[10] += w2 * xv.z; v[11] += w2;
        v[12] += w3 * xv.x; v[13] += w3 * xv.y; v[14] += w3 * xv.z; v[15] += w3;
    }

#pragma unroll
    for (int d = 8; d >= 1; d >>= 1) {
#pragma unroll
        for (int i = 0; i < 16; ++i) {
            if (i < d) {
                float a = v[i], b = v[i + d];
                float send = (sl & d) ? a : b;
                float recv = __shfl_xor(send, d);
                v[i] = ((sl & d) ? b : a) + recv;
            }
        }
    }
    float r = v[0];

    float agx[4], agy[4], agz[4], dn[4];
#pragma unroll
    for (int h = 0; h < 4; ++h) {
        agx[h] = __shfl(r, lb + 4 * h + 0);
        agy[h] = __shfl(r, lb + 4 * h + 1);
        agz[h] = __shfl(r, lb + 4 * h + 2);
        dn[h]  = __shfl(r, lb + 4 * h + 3);
    }

    {
        float4 a = as4[node];
        float4 xv = x4[node];
        float z0 = a.x + ad.x, z1 = a.y + ad.y, z2 = a.z + ad.z, z3 = a.w + ad.w;
        z0 = (z0 > 0.f) ? z0 : 0.2f * z0;
        z1 = (z1 > 0.f) ? z1 : 0.2f * z1;
        z2 = (z2 > 0.f) ? z2 : 0.2f * z2;
        z3 = (z3 > 0.f) ? z3 : 0.2f * z3;
        float w0 = __expf(z0), w1 = __expf(z1), w2 = __expf(z2), w3 = __expf(z3);
        agx[0] += w0 * xv.x; agy[0] += w0 * xv.y; agz[0] += w0 * xv.z; dn[0] += w0;
        agx[1] += w1 * xv.x; agy[1] += w1 * xv.y; agz[1] += w1 * xv.z; dn[1] += w1;
        agx[2] += w2 * xv.x; agy[2] += w2 * xv.y; agz[2] += w2 * xv.z; dn[2] += w2;
        agx[3] += w3 * xv.x; agy[3] += w3 * xv.y; agz[3] += w3 * xv.z; dn[3] += w3;
    }

#pragma unroll
    for (int h = 0; h < 4; ++h) {
        int j = h * 16 + sl;
        float inv = 1.f / (dn[h] + 1e-16f);
        float o = (agx[h] * W1[j] + agy[h] * W1[64 + j] + agz[h] * W1[128 + j]) * inv + b1[j];
        x1[(size_t)node * 64 + j] = (o > 0.f) ? o : 0.f;
    }
}

// ---------------- Layer 2: GATv2Conv(64, 16, heads=2) ----------------

// one thread per node; uniform (scalar) weight loads; vectorized row I/O
__global__ __launch_bounds__(256) void k_l2_transform(const float* __restrict__ x1,
                                                      const float* __restrict__ W2l, const float* __restrict__ b2l,
                                                      const float* __restrict__ W2r, const float* __restrict__ b2r,
                                                      unsigned short* __restrict__ hlb, float* __restrict__ hr, int N) {
    int node = blockIdx.x * 256 + threadIdx.x;
    if (node >= N) return;
    const float4* xr = (const float4*)(x1 + (size_t)node * 64);
    float accl[32], accr[32];
#pragma unroll
    for (int j = 0; j < 32; ++j) { accl[j] = b2l[j]; accr[j] = b2r[j]; }
#pragma unroll 2
    for (int k4 = 0; k4 < 16; ++k4) {
        float4 xv = xr[k4];
        float xs0 = xv.x, xs1 = xv.y, xs2 = xv.z, xs3 = xv.w;
        const float* wl = W2l + k4 * 128;
        const float* wr = W2r + k4 * 128;
#pragma unroll
        for (int j = 0; j < 32; ++j) {
            accl[j] += xs0 * wl[j] + xs1 * wl[32 + j] + xs2 * wl[64 + j] + xs3 * wl[96 + j];
            accr[j] += xs0 * wr[j] + xs1 * wr[32 + j] + xs2 * wr[64 + j] + xs3 * wr[96 + j];
        }
    }
    float4* hr4 = (float4*)(hr + (size_t)node * 32);
#pragma unroll
    for (int q = 0; q < 8; ++q)
        hr4[q] = make_float4(accr[4 * q], accr[4 * q + 1], accr[4 * q + 2], accr[4 * q + 3]);
    union { unsigned int u[16]; uint4 v[4]; } pk;
#pragma unroll
    for (int q = 0; q < 16; ++q)
        pk.u[q] = (unsigned)f2us(accl[2 * q]) | ((unsigned)f2us(accl[2 * q + 1]) << 16);
    uint4* hp = (uint4*)(hlb + (size_t)node * 32);
#pragma unroll
    for (int q = 0; q < 4; ++q) hp[q] = pk.v[q];
}

// 32 lanes per node (2 nodes per wave); lane = head*16 + chan; 4-deep unroll
__global__ __launch_bounds__(256) void k_l2_agg(const unsigned short* __restrict__ hlb, const float* __restrict__ hr,
                                                const float* __restrict__ att2, const float* __restrict__ b2,
                                                const int* __restrict__ off, const int* __restrict__ csr,
                                                float* __restrict__ x2, int N) {
    int tid = threadIdx.x;
    int node = blockIdx.x * 8 + (tid >> 5);
    if (node >= N) return;
    int sl = tid & 31;
    float hrd = hr[(size_t)node * 32 + sl];
    float a2 = att2[sl];
    int e0 = off[node], e1 = off[node + 1];
    float hsf = us2f(hlb[(size_t)node * 32 + sl]);
    float e = hsf + hrd;
    e = (e > 0.f) ? e : 0.2f * e;
    float t = e * a2;
    t += __shfl_xor(t, 1); t += __shfl_xor(t, 2);
    t += __shfl_xor(t, 4); t += __shfl_xor(t, 8);
    float w = __expf(t);
    float den0 = w, den1 = 0.f, den2 = 0.f, den3 = 0.f;
    float acc0 = w * hsf, acc1 = 0.f, acc2 = 0.f, acc3 = 0.f;
    int jj = e0;
    for (; jj + 4 <= e1; jj += 4) {
        int s0 = csr[jj], s1 = csr[jj + 1], s2 = csr[jj + 2], s3 = csr[jj + 3];
        float h0 = us2f(hlb[(size_t)s0 * 32 + sl]);
        float h1v = us2f(hlb[(size_t)s1 * 32 + sl]);
        float h2v = us2f(hlb[(size_t)s2 * 32 + sl]);
        float h3v = us2f(hlb[(size_t)s3 * 32 + sl]);
        float e0v = h0 + hrd, e1v = h1v + hrd, e2v = h2v + hrd, e3v = h3v + hrd;
        e0v = (e0v > 0.f) ? e0v : 0.2f * e0v;
        e1v = (e1v > 0.f) ? e1v : 0.2f * e1v;
        e2v = (e2v > 0.f) ? e2v : 0.2f * e2v;
        e3v = (e3v > 0.f) ? e3v : 0.2f * e3v;
        float t0 = e0v * a2, t1 = e1v * a2, t2 = e2v * a2, t3 = e3v * a2;
        t0 += __shfl_xor(t0, 1); t1 += __shfl_xor(t1, 1); t2 += __shfl_xor(t2, 1); t3 += __shfl_xor(t3, 1);
        t0 += __shfl_xor(t0, 2); t1 += __shfl_xor(t1, 2); t2 += __shfl_xor(t2, 2); t3 += __shfl_xor(t3, 2);
        t0 += __shfl_xor(t0, 4); t1 += __shfl_xor(t1, 4); t2 += __shfl_xor(t2, 4); t3 += __shfl_xor(t3, 4);
        t0 += __shfl_xor(t0, 8); t1 += __shfl_xor(t1, 8); t2 += __shfl_xor(t2, 8); t3 += __shfl_xor(t3, 8);
        float w0 = __expf(t0), w1 = __expf(t1), w2 = __expf(t2), w3 = __expf(t3);
        den0 += w0; acc0 += w0 * h0;
        den1 += w1; acc1 += w1 * h1v;
        den2 += w2; acc2 += w2 * h2v;
        den3 += w3; acc3 += w3 * h3v;
    }
    for (; jj < e1; ++jj) {
        int s0 = csr[jj];
        float h0 = us2f(hlb[(size_t)s0 * 32 + sl]);
        float e0v = h0 + hrd;
        e0v = (e0v > 0.f) ? e0v : 0.2f * e0v;
        float t0 = e0v * a2;
        t0 += __shfl_xor(t0, 1); t0 += __shfl_xor(t0, 2);
        t0 += __shfl_xor(t0, 4); t0 += __shfl_xor(t0, 8);
        float w0 = __expf(t0);
        den0 += w0; acc0 += w0 * h0;
    }
    x2[(size_t)node * 32 + sl] = (acc0 + acc1 + acc2 + acc3) / (den0 + den1 + den2 + den3 + 1e-16f) + b2[sl];
}

// ---------------- Layer 3: TransformerConv(32, 7, heads=1) ----------------

// one thread per node; outputs packed: QS[node][16] = {Q0..6,pad,SK0..6,pad},
// KV[node][16] = {K0..6,pad,V0..6,pad} (one 64B line per edge gather)
__global__ __launch_bounds__(256) void k_l3_transform(const float* __restrict__ x2,
                                                      const float* __restrict__ Wq, const float* __restrict__ bq,
                                                      const float* __restrict__ Wk, const float* __restrict__ bk,
                                                      const float* __restrict__ Wv, const float* __restrict__ bv,
                                                      const float* __restrict__ Wsk, const float* __restrict__ bsk,
                                                      float* __restrict__ QS, float* __restrict__ KV, int N) {
    int node = blockIdx.x * 256 + threadIdx.x;
    if (node >= N) return;
    const float4* xr = (const float4*)(x2 + (size_t)node * 32);
    float q[7], kk[7], vv[7], sk[7];
#pragma unroll
    for (int c = 0; c < 7; ++c) { q[c] = bq[c]; kk[c] = bk[c]; vv[c] = bv[c]; sk[c] = bsk[c]; }
#pragma unroll 2
    for (int k4 = 0; k4 < 8; ++k4) {
        float4 xv = xr[k4];
        float xs0 = xv.x, xs1 = xv.y, xs2 = xv.z, xs3 = xv.w;
        const float* wq = Wq + k4 * 28;
        const float* wk = Wk + k4 * 28;
        const float* wv = Wv + k4 * 28;
        const float* ws = Wsk + k4 * 28;
#pragma unroll
        for (int c = 0; c < 7; ++c) {
            q[c]  += xs0 * wq[c] + xs1 * wq[7 + c] + xs2 * wq[14 + c] + xs3 * wq[21 + c];
            kk[c] += xs0 * wk[c] + xs1 * wk[7 + c] + xs2 * wk[14 + c] + xs3 * wk[21 + c];
            vv[c] += xs0 * wv[c] + xs1 * wv[7 + c] + xs2 * wv[14 + c] + xs3 * wv[21 + c];
            sk[c] += xs0 * ws[c] + xs1 * ws[7 + c] + xs2 * ws[14 + c] + xs3 * ws[21 + c];
        }
    }
    float4* qs4 = (float4*)(QS + (size_t)node * 16);
    qs4[0] = make_float4(q[0], q[1], q[2], q[3]);
    qs4[1] = make_float4(q[4], q[5], q[6], 0.f);
    qs4[2] = make_float4(sk[0], sk[1], sk[2], sk[3]);
    qs4[3] = make_float4(sk[4], sk[5], sk[6], 0.f);
    float4* kv4 = (float4*)(KV + (size_t)node * 16);
    kv4[0] = make_float4(kk[0], kk[1], kk[2], kk[3]);
    kv4[1] = make_float4(kk[4], kk[5], kk[6], 0.f);
    kv4[2] = make_float4(vv[0], vv[1], vv[2], vv[3]);
    kv4[3] = make_float4(vv[4], vv[5], vv[6], 0.f);
}

// 8 lanes per node; K and V of one source share a cache line; 2-deep unroll
__global__ __launch_bounds__(256) void k_l3_agg(const float* __restrict__ QS, const float* __restrict__ KV,
                                                const int* __restrict__ off, const int* __restrict__ csr,
                                                float* __restrict__ out, int N) {
    int tid = threadIdx.x;
    int node = blockIdx.x * 32 + (tid >> 3);
    if (node >= N) return;
    int sl = tid & 7;
    bool act = sl < 7;
    float qd = act ? QS[(size_t)node * 16 + sl] : 0.f;
    float acc0 = 0.f, den0 = 0.f, acc1 = 0.f, den1 = 0.f;
    int e0 = off[node], e1 = off[node + 1];
    const float scale = 0.3779644730092272f;  // 1/sqrt(7)
    int jj = e0;
    for (; jj + 2 <= e1; jj += 2) {
        int s0 = csr[jj], s1 = csr[jj + 1];
        float k0 = act ? KV[(size_t)s0 * 16 + sl] : 0.f;
        float k1 = act ? KV[(size_t)s1 * 16 + sl] : 0.f;
        float v0 = act ? KV[(size_t)s0 * 16 + 8 + sl] : 0.f;
        float v1 = act ? KV[(size_t)s1 * 16 + 8 + sl] : 0.f;
        float t0 = qd * k0, t1 = qd * k1;
        t0 += __shfl_xor(t0, 1); t1 += __shfl_xor(t1, 1);
        t0 += __shfl_xor(t0, 2); t1 += __shfl_xor(t1, 2);
        t0 += __shfl_xor(t0, 4); t1 += __shfl_xor(t1, 4);
        float w0 = __expf(t0 * scale), w1 = __expf(t1 * scale);
        den0 += w0; acc0 += w0 * v0;
        den1 += w1; acc1 += w1 * v1;
    }
    if (jj < e1) {
        int s0 = csr[jj];
        float k0 = act ? KV[(size_t)s0 * 16 + sl] : 0.f;
        float v0 = act ? KV[(size_t)s0 * 16 + 8 + sl] : 0.f;
        float t0 = qd * k0;
        t0 += __shfl_xor(t0, 1); t0 += __shfl_xor(t0, 2); t0 += __shfl_xor(t0, 4);
        float w0 = __expf(t0 * scale);
        den0 += w0; acc0 += w0 * v0;
    }
    if (act) out[(size_t)node * 7 + sl] = (acc0 + acc1) / (den0 + den1 + 1e-16f)
                                          + QS[(size_t)node * 16 + 8 + sl];
}

// ---------------- launcher ----------------

extern "C" void kernel_launch(void* const* d_in, const int* in_sizes, int n_in,
                              void* d_out, int out_size, void* d_ws, size_t ws_size,
                              hipStream_t stream) {
    const int* ei = (const int*)d_in[1];
    float* out = (float*)d_out;

    int N = in_sizes[0] / 3;
    int E = in_sizes[1] / 2;
    int NB = (N + 1023) >> 10;   // assumed <= 256 (N <= 262144)

    char* ws = (char*)d_ws;
    size_t o = 0;
    auto take = [&](size_t bytes) -> char* {
        char* p = ws + o;
        o = (o + bytes + 255) & ~(size_t)255;
        return p;
    };
    int*   flags   = (int*)take(64);
    int total_f = 0;
    for (int i = 0; i < 20; ++i) if (i != 1) total_f += in_sizes[i];
    float* canon   = (float*)take((size_t)total_f * 4);
    int*   csr_off = (int*)take((size_t)(N + 1) * 4);
    int*   bcnt    = (int*)take(256 * 4);
    int*   bbase   = (int*)take(257 * 4);
    int*   bcur    = (int*)take(256 * 4);
    int*   csr     = (int*)take((size_t)E * 4);
    float* bufA    = (float*)take((size_t)N * 64 * 4);  // x4 -> hlb|hr -> QS|KV
    float* as1     = (float*)take((size_t)N * 4 * 4);
    float* ad1     = (float*)take((size_t)N * 4 * 4);
    float* bufB    = (float*)take((size_t)N * 64 * 4);  // bkt -> x1 -> x2
    (void)ws_size; (void)n_in; (void)out_size;

    CvtArgs ca;
    const float* cp[20];
    {
        int off_ = 0, k = 0;
        for (int i = 0; i < 20; ++i) {
            if (i == 1) { cp[i] = nullptr; continue; }
            ca.p[k] = d_in[i];
            ca.sz[k] = in_sizes[i];
            cp[i] = canon + off_;
            off_ += in_sizes[i];
            ++k;
        }
    }

    hipMemsetAsync(bcnt, 0, 256 * 4, stream);
    k_detect<<<1, 256, 0, stream>>>((const unsigned short*)d_in[0], ei, flags);
    k_convert<<<(total_f + 255) / 256, 256, 0, stream>>>(ca, flags, canon, total_f);

    int2* bkt = (int2*)bufB;
    int gb = (E + 4095) / 4096;
    k_bhist<<<gb, 1024, 0, stream>>>(ei, flags, bcnt, E, NB);
    k_bscan<<<1, 256, 0, stream>>>(bcnt, bbase, bcur, csr_off, NB, N, E);
    k_bscatter<<<gb, 1024, 0, stream>>>(ei, flags, bcur, bkt, E, NB);
    k_bbuild<<<NB, 1024, 0, stream>>>(bkt, bbase, csr_off, csr, N);

    float4* x4 = (float4*)bufA;                                  // N*16B = 1.6 MB, L2-resident
    k_l1_transform<<<(N + 3) / 4, 256, 0, stream>>>(cp[0], cp[2], cp[3], cp[4], x4, as1, ad1, N);
    float* x1 = bufB;
    k_l1_agg<<<(N + 15) / 16, 256, 0, stream>>>(x4, (const float4*)as1, (const float4*)ad1,
                                                csr_off, csr, cp[2], cp[5], x1, N);

    unsigned short* hlb = (unsigned short*)bufA;                 // N*32 bf16 = 6.4 MB
    float* hr = bufA + (size_t)N * 16;
    k_l2_transform<<<(N + 255) / 256, 256, 0, stream>>>(x1, cp[6], cp[7], cp[8], cp[9], hlb, hr, N);
    float* x2 = bufB;
    k_l2_agg<<<(N + 7) / 8, 256, 0, stream>>>(hlb, hr, cp[10], cp[11], csr_off, csr, x2, N);

    float* QS = bufA;                                            // N*16 floats
    float* KV = bufA + (size_t)N * 16;                           // N*16 floats
    k_l3_transform<<<(N + 255) / 256, 256, 0, stream>>>(x2, cp[12], cp[13], cp[14], cp[15], cp[16], cp[17],
                                                        cp[18], cp[19], QS, KV, N);
    k_l3_agg<<<(N + 31) / 32, 256, 0, stream>>>(QS, KV, csr_off, csr, out, N);
}

// Round 8
// 362.883 us; speedup vs baseline: 1.3813x; 1.0603x over previous
//
#include <hip/hip_runtime.h>
#include <hip/hip_bf16.h>

typedef __hip_bfloat16 bf16;

static __device__ __forceinline__ float us2f(unsigned short u) {
    union { unsigned int i; float f; } c; c.i = ((unsigned int)u) << 16; return c.f;
}
static __device__ __forceinline__ unsigned short f2us(float f) {
    union { float f; unsigned int i; } c; c.f = f;
    unsigned int r = c.i + 0x7FFF + ((c.i >> 16) & 1);   // round-to-nearest-even
    return (unsigned short)(r >> 16);
}

// ---------------- dtype probe + canonicalization ----------------

__global__ __launch_bounds__(256) void k_detect(const unsigned short* __restrict__ xr,
                                                const int* __restrict__ er,
                                                int* __restrict__ flags) {
    __shared__ int sbad, snz;
    int tid = threadIdx.x;
    if (tid == 0) { sbad = 0; snz = 0; }
    __syncthreads();
    int bad = 0, nz = 0;
    for (int i = tid; i < 1024; i += 256) {
        unsigned short w = xr[2 * i];
        int ex = (w >> 7) & 0xFF;
        if (ex < 110 || ex > 135) bad++;
        if (er[2 * i + 1] != 0) nz++;
    }
    atomicAdd(&sbad, bad);
    atomicAdd(&snz, nz);
    __syncthreads();
    if (tid == 0) {
        flags[0] = (sbad > 256) ? 1 : 0;
        flags[1] = (snz < 512) ? 1 : 0;
    }
}

struct CvtArgs { const void* p[19]; int sz[19]; };

__global__ __launch_bounds__(256) void k_convert(CvtArgs a, const int* __restrict__ flags,
                                                 float* __restrict__ dst, int total) {
    int t = blockIdx.x * 256 + threadIdx.x;
    if (t >= total) return;
    int isf32 = flags[0];
    int base = 0, seg = -1, off = 0;
#pragma unroll
    for (int i = 0; i < 19; i++) {
        if (seg < 0 && t < base + a.sz[i]) { seg = i; off = t - base; }
        base += a.sz[i];
    }
    const void* p = a.p[seg];
    float v = isf32 ? ((const float*)p)[off] : __bfloat162float(((const bf16*)p)[off]);
    dst[t] = v;
}

static __device__ __forceinline__ int ld_edge(const int* er, size_t i, int idx64) {
    return idx64 ? er[2 * i] : er[i];
}

// ---------------- bucketed CSR build ----------------
// bucket b = dst >> 10 (1024 nodes per bucket), NB <= 256 assumed (N <= 262144)

__global__ __launch_bounds__(1024) void k_bhist(const int* __restrict__ er, const int* __restrict__ flags,
                                                int* __restrict__ bcnt, int E, int NB) {
    __shared__ int cnt[256];
    int tid = threadIdx.x;
    if (tid < 256) cnt[tid] = 0;
    __syncthreads();
    int idx64 = flags[1];
    int base = blockIdx.x * 4096 + tid;
#pragma unroll
    for (int k = 0; k < 4; ++k) {
        int e = base + k * 1024;
        if (e < E) {
            int d = ld_edge(er, (size_t)E + e, idx64);
            atomicAdd(&cnt[d >> 10], 1);
        }
    }
    __syncthreads();
    if (tid < NB && cnt[tid]) atomicAdd(&bcnt[tid], cnt[tid]);
}

__global__ __launch_bounds__(256) void k_bscan(const int* __restrict__ bcnt, int* __restrict__ bbase,
                                               int* __restrict__ bcur, int* __restrict__ csr_off,
                                               int NB, int N, int E) {
    __shared__ int sm[256];
    int tid = threadIdx.x;
    int v = (tid < NB) ? bcnt[tid] : 0;
    sm[tid] = v;
    __syncthreads();
    for (int d = 1; d < 256; d <<= 1) {
        int t = (tid >= d) ? sm[tid - d] : 0;
        __syncthreads();
        sm[tid] += t;
        __syncthreads();
    }
    int excl = sm[tid] - v;
    if (tid < NB) { bbase[tid] = excl; bcur[tid] = excl; }
    if (tid == 0) { bbase[NB] = E; csr_off[N] = E; }
}

__global__ __launch_bounds__(1024) void k_bscatter(const int* __restrict__ er, const int* __restrict__ flags,
                                                   int* __restrict__ bcur, int2* __restrict__ bkt,
                                                   int E, int NB) {
    __shared__ int cnt[256];
    __shared__ int res[256];
    int tid = threadIdx.x;
    if (tid < 256) cnt[tid] = 0;
    __syncthreads();
    int idx64 = flags[1];
    int base = blockIdx.x * 4096 + tid;
    int sv[4], dv[4], bv[4];
    bool val[4];
#pragma unroll
    for (int k = 0; k < 4; ++k) {
        int e = base + k * 1024;
        val[k] = (e < E);
        if (val[k]) {
            sv[k] = ld_edge(er, (size_t)e, idx64);
            dv[k] = ld_edge(er, (size_t)E + e, idx64);
            bv[k] = dv[k] >> 10;
            atomicAdd(&cnt[bv[k]], 1);
        }
    }
    __syncthreads();
    if (tid < NB) {
        int c = cnt[tid];
        res[tid] = c ? atomicAdd(&bcur[tid], c) : 0;
        cnt[tid] = 0;
    }
    __syncthreads();
#pragma unroll
    for (int k = 0; k < 4; ++k) {
        if (val[k]) {
            int r = atomicAdd(&cnt[bv[k]], 1);
            bkt[res[bv[k]] + r] = make_int2(sv[k], dv[k]);
        }
    }
}

__global__ __launch_bounds__(1024) void k_bbuild(const int2* __restrict__ bkt, const int* __restrict__ bbase,
                                                 int* __restrict__ csr_off, int* __restrict__ csr, int N) {
    __shared__ int sm[1024];
    int b = blockIdx.x, tid = threadIdx.x;
    int node0 = b << 10;
    int n0 = bbase[b], n1 = bbase[b + 1];
    int m = n1 - n0;
    sm[tid] = 0;
    __syncthreads();
    const int2* bp = bkt + n0;
    for (int i = tid; i < m; i += 1024) atomicAdd(&sm[bp[i].y - node0], 1);
    __syncthreads();
    int v = sm[tid];
    for (int d = 1; d < 1024; d <<= 1) {
        int t = (tid >= d) ? sm[tid - d] : 0;
        __syncthreads();
        sm[tid] += t;
        __syncthreads();
    }
    int excl = sm[tid] - v;
    int node = node0 + tid;
    if (node < N) csr_off[node] = n0 + excl;
    __syncthreads();
    sm[tid] = excl;
    __syncthreads();
    for (int i = tid; i < m; i += 1024) {
        int2 sd = bp[i];
        int r = atomicAdd(&sm[sd.y - node0], 1);
        csr[n0 + r] = sd.x;
    }
}

// ---------------- Layer 1: GATConv(3, 16, heads=4) ----------------

__global__ __launch_bounds__(256) void k_l1_transform(const float* __restrict__ x, const float* __restrict__ W1,
                                                      const float* __restrict__ att_s, const float* __restrict__ att_d,
                                                      float4* __restrict__ x4, float* __restrict__ as1,
                                                      float* __restrict__ ad1, int N) {
    int tid = threadIdx.x;
    int node = blockIdx.x * 4 + (tid >> 6);
    if (node >= N) return;
    int lane = tid & 63;
    float x0 = x[node * 3 + 0];
    float x1 = x[node * 3 + 1];
    float x2 = x[node * 3 + 2];
    float h = x0 * W1[lane] + x1 * W1[64 + lane] + x2 * W1[128 + lane];
    if (lane == 0) x4[node] = make_float4(x0, x1, x2, 0.f);
    float ts = h * att_s[lane];
    float td = h * att_d[lane];
    for (int m = 8; m >= 1; m >>= 1) { ts += __shfl_xor(ts, m); td += __shfl_xor(td, m); }
    if ((lane & 15) == 0) {
        as1[node * 4 + (lane >> 4)] = ts;
        ad1[node * 4 + (lane >> 4)] = td;
    }
}

// Edge-parallel: 16 lanes per node; accumulate per-head weighted x-3vec + denom, butterfly-reduce.
__global__ __launch_bounds__(256) void k_l1_agg(const float4* __restrict__ x4, const float4* __restrict__ as4,
                                                const float4* __restrict__ ad4p, const int* __restrict__ off,
                                                const int* __restrict__ csr, const float* __restrict__ W1,
                                                const float* __restrict__ b1,
                                                float* __restrict__ x1, int N) {
    int tid = threadIdx.x;
    int node = blockIdx.x * 16 + (tid >> 4);
    if (node >= N) return;
    int sl = tid & 15;
    int lane = tid & 63;
    int lb = lane & 48;

    float4 ad = ad4p[node];
    int e0 = off[node], e1 = off[node + 1];

    float v[16];
#pragma unroll
    for (int i = 0; i < 16; ++i) v[i] = 0.f;

    for (int jj = e0 + sl; jj < e1; jj += 16) {
        int s = csr[jj];
        float4 a = as4[s];
        float4 xv = x4[s];
        float z0 = a.x + ad.x, z1 = a.y + ad.y, z2 = a.z + ad.z, z3 = a.w + ad.w;
        z0 = (z0 > 0.f) ? z0 : 0.2f * z0;
        z1 = (z1 > 0.f) ? z1 : 0.2f * z1;
        z2 = (z2 > 0.f) ? z2 : 0.2f * z2;
        z3 = (z3 > 0.f) ? z3 : 0.2f * z3;
        float w0 = __expf(z0), w1 = __expf(z1), w2 = __expf(z2), w3 = __expf(z3);
        v[0] += w0 * xv.x; v[1] += w0 * xv.y; v[2]  += w0 * xv.z; v[3]  += w0;
        v[4] += w1 * xv.x; v[5] += w1 * xv.y; v[6]  += w1 * xv.z; v[7]  += w1;
        v[8] += w2 * xv.x; v[9] += w2 * xv.y; v[10] += w2 * xv.z; v[11] += w2;
        v[12] += w3 * xv.x; v[13] += w3 * xv.y; v[14] += w3 * xv.z; v[15] += w3;
    }

#pragma unroll
    for (int d = 8; d >= 1; d >>= 1) {
#pragma unroll
        for (int i = 0; i < 16; ++i) {
            if (i < d) {
                float a = v[i], b = v[i + d];
                float send = (sl & d) ? a : b;
                float recv = __shfl_xor(send, d);
                v[i] = ((sl & d) ? b : a) + recv;
            }
        }
    }
    float r = v[0];

    float agx[4], agy[4], agz[4], dn[4];
#pragma unroll
    for (int h = 0; h < 4; ++h) {
        agx[h] = __shfl(r, lb + 4 * h + 0);
        agy[h] = __shfl(r, lb + 4 * h + 1);
        agz[h] = __shfl(r, lb + 4 * h + 2);
        dn[h]  = __shfl(r, lb + 4 * h + 3);
    }

    {
        float4 a = as4[node];
        float4 xv = x4[node];
        float z0 = a.x + ad.x, z1 = a.y + ad.y, z2 = a.z + ad.z, z3 = a.w + ad.w;
        z0 = (z0 > 0.f) ? z0 : 0.2f * z0;
        z1 = (z1 > 0.f) ? z1 : 0.2f * z1;
        z2 = (z2 > 0.f) ? z2 : 0.2f * z2;
        z3 = (z3 > 0.f) ? z3 : 0.2f * z3;
        float w0 = __expf(z0), w1 = __expf(z1), w2 = __expf(z2), w3 = __expf(z3);
        agx[0] += w0 * xv.x; agy[0] += w0 * xv.y; agz[0] += w0 * xv.z; dn[0] += w0;
        agx[1] += w1 * xv.x; agy[1] += w1 * xv.y; agz[1] += w1 * xv.z; dn[1] += w1;
        agx[2] += w2 * xv.x; agy[2] += w2 * xv.y; agz[2] += w2 * xv.z; dn[2] += w2;
        agx[3] += w3 * xv.x; agy[3] += w3 * xv.y; agz[3] += w3 * xv.z; dn[3] += w3;
    }

#pragma unroll
    for (int h = 0; h < 4; ++h) {
        int j = h * 16 + sl;
        float inv = 1.f / (dn[h] + 1e-16f);
        float o = (agx[h] * W1[j] + agy[h] * W1[64 + j] + agz[h] * W1[128 + j]) * inv + b1[j];
        x1[(size_t)node * 64 + j] = (o > 0.f) ? o : 0.f;
    }
}

// ---------------- Layer 2: GATv2Conv(64, 16, heads=2) ----------------

// 64 nodes per 256-thread block; thread = 4-node x 4-col register tile of [hl|hr]
__global__ __launch_bounds__(256) void k_l2_transform(const float* __restrict__ x1,
                                                      const float* __restrict__ W2l, const float* __restrict__ b2l,
                                                      const float* __restrict__ W2r, const float* __restrict__ b2r,
                                                      unsigned short* __restrict__ hlb, float* __restrict__ hr, int N) {
    __shared__ float xs[64 * 68];   // row stride 68: per-wave broadcast rows hit banks {0,4,8,12}
    int t = threadIdx.x;
    int node0 = blockIdx.x * 64;
    int nrem = N - node0; if (nrem > 64) nrem = 64;
    const float4* xg = (const float4*)x1;
#pragma unroll
    for (int it = 0; it < 4; ++it) {
        int id = it * 256 + t;
        int row = id >> 4, c4 = id & 15;
        float4 v = make_float4(0.f, 0.f, 0.f, 0.f);
        if (row < nrem) v = xg[(size_t)(node0 + row) * 16 + c4];
        *(float4*)&xs[row * 68 + c4 * 4] = v;
    }
    __syncthreads();
    int nt = t >> 4;              // node sub-tile 0..15 -> rows nt + i*16
    int jt = t & 15;              // col tile; jt<8 -> hl cols, else hr cols
    int jq = jt & 7;              // col-quad within the selected matrix
    int jc = jq * 4;
    const float4* W4 = (const float4*)((jt < 8) ? W2l : W2r);
    const float4* B4 = (const float4*)((jt < 8) ? b2l : b2r);
    float4 bb = B4[jq];
    float4 acc[4];
#pragma unroll
    for (int i = 0; i < 4; ++i) acc[i] = bb;
#pragma unroll
    for (int k4 = 0; k4 < 16; ++k4) {
        float4 w0 = W4[(k4 * 4 + 0) * 8 + jq];
        float4 w1 = W4[(k4 * 4 + 1) * 8 + jq];
        float4 w2 = W4[(k4 * 4 + 2) * 8 + jq];
        float4 w3 = W4[(k4 * 4 + 3) * 8 + jq];
#pragma unroll
        for (int i = 0; i < 4; ++i) {
            float4 xv = *(const float4*)&xs[(nt + i * 16) * 68 + k4 * 4];
            acc[i].x += xv.x * w0.x + xv.y * w1.x + xv.z * w2.x + xv.w * w3.x;
            acc[i].y += xv.x * w0.y + xv.y * w1.y + xv.z * w2.y + xv.w * w3.y;
            acc[i].z += xv.x * w0.z + xv.y * w1.z + xv.z * w2.z + xv.w * w3.z;
            acc[i].w += xv.x * w0.w + xv.y * w1.w + xv.z * w2.w + xv.w * w3.w;
        }
    }
#pragma unroll
    for (int i = 0; i < 4; ++i) {
        int row = nt + i * 16;
        if (row < nrem) {
            size_t node = node0 + row;
            if (jt < 8) {
                uint2 p;
                p.x = (unsigned)f2us(acc[i].x) | ((unsigned)f2us(acc[i].y) << 16);
                p.y = (unsigned)f2us(acc[i].z) | ((unsigned)f2us(acc[i].w) << 16);
                *(uint2*)&hlb[node * 32 + jc] = p;
            } else {
                *(float4*)&hr[node * 32 + jc] = acc[i];
            }
        }
    }
}

// 32 lanes per node (2 nodes per wave); lane = head*16 + chan; 4-deep unroll
__global__ __launch_bounds__(256) void k_l2_agg(const unsigned short* __restrict__ hlb, const float* __restrict__ hr,
                                                const float* __restrict__ att2, const float* __restrict__ b2,
                                                const int* __restrict__ off, const int* __restrict__ csr,
                                                float* __restrict__ x2, int N) {
    int tid = threadIdx.x;
    int node = blockIdx.x * 8 + (tid >> 5);
    if (node >= N) return;
    int sl = tid & 31;
    float hrd = hr[(size_t)node * 32 + sl];
    float a2 = att2[sl];
    int e0 = off[node], e1 = off[node + 1];
    float hsf = us2f(hlb[(size_t)node * 32 + sl]);
    float e = hsf + hrd;
    e = (e > 0.f) ? e : 0.2f * e;
    float t = e * a2;
    t += __shfl_xor(t, 1); t += __shfl_xor(t, 2);
    t += __shfl_xor(t, 4); t += __shfl_xor(t, 8);
    float w = __expf(t);
    float den0 = w, den1 = 0.f, den2 = 0.f, den3 = 0.f;
    float acc0 = w * hsf, acc1 = 0.f, acc2 = 0.f, acc3 = 0.f;
    int jj = e0;
    for (; jj + 4 <= e1; jj += 4) {
        int s0 = csr[jj], s1 = csr[jj + 1], s2 = csr[jj + 2], s3 = csr[jj + 3];
        float h0 = us2f(hlb[(size_t)s0 * 32 + sl]);
        float h1v = us2f(hlb[(size_t)s1 * 32 + sl]);
        float h2v = us2f(hlb[(size_t)s2 * 32 + sl]);
        float h3v = us2f(hlb[(size_t)s3 * 32 + sl]);
        float e0v = h0 + hrd, e1v = h1v + hrd, e2v = h2v + hrd, e3v = h3v + hrd;
        e0v = (e0v > 0.f) ? e0v : 0.2f * e0v;
        e1v = (e1v > 0.f) ? e1v : 0.2f * e1v;
        e2v = (e2v > 0.f) ? e2v : 0.2f * e2v;
        e3v = (e3v > 0.f) ? e3v : 0.2f * e3v;
        float t0 = e0v * a2, t1 = e1v * a2, t2 = e2v * a2, t3 = e3v * a2;
        t0 += __shfl_xor(t0, 1); t1 += __shfl_xor(t1, 1); t2 += __shfl_xor(t2, 1); t3 += __shfl_xor(t3, 1);
        t0 += __shfl_xor(t0, 2); t1 += __shfl_xor(t1, 2); t2 += __shfl_xor(t2, 2); t3 += __shfl_xor(t3, 2);
        t0 += __shfl_xor(t0, 4); t1 += __shfl_xor(t1, 4); t2 += __shfl_xor(t2, 4); t3 += __shfl_xor(t3, 4);
        t0 += __shfl_xor(t0, 8); t1 += __shfl_xor(t1, 8); t2 += __shfl_xor(t2, 8); t3 += __shfl_xor(t3, 8);
        float w0 = __expf(t0), w1 = __expf(t1), w2 = __expf(t2), w3 = __expf(t3);
        den0 += w0; acc0 += w0 * h0;
        den1 += w1; acc1 += w1 * h1v;
        den2 += w2; acc2 += w2 * h2v;
        den3 += w3; acc3 += w3 * h3v;
    }
    for (; jj < e1; ++jj) {
        int s0 = csr[jj];
        float h0 = us2f(hlb[(size_t)s0 * 32 + sl]);
        float e0v = h0 + hrd;
        e0v = (e0v > 0.f) ? e0v : 0.2f * e0v;
        float t0 = e0v * a2;
        t0 += __shfl_xor(t0, 1); t0 += __shfl_xor(t0, 2);
        t0 += __shfl_xor(t0, 4); t0 += __shfl_xor(t0, 8);
        float w0 = __expf(t0);
        den0 += w0; acc0 += w0 * h0;
    }
    x2[(size_t)node * 32 + sl] = (acc0 + acc1 + acc2 + acc3) / (den0 + den1 + den2 + den3 + 1e-16f) + b2[sl];
}

// ---------------- Layer 3: TransformerConv(32, 7, heads=1) ----------------

// pack Wq/Wsk/Wk/Wv -> Wcat[32][32] whose output row is {q0..6,0,sk0..6,0,k0..6,0,v0..6,0}
__global__ __launch_bounds__(1024) void k_l3_wcat(const float* __restrict__ Wq, const float* __restrict__ bq,
                                                  const float* __restrict__ Wk, const float* __restrict__ bk,
                                                  const float* __restrict__ Wv, const float* __restrict__ bv,
                                                  const float* __restrict__ Ws, const float* __restrict__ bs,
                                                  float* __restrict__ Wcat, float* __restrict__ bcat) {
    int t = threadIdx.x;
    int c = t & 31, g = c >> 3, cc = c & 7;
    const float* Wg = (g == 0) ? Wq : (g == 1) ? Ws : (g == 2) ? Wk : Wv;
    const float* Bg = (g == 0) ? bq : (g == 1) ? bs : (g == 2) ? bk : bv;
    int kk = t >> 5;
    Wcat[t] = (cc < 7) ? Wg[kk * 7 + cc] : 0.f;
    if (t < 32) bcat[t] = (cc < 7) ? Bg[cc] : 0.f;
}

// 128 nodes per 256-thread block; thread = 4-node x 4-col tile; cols map to QS|KV directly
__global__ __launch_bounds__(256) void k_l3_transform(const float* __restrict__ x2,
                                                      const float4* __restrict__ Wc4, const float4* __restrict__ bc4,
                                                      float* __restrict__ QS, float* __restrict__ KV, int N) {
    __shared__ float xs[128 * 36];  // stride 36: 8 broadcast rows/wave hit banks {0,4,..,28}
    int t = threadIdx.x;
    int node0 = blockIdx.x * 128;
    int nrem = N - node0; if (nrem > 128) nrem = 128;
    const float4* xg = (const float4*)x2;
#pragma unroll
    for (int it = 0; it < 4; ++it) {
        int id = it * 256 + t;
        int row = id >> 3, c4 = id & 7;
        float4 v = make_float4(0.f, 0.f, 0.f, 0.f);
        if (row < nrem) v = xg[(size_t)(node0 + row) * 8 + c4];
        *(float4*)&xs[row * 36 + c4 * 4] = v;
    }
    __syncthreads();
    int nt = t >> 3;              // 0..31 -> rows nt + i*32
    int jt = t & 7;               // col quad 0..7 of out32
    float4 bb = bc4[jt];
    float4 acc[4];
#pragma unroll
    for (int i = 0; i < 4; ++i) acc[i] = bb;
#pragma unroll
    for (int k4 = 0; k4 < 8; ++k4) {
        float4 w0 = Wc4[(k4 * 4 + 0) * 8 + jt];
        float4 w1 = Wc4[(k4 * 4 + 1) * 8 + jt];
        float4 w2 = Wc4[(k4 * 4 + 2) * 8 + jt];
        float4 w3 = Wc4[(k4 * 4 + 3) * 8 + jt];
#pragma unroll
        for (int i = 0; i < 4; ++i) {
            float4 xv = *(const float4*)&xs[(nt + i * 32) * 36 + k4 * 4];
            acc[i].x += xv.x * w0.x + xv.y * w1.x + xv.z * w2.x + xv.w * w3.x;
            acc[i].y += xv.x * w0.y + xv.y * w1.y + xv.z * w2.y + xv.w * w3.y;
            acc[i].z += xv.x * w0.z + xv.y * w1.z + xv.z * w2.z + xv.w * w3.z;
            acc[i].w += xv.x * w0.w + xv.y * w1.w + xv.z * w2.w + xv.w * w3.w;
        }
    }
#pragma unroll
    for (int i = 0; i < 4; ++i) {
        int row = nt + i * 32;
        if (row < nrem) {
            size_t node = node0 + row;
            float* dst = (jt < 4) ? (QS + node * 16 + jt * 4) : (KV + node * 16 + (jt - 4) * 4);
            *(float4*)dst = acc[i];
        }
    }
}

// 8 lanes per node; K and V of one source share a cache line; 2-deep unroll
__global__ __launch_bounds__(256) void k_l3_agg(const float* __restrict__ QS, const float* __restrict__ KV,
                                                const int* __restrict__ off, const int* __restrict__ csr,
                                                float* __restrict__ out, int N) {
    int tid = threadIdx.x;
    int node = blockIdx.x * 32 + (tid >> 3);
    if (node >= N) return;
    int sl = tid & 7;
    bool act = sl < 7;
    float qd = act ? QS[(size_t)node * 16 + sl] : 0.f;
    float acc0 = 0.f, den0 = 0.f, acc1 = 0.f, den1 = 0.f;
    int e0 = off[node], e1 = off[node + 1];
    const float scale = 0.3779644730092272f;  // 1/sqrt(7)
    int jj = e0;
    for (; jj + 2 <= e1; jj += 2) {
        int s0 = csr[jj], s1 = csr[jj + 1];
        float k0 = act ? KV[(size_t)s0 * 16 + sl] : 0.f;
        float k1 = act ? KV[(size_t)s1 * 16 + sl] : 0.f;
        float v0 = act ? KV[(size_t)s0 * 16 + 8 + sl] : 0.f;
        float v1 = act ? KV[(size_t)s1 * 16 + 8 + sl] : 0.f;
        float t0 = qd * k0, t1 = qd * k1;
        t0 += __shfl_xor(t0, 1); t1 += __shfl_xor(t1, 1);
        t0 += __shfl_xor(t0, 2); t1 += __shfl_xor(t1, 2);
        t0 += __shfl_xor(t0, 4); t1 += __shfl_xor(t1, 4);
        float w0 = __expf(t0 * scale), w1 = __expf(t1 * scale);
        den0 += w0; acc0 += w0 * v0;
        den1 += w1; acc1 += w1 * v1;
    }
    if (jj < e1) {
        int s0 = csr[jj];
        float k0 = act ? KV[(size_t)s0 * 16 + sl] : 0.f;
        float v0 = act ? KV[(size_t)s0 * 16 + 8 + sl] : 0.f;
        float t0 = qd * k0;
        t0 += __shfl_xor(t0, 1); t0 += __shfl_xor(t0, 2); t0 += __shfl_xor(t0, 4);
        float w0 = __expf(t0 * scale);
        den0 += w0; acc0 += w0 * v0;
    }
    if (act) out[(size_t)node * 7 + sl] = (acc0 + acc1) / (den0 + den1 + 1e-16f)
                                          + QS[(size_t)node * 16 + 8 + sl];
}

// ---------------- launcher ----------------

extern "C" void kernel_launch(void* const* d_in, const int* in_sizes, int n_in,
                              void* d_out, int out_size, void* d_ws, size_t ws_size,
                              hipStream_t stream) {
    const int* ei = (const int*)d_in[1];
    float* out = (float*)d_out;

    int N = in_sizes[0] / 3;
    int E = in_sizes[1] / 2;
    int NB = (N + 1023) >> 10;   // assumed <= 256 (N <= 262144)

    char* ws = (char*)d_ws;
    size_t o = 0;
    auto take = [&](size_t bytes) -> char* {
        char* p = ws + o;
        o = (o + bytes + 255) & ~(size_t)255;
        return p;
    };
    int*   flags   = (int*)take(64);
    int total_f = 0;
    for (int i = 0; i < 20; ++i) if (i != 1) total_f += in_sizes[i];
    float* canon   = (float*)take((size_t)total_f * 4);
    float* Wcat    = (float*)take(32 * 32 * 4);
    float* bcat    = (float*)take(32 * 4);
    int*   csr_off = (int*)take((size_t)(N + 1) * 4);
    int*   bcnt    = (int*)take(256 * 4);
    int*   bbase   = (int*)take(257 * 4);
    int*   bcur    = (int*)take(256 * 4);
    int*   csr     = (int*)take((size_t)E * 4);
    float* bufA    = (float*)take((size_t)N * 64 * 4);  // x4 -> hlb|hr -> QS|KV
    float* as1     = (float*)take((size_t)N * 4 * 4);
    float* ad1     = (float*)take((size_t)N * 4 * 4);
    float* bufB    = (float*)take((size_t)N * 64 * 4);  // bkt -> x1 -> x2
    (void)ws_size; (void)n_in; (void)out_size;

    CvtArgs ca;
    const float* cp[20];
    {
        int off_ = 0, k = 0;
        for (int i = 0; i < 20; ++i) {
            if (i == 1) { cp[i] = nullptr; continue; }
            ca.p[k] = d_in[i];
            ca.sz[k] = in_sizes[i];
            cp[i] = canon + off_;
            off_ += in_sizes[i];
            ++k;
        }
    }

    hipMemsetAsync(bcnt, 0, 256 * 4, stream);
    k_detect<<<1, 256, 0, stream>>>((const unsigned short*)d_in[0], ei, flags);
    k_convert<<<(total_f + 255) / 256, 256, 0, stream>>>(ca, flags, canon, total_f);
    k_l3_wcat<<<1, 1024, 0, stream>>>(cp[12], cp[13], cp[14], cp[15], cp[16], cp[17],
                                      cp[18], cp[19], Wcat, bcat);

    int2* bkt = (int2*)bufB;
    int gb = (E + 4095) / 4096;
    k_bhist<<<gb, 1024, 0, stream>>>(ei, flags, bcnt, E, NB);
    k_bscan<<<1, 256, 0, stream>>>(bcnt, bbase, bcur, csr_off, NB, N, E);
    k_bscatter<<<gb, 1024, 0, stream>>>(ei, flags, bcur, bkt, E, NB);
    k_bbuild<<<NB, 1024, 0, stream>>>(bkt, bbase, csr_off, csr, N);

    float4* x4 = (float4*)bufA;                                  // N*16B = 1.6 MB, L2-resident
    k_l1_transform<<<(N + 3) / 4, 256, 0, stream>>>(cp[0], cp[2], cp[3], cp[4], x4, as1, ad1, N);
    float* x1 = bufB;
    k_l1_agg<<<(N + 15) / 16, 256, 0, stream>>>(x4, (const float4*)as1, (const float4*)ad1,
                                                csr_off, csr, cp[2], cp[5], x1, N);

    unsigned short* hlb = (unsigned short*)bufA;                 // N*32 bf16 = 6.4 MB
    float* hr = bufA + (size_t)N * 16;
    k_l2_transform<<<(N + 63) / 64, 256, 0, stream>>>(x1, cp[6], cp[7], cp[8], cp[9], hlb, hr, N);
    float* x2 = bufB;
    k_l2_agg<<<(N + 7) / 8, 256, 0, stream>>>(hlb, hr, cp[10], cp[11], csr_off, csr, x2, N);

    float* QS = bufA;                                            // N*16 floats
    float* KV = bufA + (size_t)N * 16;                           // N*16 floats
    k_l3_transform<<<(N + 127) / 128, 256, 0, stream>>>(x2, (const float4*)Wcat, (const float4*)bcat,
                                                        QS, KV, N);
    k_l3_agg<<<(N + 31) / 32, 256, 0, stream>>>(QS, KV, csr_off, csr, out, N);
}

// Round 9
// 356.524 us; speedup vs baseline: 1.4059x; 1.0178x over previous
//
#include <hip/hip_runtime.h>
#include <hip/hip_bf16.h>

typedef __hip_bfloat16 bf16;

static __device__ __forceinline__ float us2f(unsigned short u) {
    union { unsigned int i; float f; } c; c.i = ((unsigned int)u) << 16; return c.f;
}
static __device__ __forceinline__ unsigned short f2us(float f) {
    union { float f; unsigned int i; } c; c.f = f;
    unsigned int r = c.i + 0x7FFF + ((c.i >> 16) & 1);   // round-to-nearest-even
    return (unsigned short)(r >> 16);
}

// ---------------- dtype probe + canonicalization ----------------

__global__ __launch_bounds__(256) void k_detect(const unsigned short* __restrict__ xr,
                                                const int* __restrict__ er,
                                                int* __restrict__ flags) {
    __shared__ int sbad, snz;
    int tid = threadIdx.x;
    if (tid == 0) { sbad = 0; snz = 0; }
    __syncthreads();
    int bad = 0, nz = 0;
    for (int i = tid; i < 1024; i += 256) {
        unsigned short w = xr[2 * i];
        int ex = (w >> 7) & 0xFF;
        if (ex < 110 || ex > 135) bad++;
        if (er[2 * i + 1] != 0) nz++;
    }
    atomicAdd(&sbad, bad);
    atomicAdd(&snz, nz);
    __syncthreads();
    if (tid == 0) {
        flags[0] = (sbad > 256) ? 1 : 0;
        flags[1] = (snz < 512) ? 1 : 0;
    }
}

struct CvtArgs { const void* p[19]; int sz[19]; };

__global__ __launch_bounds__(256) void k_convert(CvtArgs a, const int* __restrict__ flags,
                                                 float* __restrict__ dst, int total) {
    int t = blockIdx.x * 256 + threadIdx.x;
    if (t >= total) return;
    int isf32 = flags[0];
    int base = 0, seg = -1, off = 0;
#pragma unroll
    for (int i = 0; i < 19; i++) {
        if (seg < 0 && t < base + a.sz[i]) { seg = i; off = t - base; }
        base += a.sz[i];
    }
    const void* p = a.p[seg];
    float v = isf32 ? ((const float*)p)[off] : __bfloat162float(((const bf16*)p)[off]);
    dst[t] = v;
}

static __device__ __forceinline__ int ld_edge(const int* er, size_t i, int idx64) {
    return idx64 ? er[2 * i] : er[i];
}

// ---------------- bucketed CSR build ----------------
// bucket b = dst >> 10 (1024 nodes per bucket), NB <= 256 assumed (N <= 262144)

__global__ __launch_bounds__(1024) void k_bhist(const int* __restrict__ er, const int* __restrict__ flags,
                                                int* __restrict__ bcnt, int E, int NB) {
    __shared__ int cnt[256];
    int tid = threadIdx.x;
    if (tid < 256) cnt[tid] = 0;
    __syncthreads();
    int idx64 = flags[1];
    int base = blockIdx.x * 4096 + tid;
#pragma unroll
    for (int k = 0; k < 4; ++k) {
        int e = base + k * 1024;
        if (e < E) {
            int d = ld_edge(er, (size_t)E + e, idx64);
            atomicAdd(&cnt[d >> 10], 1);
        }
    }
    __syncthreads();
    if (tid < NB && cnt[tid]) atomicAdd(&bcnt[tid], cnt[tid]);
}

__global__ __launch_bounds__(256) void k_bscan(const int* __restrict__ bcnt, int* __restrict__ bbase,
                                               int* __restrict__ bcur, int* __restrict__ csr_off,
                                               int NB, int N, int E) {
    __shared__ int sm[256];
    int tid = threadIdx.x;
    int v = (tid < NB) ? bcnt[tid] : 0;
    sm[tid] = v;
    __syncthreads();
    for (int d = 1; d < 256; d <<= 1) {
        int t = (tid >= d) ? sm[tid - d] : 0;
        __syncthreads();
        sm[tid] += t;
        __syncthreads();
    }
    int excl = sm[tid] - v;
    if (tid < NB) { bbase[tid] = excl; bcur[tid] = excl; }
    if (tid == 0) { bbase[NB] = E; csr_off[N] = E; }
}

__global__ __launch_bounds__(1024) void k_bscatter(const int* __restrict__ er, const int* __restrict__ flags,
                                                   int* __restrict__ bcur, int2* __restrict__ bkt,
                                                   int E, int NB) {
    __shared__ int cnt[256];
    __shared__ int res[256];
    int tid = threadIdx.x;
    if (tid < 256) cnt[tid] = 0;
    __syncthreads();
    int idx64 = flags[1];
    int base = blockIdx.x * 4096 + tid;
    int sv[4], dv[4], bv[4];
    bool val[4];
#pragma unroll
    for (int k = 0; k < 4; ++k) {
        int e = base + k * 1024;
        val[k] = (e < E);
        if (val[k]) {
            sv[k] = ld_edge(er, (size_t)e, idx64);
            dv[k] = ld_edge(er, (size_t)E + e, idx64);
            bv[k] = dv[k] >> 10;
            atomicAdd(&cnt[bv[k]], 1);
        }
    }
    __syncthreads();
    if (tid < NB) {
        int c = cnt[tid];
        res[tid] = c ? atomicAdd(&bcur[tid], c) : 0;
        cnt[tid] = 0;
    }
    __syncthreads();
#pragma unroll
    for (int k = 0; k < 4; ++k) {
        if (val[k]) {
            int r = atomicAdd(&cnt[bv[k]], 1);
            bkt[res[bv[k]] + r] = make_int2(sv[k], dv[k]);
        }
    }
}

__global__ __launch_bounds__(1024) void k_bbuild(const int2* __restrict__ bkt, const int* __restrict__ bbase,
                                                 int* __restrict__ csr_off, int* __restrict__ csr, int N) {
    __shared__ int sm[1024];
    int b = blockIdx.x, tid = threadIdx.x;
    int node0 = b << 10;
    int n0 = bbase[b], n1 = bbase[b + 1];
    int m = n1 - n0;
    sm[tid] = 0;
    __syncthreads();
    const int2* bp = bkt + n0;
    for (int i = tid; i < m; i += 1024) atomicAdd(&sm[bp[i].y - node0], 1);
    __syncthreads();
    int v = sm[tid];
    for (int d = 1; d < 1024; d <<= 1) {
        int t = (tid >= d) ? sm[tid - d] : 0;
        __syncthreads();
        sm[tid] += t;
        __syncthreads();
    }
    int excl = sm[tid] - v;
    int node = node0 + tid;
    if (node < N) csr_off[node] = n0 + excl;
    __syncthreads();
    sm[tid] = excl;
    __syncthreads();
    for (int i = tid; i < m; i += 1024) {
        int2 sd = bp[i];
        int r = atomicAdd(&sm[sd.y - node0], 1);
        csr[n0 + r] = sd.x;
    }
}

// ---------------- Layer 1: GATConv(3, 16, heads=4) ----------------

__global__ __launch_bounds__(256) void k_l1_transform(const float* __restrict__ x, const float* __restrict__ W1,
                                                      const float* __restrict__ att_s, const float* __restrict__ att_d,
                                                      float4* __restrict__ x4, float* __restrict__ as1,
                                                      float* __restrict__ ad1, int N) {
    int tid = threadIdx.x;
    int node = blockIdx.x * 4 + (tid >> 6);
    if (node >= N) return;
    int lane = tid & 63;
    float x0 = x[node * 3 + 0];
    float x1 = x[node * 3 + 1];
    float x2 = x[node * 3 + 2];
    float h = x0 * W1[lane] + x1 * W1[64 + lane] + x2 * W1[128 + lane];
    if (lane == 0) x4[node] = make_float4(x0, x1, x2, 0.f);
    float ts = h * att_s[lane];
    float td = h * att_d[lane];
    for (int m = 8; m >= 1; m >>= 1) { ts += __shfl_xor(ts, m); td += __shfl_xor(td, m); }
    if ((lane & 15) == 0) {
        as1[node * 4 + (lane >> 4)] = ts;
        ad1[node * 4 + (lane >> 4)] = td;
    }
}

// Edge-parallel: 16 lanes per node; accumulate per-head weighted x-3vec + denom, butterfly-reduce.
__global__ __launch_bounds__(256) void k_l1_agg(const float4* __restrict__ x4, const float4* __restrict__ as4,
                                                const float4* __restrict__ ad4p, const int* __restrict__ off,
                                                const int* __restrict__ csr, const float* __restrict__ W1,
                                                const float* __restrict__ b1,
                                                float* __restrict__ x1, int N) {
    int tid = threadIdx.x;
    int node = blockIdx.x * 16 + (tid >> 4);
    if (node >= N) return;
    int sl = tid & 15;
    int lane = tid & 63;
    int lb = lane & 48;

    float4 ad = ad4p[node];
    int e0 = off[node], e1 = off[node + 1];

    float v[16];
#pragma unroll
    for (int i = 0; i < 16; ++i) v[i] = 0.f;

    for (int jj = e0 + sl; jj < e1; jj += 16) {
        int s = csr[jj];
        float4 a = as4[s];
        float4 xv = x4[s];
        float z0 = a.x + ad.x, z1 = a.y + ad.y, z2 = a.z + ad.z, z3 = a.w + ad.w;
        z0 = (z0 > 0.f) ? z0 : 0.2f * z0;
        z1 = (z1 > 0.f) ? z1 : 0.2f * z1;
        z2 = (z2 > 0.f) ? z2 : 0.2f * z2;
        z3 = (z3 > 0.f) ? z3 : 0.2f * z3;
        float w0 = __expf(z0), w1 = __expf(z1), w2 = __expf(z2), w3 = __expf(z3);
        v[0] += w0 * xv.x; v[1] += w0 * xv.y; v[2]  += w0 * xv.z; v[3]  += w0;
        v[4] += w1 * xv.x; v[5] += w1 * xv.y; v[6]  += w1 * xv.z; v[7]  += w1;
        v[8] += w2 * xv.x; v[9] += w2 * xv.y; v[10] += w2 * xv.z; v[11] += w2;
        v[12] += w3 * xv.x; v[13] += w3 * xv.y; v[14] += w3 * xv.z; v[15] += w3;
    }

#pragma unroll
    for (int d = 8; d >= 1; d >>= 1) {
#pragma unroll
        for (int i = 0; i < 16; ++i) {
            if (i < d) {
                float a = v[i], b = v[i + d];
                float send = (sl & d) ? a : b;
                float recv = __shfl_xor(send, d);
                v[i] = ((sl & d) ? b : a) + recv;
            }
        }
    }
    float r = v[0];

    float agx[4], agy[4], agz[4], dn[4];
#pragma unroll
    for (int h = 0; h < 4; ++h) {
        agx[h] = __shfl(r, lb + 4 * h + 0);
        agy[h] = __shfl(r, lb + 4 * h + 1);
        agz[h] = __shfl(r, lb + 4 * h + 2);
        dn[h]  = __shfl(r, lb + 4 * h + 3);
    }

    {
        float4 a = as4[node];
        float4 xv = x4[node];
        float z0 = a.x + ad.x, z1 = a.y + ad.y, z2 = a.z + ad.z, z3 = a.w + ad.w;
        z0 = (z0 > 0.f) ? z0 : 0.2f * z0;
        z1 = (z1 > 0.f) ? z1 : 0.2f * z1;
        z2 = (z2 > 0.f) ? z2 : 0.2f * z2;
        z3 = (z3 > 0.f) ? z3 : 0.2f * z3;
        float w0 = __expf(z0), w1 = __expf(z1), w2 = __expf(z2), w3 = __expf(z3);
        agx[0] += w0 * xv.x; agy[0] += w0 * xv.y; agz[0] += w0 * xv.z; dn[0] += w0;
        agx[1] += w1 * xv.x; agy[1] += w1 * xv.y; agz[1] += w1 * xv.z; dn[1] += w1;
        agx[2] += w2 * xv.x; agy[2] += w2 * xv.y; agz[2] += w2 * xv.z; dn[2] += w2;
        agx[3] += w3 * xv.x; agy[3] += w3 * xv.y; agz[3] += w3 * xv.z; dn[3] += w3;
    }

#pragma unroll
    for (int h = 0; h < 4; ++h) {
        int j = h * 16 + sl;
        float inv = 1.f / (dn[h] + 1e-16f);
        float o = (agx[h] * W1[j] + agy[h] * W1[64 + j] + agz[h] * W1[128 + j]) * inv + b1[j];
        x1[(size_t)node * 64 + j] = (o > 0.f) ? o : 0.f;
    }
}

// ---------------- Layer 2: GATv2Conv(64, 16, heads=2) ----------------

// 64 nodes per 256-thread block; thread = 4-node x 4-col register tile of [hl|hr]
__global__ __launch_bounds__(256) void k_l2_transform(const float* __restrict__ x1,
                                                      const float* __restrict__ W2l, const float* __restrict__ b2l,
                                                      const float* __restrict__ W2r, const float* __restrict__ b2r,
                                                      unsigned short* __restrict__ hlb, float* __restrict__ hr, int N) {
    __shared__ float xs[64 * 68];   // row stride 68: per-wave broadcast rows hit banks {0,4,8,12}
    int t = threadIdx.x;
    int node0 = blockIdx.x * 64;
    int nrem = N - node0; if (nrem > 64) nrem = 64;
    const float4* xg = (const float4*)x1;
#pragma unroll
    for (int it = 0; it < 4; ++it) {
        int id = it * 256 + t;
        int row = id >> 4, c4 = id & 15;
        float4 v = make_float4(0.f, 0.f, 0.f, 0.f);
        if (row < nrem) v = xg[(size_t)(node0 + row) * 16 + c4];
        *(float4*)&xs[row * 68 + c4 * 4] = v;
    }
    __syncthreads();
    int nt = t >> 4;
    int jt = t & 15;
    int jq = jt & 7;
    int jc = jq * 4;
    const float4* W4 = (const float4*)((jt < 8) ? W2l : W2r);
    const float4* B4 = (const float4*)((jt < 8) ? b2l : b2r);
    float4 bb = B4[jq];
    float4 acc[4];
#pragma unroll
    for (int i = 0; i < 4; ++i) acc[i] = bb;
#pragma unroll
    for (int k4 = 0; k4 < 16; ++k4) {
        float4 w0 = W4[(k4 * 4 + 0) * 8 + jq];
        float4 w1 = W4[(k4 * 4 + 1) * 8 + jq];
        float4 w2 = W4[(k4 * 4 + 2) * 8 + jq];
        float4 w3 = W4[(k4 * 4 + 3) * 8 + jq];
#pragma unroll
        for (int i = 0; i < 4; ++i) {
            float4 xv = *(const float4*)&xs[(nt + i * 16) * 68 + k4 * 4];
            acc[i].x += xv.x * w0.x + xv.y * w1.x + xv.z * w2.x + xv.w * w3.x;
            acc[i].y += xv.x * w0.y + xv.y * w1.y + xv.z * w2.y + xv.w * w3.y;
            acc[i].z += xv.x * w0.z + xv.y * w1.z + xv.z * w2.z + xv.w * w3.z;
            acc[i].w += xv.x * w0.w + xv.y * w1.w + xv.z * w2.w + xv.w * w3.w;
        }
    }
#pragma unroll
    for (int i = 0; i < 4; ++i) {
        int row = nt + i * 16;
        if (row < nrem) {
            size_t node = node0 + row;
            if (jt < 8) {
                uint2 p;
                p.x = (unsigned)f2us(acc[i].x) | ((unsigned)f2us(acc[i].y) << 16);
                p.y = (unsigned)f2us(acc[i].z) | ((unsigned)f2us(acc[i].w) << 16);
                *(uint2*)&hlb[node * 32 + jc] = p;
            } else {
                *(float4*)&hr[node * 32 + jc] = acc[i];
            }
        }
    }
}

// 32 lanes per node; batched (16-edge) transposed softmax: per-channel logit partials,
// one butterfly per batch lands edge-e logit on lane e; one exp covers 16 edges.
__global__ __launch_bounds__(256) void k_l2_agg(const unsigned short* __restrict__ hlb, const float* __restrict__ hr,
                                                const float* __restrict__ att2, const float* __restrict__ b2,
                                                const int* __restrict__ off, const int* __restrict__ csr,
                                                float* __restrict__ x2, int N) {
    int tid = threadIdx.x;
    int node = blockIdx.x * 8 + (tid >> 5);
    if (node >= N) return;
    int sl = tid & 31;
    int lane = tid & 63;
    int es = sl & 15;            // this lane's edge slot within the 16-lane head group
    int lb16 = lane & 48;        // head-group base lane

    float hrd = hr[(size_t)node * 32 + sl];
    float a2 = att2[sl];
    int e0 = off[node], e1 = off[node + 1];

    // self-loop (classic 4-shfl reduce, once per node)
    float hsf = us2f(hlb[(size_t)node * 32 + sl]);
    float ev = hsf + hrd;
    ev = (ev > 0.f) ? ev : 0.2f * ev;
    float ts = ev * a2;
    ts += __shfl_xor(ts, 1); ts += __shfl_xor(ts, 2);
    ts += __shfl_xor(ts, 4); ts += __shfl_xor(ts, 8);
    float wself = __expf(ts);
    float acc = wself * hsf;
    float den_l = 0.f;

    for (int jj = e0; jj < e1; jj += 16) {
        int rem = e1 - jj; if (rem > 16) rem = 16;
        float hv[16], v[16];
#pragma unroll
        for (int k = 0; k < 16; ++k) {
            int idx = (k < rem) ? (jj + k) : (jj + rem - 1);
            int s = csr[idx];
            hv[k] = us2f(hlb[(size_t)s * 32 + sl]);
        }
#pragma unroll
        for (int k = 0; k < 16; ++k) {
            float e2 = hv[k] + hrd;
            e2 = (e2 > 0.f) ? e2 : 0.2f * e2;
            v[k] = e2 * a2;
        }
        // value-splitting butterfly across the 16-lane head group
#pragma unroll
        for (int d = 8; d >= 1; d >>= 1) {
#pragma unroll
            for (int i = 0; i < 16; ++i) {
                if (i < d) {
                    float a = v[i], b = v[i + d];
                    float send = (es & d) ? a : b;
                    float recv = __shfl_xor(send, d);
                    v[i] = ((es & d) ? b : a) + recv;
                }
            }
        }
        float w = (es < rem) ? __expf(v[0]) : 0.f;
        den_l += w;
#pragma unroll
        for (int k = 0; k < 16; ++k) {
            float wk = __shfl(w, lb16 + k);
            acc += wk * hv[k];
        }
    }
    den_l += __shfl_xor(den_l, 1); den_l += __shfl_xor(den_l, 2);
    den_l += __shfl_xor(den_l, 4); den_l += __shfl_xor(den_l, 8);
    float den = den_l + wself;
    x2[(size_t)node * 32 + sl] = acc / (den + 1e-16f) + b2[sl];
}

// ---------------- Layer 3: TransformerConv(32, 7, heads=1) ----------------

// pack Wq/Wsk/Wk/Wv -> Wcat[32][32] whose output row is {q0..6,0,sk0..6,0,k0..6,0,v0..6,0}
__global__ __launch_bounds__(1024) void k_l3_wcat(const float* __restrict__ Wq, const float* __restrict__ bq,
                                                  const float* __restrict__ Wk, const float* __restrict__ bk,
                                                  const float* __restrict__ Wv, const float* __restrict__ bv,
                                                  const float* __restrict__ Ws, const float* __restrict__ bs,
                                                  float* __restrict__ Wcat, float* __restrict__ bcat) {
    int t = threadIdx.x;
    int c = t & 31, g = c >> 3, cc = c & 7;
    const float* Wg = (g == 0) ? Wq : (g == 1) ? Ws : (g == 2) ? Wk : Wv;
    const float* Bg = (g == 0) ? bq : (g == 1) ? bs : (g == 2) ? bk : bv;
    int kk = t >> 5;
    Wcat[t] = (cc < 7) ? Wg[kk * 7 + cc] : 0.f;
    if (t < 32) bcat[t] = (cc < 7) ? Bg[cc] : 0.f;
}

// 128 nodes per 256-thread block; thread = 4-node x 4-col tile; cols map to QS|KV directly
__global__ __launch_bounds__(256) void k_l3_transform(const float* __restrict__ x2,
                                                      const float4* __restrict__ Wc4, const float4* __restrict__ bc4,
                                                      float* __restrict__ QS, float* __restrict__ KV, int N) {
    __shared__ float xs[128 * 36];
    int t = threadIdx.x;
    int node0 = blockIdx.x * 128;
    int nrem = N - node0; if (nrem > 128) nrem = 128;
    const float4* xg = (const float4*)x2;
#pragma unroll
    for (int it = 0; it < 4; ++it) {
        int id = it * 256 + t;
        int row = id >> 3, c4 = id & 7;
        float4 v = make_float4(0.f, 0.f, 0.f, 0.f);
        if (row < nrem) v = xg[(size_t)(node0 + row) * 8 + c4];
        *(float4*)&xs[row * 36 + c4 * 4] = v;
    }
    __syncthreads();
    int nt = t >> 3;
    int jt = t & 7;
    float4 bb = bc4[jt];
    float4 acc[4];
#pragma unroll
    for (int i = 0; i < 4; ++i) acc[i] = bb;
#pragma unroll
    for (int k4 = 0; k4 < 8; ++k4) {
        float4 w0 = Wc4[(k4 * 4 + 0) * 8 + jt];
        float4 w1 = Wc4[(k4 * 4 + 1) * 8 + jt];
        float4 w2 = Wc4[(k4 * 4 + 2) * 8 + jt];
        float4 w3 = Wc4[(k4 * 4 + 3) * 8 + jt];
#pragma unroll
        for (int i = 0; i < 4; ++i) {
            float4 xv = *(const float4*)&xs[(nt + i * 32) * 36 + k4 * 4];
            acc[i].x += xv.x * w0.x + xv.y * w1.x + xv.z * w2.x + xv.w * w3.x;
            acc[i].y += xv.x * w0.y + xv.y * w1.y + xv.z * w2.y + xv.w * w3.y;
            acc[i].z += xv.x * w0.z + xv.y * w1.z + xv.z * w2.z + xv.w * w3.z;
            acc[i].w += xv.x * w0.w + xv.y * w1.w + xv.z * w2.w + xv.w * w3.w;
        }
    }
#pragma unroll
    for (int i = 0; i < 4; ++i) {
        int row = nt + i * 32;
        if (row < nrem) {
            size_t node = node0 + row;
            float* dst = (jt < 4) ? (QS + node * 16 + jt * 4) : (KV + node * 16 + (jt - 4) * 4);
            *(float4*)dst = acc[i];
        }
    }
}

// 8 lanes per node; batched (8-edge) transposed softmax; K|V share one cache line per source
__global__ __launch_bounds__(256) void k_l3_agg(const float* __restrict__ QS, const float* __restrict__ KV,
                                                const int* __restrict__ off, const int* __restrict__ csr,
                                                float* __restrict__ out, int N) {
    int tid = threadIdx.x;
    int node = blockIdx.x * 32 + (tid >> 3);
    if (node >= N) return;
    int sl = tid & 7;            // channel (7 = zero pad)
    int lane = tid & 63;
    int lb8 = lane & 56;

    float qd = QS[(size_t)node * 16 + sl];   // pad channel reads stored 0
    float acc = 0.f, den_l = 0.f;
    int e0 = off[node], e1 = off[node + 1];
    const float scale = 0.3779644730092272f;  // 1/sqrt(7)

    for (int jj = e0; jj < e1; jj += 8) {
        int rem = e1 - jj; if (rem > 8) rem = 8;
        float kv[8], vv[8], v[8];
#pragma unroll
        for (int k = 0; k < 8; ++k) {
            int idx = (k < rem) ? (jj + k) : (jj + rem - 1);
            int s = csr[idx];
            kv[k] = KV[(size_t)s * 16 + sl];
            vv[k] = KV[(size_t)s * 16 + 8 + sl];
        }
#pragma unroll
        for (int k = 0; k < 8; ++k) v[k] = qd * kv[k];
#pragma unroll
        for (int d = 4; d >= 1; d >>= 1) {
#pragma unroll
            for (int i = 0; i < 8; ++i) {
                if (i < d) {
                    float a = v[i], b = v[i + d];
                    float send = (sl & d) ? a : b;
                    float recv = __shfl_xor(send, d);
                    v[i] = ((sl & d) ? b : a) + recv;
                }
            }
        }
        float w = (sl < rem) ? __expf(v[0] * scale) : 0.f;
        den_l += w;
#pragma unroll
        for (int k = 0; k < 8; ++k) {
            float wk = __shfl(w, lb8 + k);
            acc += wk * vv[k];
        }
    }
    den_l += __shfl_xor(den_l, 1); den_l += __shfl_xor(den_l, 2); den_l += __shfl_xor(den_l, 4);
    if (sl < 7) out[(size_t)node * 7 + sl] = acc / (den_l + 1e-16f)
                                             + QS[(size_t)node * 16 + 8 + sl];
}

// ---------------- launcher ----------------

extern "C" void kernel_launch(void* const* d_in, const int* in_sizes, int n_in,
                              void* d_out, int out_size, void* d_ws, size_t ws_size,
                              hipStream_t stream) {
    const int* ei = (const int*)d_in[1];
    float* out = (float*)d_out;

    int N = in_sizes[0] / 3;
    int E = in_sizes[1] / 2;
    int NB = (N + 1023) >> 10;   // assumed <= 256 (N <= 262144)

    char* ws = (char*)d_ws;
    size_t o = 0;
    auto take = [&](size_t bytes) -> char* {
        char* p = ws + o;
        o = (o + bytes + 255) & ~(size_t)255;
        return p;
    };
    int*   flags   = (int*)take(64);
    int total_f = 0;
    for (int i = 0; i < 20; ++i) if (i != 1) total_f += in_sizes[i];
    float* canon   = (float*)take((size_t)total_f * 4);
    float* Wcat    = (float*)take(32 * 32 * 4);
    float* bcat    = (float*)take(32 * 4);
    int*   csr_off = (int*)take((size_t)(N + 1) * 4);
    int*   bcnt    = (int*)take(256 * 4);
    int*   bbase   = (int*)take(257 * 4);
    int*   bcur    = (int*)take(256 * 4);
    int*   csr     = (int*)take((size_t)E * 4);
    float* bufA    = (float*)take((size_t)N * 64 * 4);  // x4 -> hlb|hr -> QS|KV
    float* as1     = (float*)take((size_t)N * 4 * 4);
    float* ad1     = (float*)take((size_t)N * 4 * 4);
    float* bufB    = (float*)take((size_t)N * 64 * 4);  // bkt -> x1 -> x2
    (void)ws_size; (void)n_in; (void)out_size;

    CvtArgs ca;
    const float* cp[20];
    {
        int off_ = 0, k = 0;
        for (int i = 0; i < 20; ++i) {
            if (i == 1) { cp[i] = nullptr; continue; }
            ca.p[k] = d_in[i];
            ca.sz[k] = in_sizes[i];
            cp[i] = canon + off_;
            off_ += in_sizes[i];
            ++k;
        }
    }

    hipMemsetAsync(bcnt, 0, 256 * 4, stream);
    k_detect<<<1, 256, 0, stream>>>((const unsigned short*)d_in[0], ei, flags);
    k_convert<<<(total_f + 255) / 256, 256, 0, stream>>>(ca, flags, canon, total_f);
    k_l3_wcat<<<1, 1024, 0, stream>>>(cp[12], cp[13], cp[14], cp[15], cp[16], cp[17],
                                      cp[18], cp[19], Wcat, bcat);

    int2* bkt = (int2*)bufB;
    int gb = (E + 4095) / 4096;
    k_bhist<<<gb, 1024, 0, stream>>>(ei, flags, bcnt, E, NB);
    k_bscan<<<1, 256, 0, stream>>>(bcnt, bbase, bcur, csr_off, NB, N, E);
    k_bscatter<<<gb, 1024, 0, stream>>>(ei, flags, bcur, bkt, E, NB);
    k_bbuild<<<NB, 1024, 0, stream>>>(bkt, bbase, csr_off, csr, N);

    float4* x4 = (float4*)bufA;                                  // N*16B = 1.6 MB, L2-resident
    k_l1_transform<<<(N + 3) / 4, 256, 0, stream>>>(cp[0], cp[2], cp[3], cp[4], x4, as1, ad1, N);
    float* x1 = bufB;
    k_l1_agg<<<(N + 15) / 16, 256, 0, stream>>>(x4, (const float4*)as1, (const float4*)ad1,
                                                csr_off, csr, cp[2], cp[5], x1, N);

    unsigned short* hlb = (unsigned short*)bufA;                 // N*32 bf16 = 6.4 MB
    float* hr = bufA + (size_t)N * 16;
    k_l2_transform<<<(N + 63) / 64, 256, 0, stream>>>(x1, cp[6], cp[7], cp[8], cp[9], hlb, hr, N);
    float* x2 = bufB;
    k_l2_agg<<<(N + 7) / 8, 256, 0, stream>>>(hlb, hr, cp[10], cp[11], csr_off, csr, x2, N);

    float* QS = bufA;                                            // N*16 floats
    float* KV = bufA + (size_t)N * 16;                           // N*16 floats
    k_l3_transform<<<(N + 127) / 128, 256, 0, stream>>>(x2, (const float4*)Wcat, (const float4*)bcat,
                                                        QS, KV, N);
    k_l3_agg<<<(N + 31) / 32, 256, 0, stream>>>(QS, KV, csr_off, csr, out, N);
}

// Round 10
// 336.241 us; speedup vs baseline: 1.4907x; 1.0603x over previous
//
#include <hip/hip_runtime.h>
#include <hip/hip_bf16.h>

typedef __hip_bfloat16 bf16;

static __device__ __forceinline__ float us2f(unsigned short u) {
    union { unsigned int i; float f; } c; c.i = ((unsigned int)u) << 16; return c.f;
}
static __device__ __forceinline__ unsigned short f2us(float f) {
    union { float f; unsigned int i; } c; c.f = f;
    unsigned int r = c.i + 0x7FFF + ((c.i >> 16) & 1);   // round-to-nearest-even
    return (unsigned short)(r >> 16);
}

// ---------------- dtype probe + canonicalization ----------------

__global__ __launch_bounds__(256) void k_detect(const unsigned short* __restrict__ xr,
                                                const int* __restrict__ er,
                                                int* __restrict__ flags) {
    __shared__ int sbad, snz;
    int tid = threadIdx.x;
    if (tid == 0) { sbad = 0; snz = 0; }
    __syncthreads();
    int bad = 0, nz = 0;
    for (int i = tid; i < 1024; i += 256) {
        unsigned short w = xr[2 * i];
        int ex = (w >> 7) & 0xFF;
        if (ex < 110 || ex > 135) bad++;
        if (er[2 * i + 1] != 0) nz++;
    }
    atomicAdd(&sbad, bad);
    atomicAdd(&snz, nz);
    __syncthreads();
    if (tid == 0) {
        flags[0] = (sbad > 256) ? 1 : 0;
        flags[1] = (snz < 512) ? 1 : 0;
    }
}

struct CvtArgs { const void* p[19]; int sz[19]; };

__global__ __launch_bounds__(256) void k_convert(CvtArgs a, const int* __restrict__ flags,
                                                 float* __restrict__ dst, int total) {
    int t = blockIdx.x * 256 + threadIdx.x;
    if (t >= total) return;
    int isf32 = flags[0];
    int base = 0, seg = -1, off = 0;
#pragma unroll
    for (int i = 0; i < 19; i++) {
        if (seg < 0 && t < base + a.sz[i]) { seg = i; off = t - base; }
        base += a.sz[i];
    }
    const void* p = a.p[seg];
    float v = isf32 ? ((const float*)p)[off] : __bfloat162float(((const bf16*)p)[off]);
    dst[t] = v;
}

static __device__ __forceinline__ int ld_edge(const int* er, size_t i, int idx64) {
    return idx64 ? er[2 * i] : er[i];
}

// ---------------- bucketed CSR build ----------------
// bucket b = dst >> 10 (1024 nodes per bucket), NB <= 256 assumed (N <= 262144)

__global__ __launch_bounds__(1024) void k_bhist(const int* __restrict__ er, const int* __restrict__ flags,
                                                int* __restrict__ bcnt, int E, int NB) {
    __shared__ int cnt[256];
    int tid = threadIdx.x;
    if (tid < 256) cnt[tid] = 0;
    __syncthreads();
    int idx64 = flags[1];
    int base = blockIdx.x * 4096 + tid;
#pragma unroll
    for (int k = 0; k < 4; ++k) {
        int e = base + k * 1024;
        if (e < E) {
            int d = ld_edge(er, (size_t)E + e, idx64);
            atomicAdd(&cnt[d >> 10], 1);
        }
    }
    __syncthreads();
    if (tid < NB && cnt[tid]) atomicAdd(&bcnt[tid], cnt[tid]);
}

__global__ __launch_bounds__(256) void k_bscan(const int* __restrict__ bcnt, int* __restrict__ bbase,
                                               int* __restrict__ bcur, int* __restrict__ csr_off,
                                               int NB, int N, int E) {
    __shared__ int sm[256];
    int tid = threadIdx.x;
    int v = (tid < NB) ? bcnt[tid] : 0;
    sm[tid] = v;
    __syncthreads();
    for (int d = 1; d < 256; d <<= 1) {
        int t = (tid >= d) ? sm[tid - d] : 0;
        __syncthreads();
        sm[tid] += t;
        __syncthreads();
    }
    int excl = sm[tid] - v;
    if (tid < NB) { bbase[tid] = excl; bcur[tid] = excl; }
    if (tid == 0) { bbase[NB] = E; csr_off[N] = E; }
}

__global__ __launch_bounds__(1024) void k_bscatter(const int* __restrict__ er, const int* __restrict__ flags,
                                                   int* __restrict__ bcur, int2* __restrict__ bkt,
                                                   int E, int NB) {
    __shared__ int cnt[256];
    __shared__ int res[256];
    int tid = threadIdx.x;
    if (tid < 256) cnt[tid] = 0;
    __syncthreads();
    int idx64 = flags[1];
    int base = blockIdx.x * 4096 + tid;
    int sv[4], dv[4], bv[4];
    bool val[4];
#pragma unroll
    for (int k = 0; k < 4; ++k) {
        int e = base + k * 1024;
        val[k] = (e < E);
        if (val[k]) {
            sv[k] = ld_edge(er, (size_t)e, idx64);
            dv[k] = ld_edge(er, (size_t)E + e, idx64);
            bv[k] = dv[k] >> 10;
            atomicAdd(&cnt[bv[k]], 1);
        }
    }
    __syncthreads();
    if (tid < NB) {
        int c = cnt[tid];
        res[tid] = c ? atomicAdd(&bcur[tid], c) : 0;
        cnt[tid] = 0;
    }
    __syncthreads();
#pragma unroll
    for (int k = 0; k < 4; ++k) {
        if (val[k]) {
            int r = atomicAdd(&cnt[bv[k]], 1);
            bkt[res[bv[k]] + r] = make_int2(sv[k], dv[k]);
        }
    }
}

__global__ __launch_bounds__(1024) void k_bbuild(const int2* __restrict__ bkt, const int* __restrict__ bbase,
                                                 int* __restrict__ csr_off, int* __restrict__ csr, int N) {
    __shared__ int sm[1024];
    int b = blockIdx.x, tid = threadIdx.x;
    int node0 = b << 10;
    int n0 = bbase[b], n1 = bbase[b + 1];
    int m = n1 - n0;
    sm[tid] = 0;
    __syncthreads();
    const int2* bp = bkt + n0;
    for (int i = tid; i < m; i += 1024) atomicAdd(&sm[bp[i].y - node0], 1);
    __syncthreads();
    int v = sm[tid];
    for (int d = 1; d < 1024; d <<= 1) {
        int t = (tid >= d) ? sm[tid - d] : 0;
        __syncthreads();
        sm[tid] += t;
        __syncthreads();
    }
    int excl = sm[tid] - v;
    int node = node0 + tid;
    if (node < N) csr_off[node] = n0 + excl;
    __syncthreads();
    sm[tid] = excl;
    __syncthreads();
    for (int i = tid; i < m; i += 1024) {
        int2 sd = bp[i];
        int r = atomicAdd(&sm[sd.y - node0], 1);
        csr[n0 + r] = sd.x;
    }
}

// ---------------- Layer 1: GATConv(3, 16, heads=4) ----------------

__global__ __launch_bounds__(256) void k_l1_transform(const float* __restrict__ x, const float* __restrict__ W1,
                                                      const float* __restrict__ att_s, const float* __restrict__ att_d,
                                                      float4* __restrict__ x4, float* __restrict__ as1,
                                                      float* __restrict__ ad1, int N) {
    int tid = threadIdx.x;
    int node = blockIdx.x * 4 + (tid >> 6);
    if (node >= N) return;
    int lane = tid & 63;
    float x0 = x[node * 3 + 0];
    float x1 = x[node * 3 + 1];
    float x2 = x[node * 3 + 2];
    float h = x0 * W1[lane] + x1 * W1[64 + lane] + x2 * W1[128 + lane];
    if (lane == 0) x4[node] = make_float4(x0, x1, x2, 0.f);
    float ts = h * att_s[lane];
    float td = h * att_d[lane];
    for (int m = 8; m >= 1; m >>= 1) { ts += __shfl_xor(ts, m); td += __shfl_xor(td, m); }
    if ((lane & 15) == 0) {
        as1[node * 4 + (lane >> 4)] = ts;
        ad1[node * 4 + (lane >> 4)] = td;
    }
}

// Edge-parallel: 16 lanes per node; accumulate per-head weighted x-3vec + denom, butterfly-reduce.
__global__ __launch_bounds__(256) void k_l1_agg(const float4* __restrict__ x4, const float4* __restrict__ as4,
                                                const float4* __restrict__ ad4p, const int* __restrict__ off,
                                                const int* __restrict__ csr, const float* __restrict__ W1,
                                                const float* __restrict__ b1,
                                                float* __restrict__ x1, int N) {
    int tid = threadIdx.x;
    int node = blockIdx.x * 16 + (tid >> 4);
    if (node >= N) return;
    int sl = tid & 15;
    int lane = tid & 63;
    int lb = lane & 48;

    float4 ad = ad4p[node];
    int e0 = off[node], e1 = off[node + 1];

    float v[16];
#pragma unroll
    for (int i = 0; i < 16; ++i) v[i] = 0.f;

    for (int jj = e0 + sl; jj < e1; jj += 16) {
        int s = csr[jj];
        float4 a = as4[s];
        float4 xv = x4[s];
        float z0 = a.x + ad.x, z1 = a.y + ad.y, z2 = a.z + ad.z, z3 = a.w + ad.w;
        z0 = (z0 > 0.f) ? z0 : 0.2f * z0;
        z1 = (z1 > 0.f) ? z1 : 0.2f * z1;
        z2 = (z2 > 0.f) ? z2 : 0.2f * z2;
        z3 = (z3 > 0.f) ? z3 : 0.2f * z3;
        float w0 = __expf(z0), w1 = __expf(z1), w2 = __expf(z2), w3 = __expf(z3);
        v[0] += w0 * xv.x; v[1] += w0 * xv.y; v[2]  += w0 * xv.z; v[3]  += w0;
        v[4] += w1 * xv.x; v[5] += w1 * xv.y; v[6]  += w1 * xv.z; v[7]  += w1;
        v[8] += w2 * xv.x; v[9] += w2 * xv.y; v[10] += w2 * xv.z; v[11] += w2;
        v[12] += w3 * xv.x; v[13] += w3 * xv.y; v[14] += w3 * xv.z; v[15] += w3;
    }

#pragma unroll
    for (int d = 8; d >= 1; d >>= 1) {
#pragma unroll
        for (int i = 0; i < 16; ++i) {
            if (i < d) {
                float a = v[i], b = v[i + d];
                float send = (sl & d) ? a : b;
                float recv = __shfl_xor(send, d);
                v[i] = ((sl & d) ? b : a) + recv;
            }
        }
    }
    float r = v[0];

    float agx[4], agy[4], agz[4], dn[4];
#pragma unroll
    for (int h = 0; h < 4; ++h) {
        agx[h] = __shfl(r, lb + 4 * h + 0);
        agy[h] = __shfl(r, lb + 4 * h + 1);
        agz[h] = __shfl(r, lb + 4 * h + 2);
        dn[h]  = __shfl(r, lb + 4 * h + 3);
    }

    {
        float4 a = as4[node];
        float4 xv = x4[node];
        float z0 = a.x + ad.x, z1 = a.y + ad.y, z2 = a.z + ad.z, z3 = a.w + ad.w;
        z0 = (z0 > 0.f) ? z0 : 0.2f * z0;
        z1 = (z1 > 0.f) ? z1 : 0.2f * z1;
        z2 = (z2 > 0.f) ? z2 : 0.2f * z2;
        z3 = (z3 > 0.f) ? z3 : 0.2f * z3;
        float w0 = __expf(z0), w1 = __expf(z1), w2 = __expf(z2), w3 = __expf(z3);
        agx[0] += w0 * xv.x; agy[0] += w0 * xv.y; agz[0] += w0 * xv.z; dn[0] += w0;
        agx[1] += w1 * xv.x; agy[1] += w1 * xv.y; agz[1] += w1 * xv.z; dn[1] += w1;
        agx[2] += w2 * xv.x; agy[2] += w2 * xv.y; agz[2] += w2 * xv.z; dn[2] += w2;
        agx[3] += w3 * xv.x; agy[3] += w3 * xv.y; agz[3] += w3 * xv.z; dn[3] += w3;
    }

#pragma unroll
    for (int h = 0; h < 4; ++h) {
        int j = h * 16 + sl;
        float inv = 1.f / (dn[h] + 1e-16f);
        float o = (agx[h] * W1[j] + agy[h] * W1[64 + j] + agz[h] * W1[128 + j]) * inv + b1[j];
        x1[(size_t)node * 64 + j] = (o > 0.f) ? o : 0.f;
    }
}

// ---------------- Layer 2: GATv2Conv(64, 16, heads=2) ----------------

// 64 nodes per 256-thread block; thread = 4-node x 4-col register tile of [hl|hr]
__global__ __launch_bounds__(256) void k_l2_transform(const float* __restrict__ x1,
                                                      const float* __restrict__ W2l, const float* __restrict__ b2l,
                                                      const float* __restrict__ W2r, const float* __restrict__ b2r,
                                                      unsigned short* __restrict__ hlb, float* __restrict__ hr, int N) {
    __shared__ float xs[64 * 68];   // row stride 68: per-wave broadcast rows hit banks {0,4,8,12}
    int t = threadIdx.x;
    int node0 = blockIdx.x * 64;
    int nrem = N - node0; if (nrem > 64) nrem = 64;
    const float4* xg = (const float4*)x1;
#pragma unroll
    for (int it = 0; it < 4; ++it) {
        int id = it * 256 + t;
        int row = id >> 4, c4 = id & 15;
        float4 v = make_float4(0.f, 0.f, 0.f, 0.f);
        if (row < nrem) v = xg[(size_t)(node0 + row) * 16 + c4];
        *(float4*)&xs[row * 68 + c4 * 4] = v;
    }
    __syncthreads();
    int nt = t >> 4;
    int jt = t & 15;
    int jq = jt & 7;
    int jc = jq * 4;
    const float4* W4 = (const float4*)((jt < 8) ? W2l : W2r);
    const float4* B4 = (const float4*)((jt < 8) ? b2l : b2r);
    float4 bb = B4[jq];
    float4 acc[4];
#pragma unroll
    for (int i = 0; i < 4; ++i) acc[i] = bb;
#pragma unroll
    for (int k4 = 0; k4 < 16; ++k4) {
        float4 w0 = W4[(k4 * 4 + 0) * 8 + jq];
        float4 w1 = W4[(k4 * 4 + 1) * 8 + jq];
        float4 w2 = W4[(k4 * 4 + 2) * 8 + jq];
        float4 w3 = W4[(k4 * 4 + 3) * 8 + jq];
#pragma unroll
        for (int i = 0; i < 4; ++i) {
            float4 xv = *(const float4*)&xs[(nt + i * 16) * 68 + k4 * 4];
            acc[i].x += xv.x * w0.x + xv.y * w1.x + xv.z * w2.x + xv.w * w3.x;
            acc[i].y += xv.x * w0.y + xv.y * w1.y + xv.z * w2.y + xv.w * w3.y;
            acc[i].z += xv.x * w0.z + xv.y * w1.z + xv.z * w2.z + xv.w * w3.z;
            acc[i].w += xv.x * w0.w + xv.y * w1.w + xv.z * w2.w + xv.w * w3.w;
        }
    }
#pragma unroll
    for (int i = 0; i < 4; ++i) {
        int row = nt + i * 16;
        if (row < nrem) {
            size_t node = node0 + row;
            if (jt < 8) {
                uint2 p;
                p.x = (unsigned)f2us(acc[i].x) | ((unsigned)f2us(acc[i].y) << 16);
                p.y = (unsigned)f2us(acc[i].z) | ((unsigned)f2us(acc[i].w) << 16);
                *(uint2*)&hlb[node * 32 + jc] = p;
            } else {
                *(float4*)&hr[node * 32 + jc] = acc[i];
            }
        }
    }
}

// Edge-parallel: 16 lanes per node, lane = edge slot. Full 64B hl row per edge (4x uint4),
// both head logits computed in-register (zero per-edge shfl); one butterfly per node.
__global__ __launch_bounds__(256) void k_l2_agg(const unsigned short* __restrict__ hlb, const float* __restrict__ hr,
                                                const float* __restrict__ att2, const float* __restrict__ b2,
                                                const int* __restrict__ off, const int* __restrict__ csr,
                                                float* __restrict__ x2, int N) {
    int tid = threadIdx.x;
    int node = blockIdx.x * 16 + (tid >> 4);
    if (node >= N) return;
    int sl = tid & 15;

    // hr row in registers (constant-indexed via full unroll)
    float hrd[32];
    {
        const float4* hr4 = (const float4*)(hr + (size_t)node * 32);
#pragma unroll
        for (int q = 0; q < 8; ++q) {
            float4 v = hr4[q];
            hrd[4 * q + 0] = v.x; hrd[4 * q + 1] = v.y;
            hrd[4 * q + 2] = v.z; hrd[4 * q + 3] = v.w;
        }
    }

    float accA[16], accB[16];
#pragma unroll
    for (int i = 0; i < 16; ++i) { accA[i] = 0.f; accB[i] = 0.f; }
    float den0 = 0.f, den1 = 0.f;

    int e0 = off[node], e1 = off[node + 1];
    for (int jj = e0 + sl; jj < e1; jj += 16) {
        int s = csr[jj];
        const uint4* hp = (const uint4*)(hlb + (size_t)s * 32);
        uint4 u0 = hp[0], u1 = hp[1], u2 = hp[2], u3 = hp[3];
        unsigned int uu[16] = {u0.x, u0.y, u0.z, u0.w, u1.x, u1.y, u1.z, u1.w,
                               u2.x, u2.y, u2.z, u2.w, u3.x, u3.y, u3.z, u3.w};
        float t0 = 0.f, t1 = 0.f;
#pragma unroll
        for (int q = 0; q < 8; ++q) {
            float lo = __uint_as_float(uu[q] << 16);
            float hi = __uint_as_float(uu[q] & 0xFFFF0000u);
            float el = lo + hrd[2 * q];     el = fmaxf(el, 0.2f * el);
            float eh = hi + hrd[2 * q + 1]; eh = fmaxf(eh, 0.2f * eh);
            t0 += att2[2 * q] * el + att2[2 * q + 1] * eh;
        }
#pragma unroll
        for (int q = 8; q < 16; ++q) {
            float lo = __uint_as_float(uu[q] << 16);
            float hi = __uint_as_float(uu[q] & 0xFFFF0000u);
            float el = lo + hrd[2 * q];     el = fmaxf(el, 0.2f * el);
            float eh = hi + hrd[2 * q + 1]; eh = fmaxf(eh, 0.2f * eh);
            t1 += att2[2 * q] * el + att2[2 * q + 1] * eh;
        }
        float w0 = __expf(t0), w1 = __expf(t1);
        den0 += w0; den1 += w1;
#pragma unroll
        for (int q = 0; q < 8; ++q) {
            accA[2 * q]     += w0 * __uint_as_float(uu[q] << 16);
            accA[2 * q + 1] += w0 * __uint_as_float(uu[q] & 0xFFFF0000u);
        }
#pragma unroll
        for (int q = 8; q < 16; ++q) {
            accB[2 * (q - 8)]     += w1 * __uint_as_float(uu[q] << 16);
            accB[2 * (q - 8) + 1] += w1 * __uint_as_float(uu[q] & 0xFFFF0000u);
        }
    }

    // butterfly-reduce 16+16 accs and 2 dens across the 16-lane group
#pragma unroll
    for (int d = 8; d >= 1; d >>= 1) {
#pragma unroll
        for (int i = 0; i < 16; ++i) {
            if (i < d) {
                { float a = accA[i], b = accA[i + d];
                  float send = (sl & d) ? a : b;
                  float recv = __shfl_xor(send, d);
                  accA[i] = ((sl & d) ? b : a) + recv; }
                { float a = accB[i], b = accB[i + d];
                  float send = (sl & d) ? a : b;
                  float recv = __shfl_xor(send, d);
                  accB[i] = ((sl & d) ? b : a) + recv; }
            }
        }
        den0 += __shfl_xor(den0, d);
        den1 += __shfl_xor(den1, d);
    }
    float sumA = accA[0];   // channel sl (head 0)
    float sumB = accB[0];   // channel 16+sl (head 1)

    // self-loop (cooperative: lane sl holds channels sl and 16+sl)
    float hr0 = hr[(size_t)node * 32 + sl];
    float hr1 = hr[(size_t)node * 32 + 16 + sl];
    float hl0 = us2f(hlb[(size_t)node * 32 + sl]);
    float hl1 = us2f(hlb[(size_t)node * 32 + 16 + sl]);
    float ea = hl0 + hr0; ea = fmaxf(ea, 0.2f * ea);
    float eb = hl1 + hr1; eb = fmaxf(eb, 0.2f * eb);
    float p0 = att2[sl] * ea;
    float p1 = att2[16 + sl] * eb;
    p0 += __shfl_xor(p0, 1); p0 += __shfl_xor(p0, 2); p0 += __shfl_xor(p0, 4); p0 += __shfl_xor(p0, 8);
    p1 += __shfl_xor(p1, 1); p1 += __shfl_xor(p1, 2); p1 += __shfl_xor(p1, 4); p1 += __shfl_xor(p1, 8);
    float w0 = __expf(p0), w1 = __expf(p1);
    sumA += w0 * hl0; den0 += w0;
    sumB += w1 * hl1; den1 += w1;

    x2[(size_t)node * 32 + sl]      = sumA / (den0 + 1e-16f) + b2[sl];
    x2[(size_t)node * 32 + 16 + sl] = sumB / (den1 + 1e-16f) + b2[16 + sl];
}

// ---------------- Layer 3: TransformerConv(32, 7, heads=1) ----------------

// pack Wq/Wsk/Wk/Wv -> Wcat[32][32] whose output row is {q0..6,0,sk0..6,0,k0..6,0,v0..6,0}
__global__ __launch_bounds__(1024) void k_l3_wcat(const float* __restrict__ Wq, const float* __restrict__ bq,
                                                  const float* __restrict__ Wk, const float* __restrict__ bk,
                                                  const float* __restrict__ Wv, const float* __restrict__ bv,
                                                  const float* __restrict__ Ws, const float* __restrict__ bs,
                                                  float* __restrict__ Wcat, float* __restrict__ bcat) {
    int t = threadIdx.x;
    int c = t & 31, g = c >> 3, cc = c & 7;
    const float* Wg = (g == 0) ? Wq : (g == 1) ? Ws : (g == 2) ? Wk : Wv;
    const float* Bg = (g == 0) ? bq : (g == 1) ? bs : (g == 2) ? bk : bv;
    int kk = t >> 5;
    Wcat[t] = (cc < 7) ? Wg[kk * 7 + cc] : 0.f;
    if (t < 32) bcat[t] = (cc < 7) ? Bg[cc] : 0.f;
}

// 128 nodes per 256-thread block; thread = 4-node x 4-col tile; cols map to QS|KV directly
__global__ __launch_bounds__(256) void k_l3_transform(const float* __restrict__ x2,
                                                      const float4* __restrict__ Wc4, const float4* __restrict__ bc4,
                                                      float* __restrict__ QS, float* __restrict__ KV, int N) {
    __shared__ float xs[128 * 36];
    int t = threadIdx.x;
    int node0 = blockIdx.x * 128;
    int nrem = N - node0; if (nrem > 128) nrem = 128;
    const float4* xg = (const float4*)x2;
#pragma unroll
    for (int it = 0; it < 4; ++it) {
        int id = it * 256 + t;
        int row = id >> 3, c4 = id & 7;
        float4 v = make_float4(0.f, 0.f, 0.f, 0.f);
        if (row < nrem) v = xg[(size_t)(node0 + row) * 8 + c4];
        *(float4*)&xs[row * 36 + c4 * 4] = v;
    }
    __syncthreads();
    int nt = t >> 3;
    int jt = t & 7;
    float4 bb = bc4[jt];
    float4 acc[4];
#pragma unroll
    for (int i = 0; i < 4; ++i) acc[i] = bb;
#pragma unroll
    for (int k4 = 0; k4 < 8; ++k4) {
        float4 w0 = Wc4[(k4 * 4 + 0) * 8 + jt];
        float4 w1 = Wc4[(k4 * 4 + 1) * 8 + jt];
        float4 w2 = Wc4[(k4 * 4 + 2) * 8 + jt];
        float4 w3 = Wc4[(k4 * 4 + 3) * 8 + jt];
#pragma unroll
        for (int i = 0; i < 4; ++i) {
            float4 xv = *(const float4*)&xs[(nt + i * 32) * 36 + k4 * 4];
            acc[i].x += xv.x * w0.x + xv.y * w1.x + xv.z * w2.x + xv.w * w3.x;
            acc[i].y += xv.x * w0.y + xv.y * w1.y + xv.z * w2.y + xv.w * w3.y;
            acc[i].z += xv.x * w0.z + xv.y * w1.z + xv.z * w2.z + xv.w * w3.z;
            acc[i].w += xv.x * w0.w + xv.y * w1.w + xv.z * w2.w + xv.w * w3.w;
        }
    }
#pragma unroll
    for (int i = 0; i < 4; ++i) {
        int row = nt + i * 32;
        if (row < nrem) {
            size_t node = node0 + row;
            float* dst = (jt < 4) ? (QS + node * 16 + jt * 4) : (KV + node * 16 + (jt - 4) * 4);
            *(float4*)dst = acc[i];
        }
    }
}

// Edge-parallel: 8 lanes per node, lane = edge slot; K|V row per edge (4x float4),
// dot in-register, exactly 8 reduction values (7 acc + den) butterflied over 8 lanes.
__global__ __launch_bounds__(256) void k_l3_agg(const float* __restrict__ QS, const float* __restrict__ KV,
                                                const int* __restrict__ off, const int* __restrict__ csr,
                                                float* __restrict__ out, int N) {
    int tid = threadIdx.x;
    int node = blockIdx.x * 32 + (tid >> 3);
    if (node >= N) return;
    int sl = tid & 7;
    int lane = tid & 63;
    const float scale = 0.3779644730092272f;  // 1/sqrt(7)
    const float4* q4 = (const float4*)(QS + (size_t)node * 16);
    float4 qa = q4[0], qb = q4[1];           // qb.w is pad
    qa.x *= scale; qa.y *= scale; qa.z *= scale; qa.w *= scale;
    qb.x *= scale; qb.y *= scale; qb.z *= scale; qb.w = 0.f;

    float v[8];
#pragma unroll
    for (int i = 0; i < 8; ++i) v[i] = 0.f;

    int e0 = off[node], e1 = off[node + 1];
    for (int jj = e0 + sl; jj < e1; jj += 8) {
        int s = csr[jj];
        const float4* kp = (const float4*)(KV + (size_t)s * 16);
        float4 k0 = kp[0], k1 = kp[1], v0 = kp[2], v1 = kp[3];
        float t = qa.x * k0.x + qa.y * k0.y + qa.z * k0.z + qa.w * k0.w
                + qb.x * k1.x + qb.y * k1.y + qb.z * k1.z;
        float w = __expf(t);
        v[0] += w * v0.x; v[1] += w * v0.y; v[2] += w * v0.z; v[3] += w * v0.w;
        v[4] += w * v1.x; v[5] += w * v1.y; v[6] += w * v1.z; v[7] += w;
    }
#pragma unroll
    for (int d = 4; d >= 1; d >>= 1) {
#pragma unroll
        for (int i = 0; i < 8; ++i) {
            if (i < d) {
                float a = v[i], b = v[i + d];
                float send = (sl & d) ? a : b;
                float recv = __shfl_xor(send, d);
                v[i] = ((sl & d) ? b : a) + recv;
            }
        }
    }
    float r = v[0];                                // value index sl
    float den = __shfl(r, (lane & 56) + 7);        // value 7 = denominator
    if (sl < 7) out[(size_t)node * 7 + sl] = r / (den + 1e-16f)
                                             + QS[(size_t)node * 16 + 8 + sl];
}

// ---------------- launcher ----------------

extern "C" void kernel_launch(void* const* d_in, const int* in_sizes, int n_in,
                              void* d_out, int out_size, void* d_ws, size_t ws_size,
                              hipStream_t stream) {
    const int* ei = (const int*)d_in[1];
    float* out = (float*)d_out;

    int N = in_sizes[0] / 3;
    int E = in_sizes[1] / 2;
    int NB = (N + 1023) >> 10;   // assumed <= 256 (N <= 262144)

    char* ws = (char*)d_ws;
    size_t o = 0;
    auto take = [&](size_t bytes) -> char* {
        char* p = ws + o;
        o = (o + bytes + 255) & ~(size_t)255;
        return p;
    };
    int*   flags   = (int*)take(64);
    int total_f = 0;
    for (int i = 0; i < 20; ++i) if (i != 1) total_f += in_sizes[i];
    float* canon   = (float*)take((size_t)total_f * 4);
    float* Wcat    = (float*)take(32 * 32 * 4);
    float* bcat    = (float*)take(32 * 4);
    int*   csr_off = (int*)take((size_t)(N + 1) * 4);
    int*   bcnt    = (int*)take(256 * 4);
    int*   bbase   = (int*)take(257 * 4);
    int*   bcur    = (int*)take(256 * 4);
    int*   csr     = (int*)take((size_t)E * 4);
    float* bufA    = (float*)take((size_t)N * 64 * 4);  // x4 -> hlb|hr -> QS|KV
    float* as1     = (float*)take((size_t)N * 4 * 4);
    float* ad1     = (float*)take((size_t)N * 4 * 4);
    float* bufB    = (float*)take((size_t)N * 64 * 4);  // bkt -> x1 -> x2
    (void)ws_size; (void)n_in; (void)out_size;

    CvtArgs ca;
    const float* cp[20];
    {
        int off_ = 0, k = 0;
        for (int i = 0; i < 20; ++i) {
            if (i == 1) { cp[i] = nullptr; continue; }
            ca.p[k] = d_in[i];
            ca.sz[k] = in_sizes[i];
            cp[i] = canon + off_;
            off_ += in_sizes[i];
            ++k;
        }
    }

    hipMemsetAsync(bcnt, 0, 256 * 4, stream);
    k_detect<<<1, 256, 0, stream>>>((const unsigned short*)d_in[0], ei, flags);
    k_convert<<<(total_f + 255) / 256, 256, 0, stream>>>(ca, flags, canon, total_f);
    k_l3_wcat<<<1, 1024, 0, stream>>>(cp[12], cp[13], cp[14], cp[15], cp[16], cp[17],
                                      cp[18], cp[19], Wcat, bcat);

    int2* bkt = (int2*)bufB;
    int gb = (E + 4095) / 4096;
    k_bhist<<<gb, 1024, 0, stream>>>(ei, flags, bcnt, E, NB);
    k_bscan<<<1, 256, 0, stream>>>(bcnt, bbase, bcur, csr_off, NB, N, E);
    k_bscatter<<<gb, 1024, 0, stream>>>(ei, flags, bcur, bkt, E, NB);
    k_bbuild<<<NB, 1024, 0, stream>>>(bkt, bbase, csr_off, csr, N);

    float4* x4 = (float4*)bufA;                                  // N*16B = 1.6 MB, L2-resident
    k_l1_transform<<<(N + 3) / 4, 256, 0, stream>>>(cp[0], cp[2], cp[3], cp[4], x4, as1, ad1, N);
    float* x1 = bufB;
    k_l1_agg<<<(N + 15) / 16, 256, 0, stream>>>(x4, (const float4*)as1, (const float4*)ad1,
                                                csr_off, csr, cp[2], cp[5], x1, N);

    unsigned short* hlb = (unsigned short*)bufA;                 // N*32 bf16 = 6.4 MB
    float* hr = bufA + (size_t)N * 16;
    k_l2_transform<<<(N + 63) / 64, 256, 0, stream>>>(x1, cp[6], cp[7], cp[8], cp[9], hlb, hr, N);
    float* x2 = bufB;
    k_l2_agg<<<(N + 15) / 16, 256, 0, stream>>>(hlb, hr, cp[10], cp[11], csr_off, csr, x2, N);

    float* QS = bufA;                                            // N*16 floats
    float* KV = bufA + (size_t)N * 16;                           // N*16 floats
    k_l3_transform<<<(N + 127) / 128, 256, 0, stream>>>(x2, (const float4*)Wcat, (const float4*)bcat,
                                                        QS, KV, N);
    k_l3_agg<<<(N + 31) / 32, 256, 0, stream>>>(QS, KV, csr_off, csr, out, N);
}

// Round 11
// 304.278 us; speedup vs baseline: 1.6473x; 1.1050x over previous
//
#include <hip/hip_runtime.h>
#include <hip/hip_bf16.h>

typedef __hip_bfloat16 bf16;

static __device__ __forceinline__ float us2f(unsigned short u) {
    union { unsigned int i; float f; } c; c.i = ((unsigned int)u) << 16; return c.f;
}
static __device__ __forceinline__ unsigned short f2us(float f) {
    union { float f; unsigned int i; } c; c.f = f;
    unsigned int r = c.i + 0x7FFF + ((c.i >> 16) & 1);   // round-to-nearest-even
    return (unsigned short)(r >> 16);
}

// ---------------- dtype probe + canonicalization ----------------

__global__ __launch_bounds__(256) void k_detect(const unsigned short* __restrict__ xr,
                                                const int* __restrict__ er,
                                                int* __restrict__ flags) {
    __shared__ int sbad, snz;
    int tid = threadIdx.x;
    if (tid == 0) { sbad = 0; snz = 0; }
    __syncthreads();
    int bad = 0, nz = 0;
    for (int i = tid; i < 1024; i += 256) {
        unsigned short w = xr[2 * i];
        int ex = (w >> 7) & 0xFF;
        if (ex < 110 || ex > 135) bad++;
        if (er[2 * i + 1] != 0) nz++;
    }
    atomicAdd(&sbad, bad);
    atomicAdd(&snz, nz);
    __syncthreads();
    if (tid == 0) {
        flags[0] = (sbad > 256) ? 1 : 0;
        flags[1] = (snz < 512) ? 1 : 0;
    }
}

struct CvtArgs { const void* p[19]; int sz[19]; };

__global__ __launch_bounds__(256) void k_convert(CvtArgs a, const int* __restrict__ flags,
                                                 float* __restrict__ dst, int total) {
    int t = blockIdx.x * 256 + threadIdx.x;
    if (t >= total) return;
    int isf32 = flags[0];
    int base = 0, seg = -1, off = 0;
#pragma unroll
    for (int i = 0; i < 19; i++) {
        if (seg < 0 && t < base + a.sz[i]) { seg = i; off = t - base; }
        base += a.sz[i];
    }
    const void* p = a.p[seg];
    float v = isf32 ? ((const float*)p)[off] : __bfloat162float(((const bf16*)p)[off]);
    dst[t] = v;
}

static __device__ __forceinline__ int ld_edge(const int* er, size_t i, int idx64) {
    return idx64 ? er[2 * i] : er[i];
}

// ---------------- bucketed CSR build ----------------
// bucket b = dst >> 10 (1024 nodes per bucket), NB <= 256 assumed (N <= 262144)

__global__ __launch_bounds__(1024) void k_bhist(const int* __restrict__ er, const int* __restrict__ flags,
                                                int* __restrict__ bcnt, int E, int NB) {
    __shared__ int cnt[256];
    int tid = threadIdx.x;
    if (tid < 256) cnt[tid] = 0;
    __syncthreads();
    int idx64 = flags[1];
    int base = blockIdx.x * 4096 + tid;
#pragma unroll
    for (int k = 0; k < 4; ++k) {
        int e = base + k * 1024;
        if (e < E) {
            int d = ld_edge(er, (size_t)E + e, idx64);
            atomicAdd(&cnt[d >> 10], 1);
        }
    }
    __syncthreads();
    if (tid < NB && cnt[tid]) atomicAdd(&bcnt[tid], cnt[tid]);
}

__global__ __launch_bounds__(256) void k_bscan(const int* __restrict__ bcnt, int* __restrict__ bbase,
                                               int* __restrict__ bcur, int* __restrict__ csr_off,
                                               int NB, int N, int E) {
    __shared__ int sm[256];
    int tid = threadIdx.x;
    int v = (tid < NB) ? bcnt[tid] : 0;
    sm[tid] = v;
    __syncthreads();
    for (int d = 1; d < 256; d <<= 1) {
        int t = (tid >= d) ? sm[tid - d] : 0;
        __syncthreads();
        sm[tid] += t;
        __syncthreads();
    }
    int excl = sm[tid] - v;
    if (tid < NB) { bbase[tid] = excl; bcur[tid] = excl; }
    if (tid == 0) { bbase[NB] = E; csr_off[N] = E; }
}

__global__ __launch_bounds__(1024) void k_bscatter(const int* __restrict__ er, const int* __restrict__ flags,
                                                   int* __restrict__ bcur, int2* __restrict__ bkt,
                                                   int E, int NB) {
    __shared__ int cnt[256];
    __shared__ int res[256];
    int tid = threadIdx.x;
    if (tid < 256) cnt[tid] = 0;
    __syncthreads();
    int idx64 = flags[1];
    int base = blockIdx.x * 4096 + tid;
    int sv[4], dv[4], bv[4];
    bool val[4];
#pragma unroll
    for (int k = 0; k < 4; ++k) {
        int e = base + k * 1024;
        val[k] = (e < E);
        if (val[k]) {
            sv[k] = ld_edge(er, (size_t)e, idx64);
            dv[k] = ld_edge(er, (size_t)E + e, idx64);
            bv[k] = dv[k] >> 10;
            atomicAdd(&cnt[bv[k]], 1);
        }
    }
    __syncthreads();
    if (tid < NB) {
        int c = cnt[tid];
        res[tid] = c ? atomicAdd(&bcur[tid], c) : 0;
        cnt[tid] = 0;
    }
    __syncthreads();
#pragma unroll
    for (int k = 0; k < 4; ++k) {
        if (val[k]) {
            int r = atomicAdd(&cnt[bv[k]], 1);
            bkt[res[bv[k]] + r] = make_int2(sv[k], dv[k]);
        }
    }
}

__global__ __launch_bounds__(1024) void k_bbuild(const int2* __restrict__ bkt, const int* __restrict__ bbase,
                                                 int* __restrict__ csr_off, int* __restrict__ csr, int N) {
    __shared__ int sm[1024];
    int b = blockIdx.x, tid = threadIdx.x;
    int node0 = b << 10;
    int n0 = bbase[b], n1 = bbase[b + 1];
    int m = n1 - n0;
    sm[tid] = 0;
    __syncthreads();
    const int2* bp = bkt + n0;
    for (int i = tid; i < m; i += 1024) atomicAdd(&sm[bp[i].y - node0], 1);
    __syncthreads();
    int v = sm[tid];
    for (int d = 1; d < 1024; d <<= 1) {
        int t = (tid >= d) ? sm[tid - d] : 0;
        __syncthreads();
        sm[tid] += t;
        __syncthreads();
    }
    int excl = sm[tid] - v;
    int node = node0 + tid;
    if (node < N) csr_off[node] = n0 + excl;
    __syncthreads();
    sm[tid] = excl;
    __syncthreads();
    for (int i = tid; i < m; i += 1024) {
        int2 sd = bp[i];
        int r = atomicAdd(&sm[sd.y - node0], 1);
        csr[n0 + r] = sd.x;
    }
}

// ---------------- Layer 1: GATConv(3, 16, heads=4) ----------------

__global__ __launch_bounds__(256) void k_l1_transform(const float* __restrict__ x, const float* __restrict__ W1,
                                                      const float* __restrict__ att_s, const float* __restrict__ att_d,
                                                      float4* __restrict__ x4, float* __restrict__ as1,
                                                      float* __restrict__ ad1, int N) {
    int tid = threadIdx.x;
    int node = blockIdx.x * 4 + (tid >> 6);
    if (node >= N) return;
    int lane = tid & 63;
    float x0 = x[node * 3 + 0];
    float x1 = x[node * 3 + 1];
    float x2 = x[node * 3 + 2];
    float h = x0 * W1[lane] + x1 * W1[64 + lane] + x2 * W1[128 + lane];
    if (lane == 0) x4[node] = make_float4(x0, x1, x2, 0.f);
    float ts = h * att_s[lane];
    float td = h * att_d[lane];
    for (int m = 8; m >= 1; m >>= 1) { ts += __shfl_xor(ts, m); td += __shfl_xor(td, m); }
    if ((lane & 15) == 0) {
        as1[node * 4 + (lane >> 4)] = ts;
        ad1[node * 4 + (lane >> 4)] = td;
    }
}

// Edge-parallel: 16 lanes per node; accumulate per-head weighted x-3vec + denom, butterfly-reduce.
__global__ __launch_bounds__(256) void k_l1_agg(const float4* __restrict__ x4, const float4* __restrict__ as4,
                                                const float4* __restrict__ ad4p, const int* __restrict__ off,
                                                const int* __restrict__ csr, const float* __restrict__ W1,
                                                const float* __restrict__ b1,
                                                float* __restrict__ x1, int N) {
    int tid = threadIdx.x;
    int node = blockIdx.x * 16 + (tid >> 4);
    if (node >= N) return;
    int sl = tid & 15;
    int lane = tid & 63;
    int lb = lane & 48;

    float4 ad = ad4p[node];
    int e0 = off[node], e1 = off[node + 1];

    float v[16];
#pragma unroll
    for (int i = 0; i < 16; ++i) v[i] = 0.f;

    for (int jj = e0 + sl; jj < e1; jj += 16) {
        int s = csr[jj];
        float4 a = as4[s];
        float4 xv = x4[s];
        float z0 = a.x + ad.x, z1 = a.y + ad.y, z2 = a.z + ad.z, z3 = a.w + ad.w;
        z0 = (z0 > 0.f) ? z0 : 0.2f * z0;
        z1 = (z1 > 0.f) ? z1 : 0.2f * z1;
        z2 = (z2 > 0.f) ? z2 : 0.2f * z2;
        z3 = (z3 > 0.f) ? z3 : 0.2f * z3;
        float w0 = __expf(z0), w1 = __expf(z1), w2 = __expf(z2), w3 = __expf(z3);
        v[0] += w0 * xv.x; v[1] += w0 * xv.y; v[2]  += w0 * xv.z; v[3]  += w0;
        v[4] += w1 * xv.x; v[5] += w1 * xv.y; v[6]  += w1 * xv.z; v[7]  += w1;
        v[8] += w2 * xv.x; v[9] += w2 * xv.y; v[10] += w2 * xv.z; v[11] += w2;
        v[12] += w3 * xv.x; v[13] += w3 * xv.y; v[14] += w3 * xv.z; v[15] += w3;
    }

#pragma unroll
    for (int d = 8; d >= 1; d >>= 1) {
#pragma unroll
        for (int i = 0; i < 16; ++i) {
            if (i < d) {
                float a = v[i], b = v[i + d];
                float send = (sl & d) ? a : b;
                float recv = __shfl_xor(send, d);
                v[i] = ((sl & d) ? b : a) + recv;
            }
        }
    }
    float r = v[0];

    float agx[4], agy[4], agz[4], dn[4];
#pragma unroll
    for (int h = 0; h < 4; ++h) {
        agx[h] = __shfl(r, lb + 4 * h + 0);
        agy[h] = __shfl(r, lb + 4 * h + 1);
        agz[h] = __shfl(r, lb + 4 * h + 2);
        dn[h]  = __shfl(r, lb + 4 * h + 3);
    }

    {
        float4 a = as4[node];
        float4 xv = x4[node];
        float z0 = a.x + ad.x, z1 = a.y + ad.y, z2 = a.z + ad.z, z3 = a.w + ad.w;
        z0 = (z0 > 0.f) ? z0 : 0.2f * z0;
        z1 = (z1 > 0.f) ? z1 : 0.2f * z1;
        z2 = (z2 > 0.f) ? z2 : 0.2f * z2;
        z3 = (z3 > 0.f) ? z3 : 0.2f * z3;
        float w0 = __expf(z0), w1 = __expf(z1), w2 = __expf(z2), w3 = __expf(z3);
        agx[0] += w0 * xv.x; agy[0] += w0 * xv.y; agz[0] += w0 * xv.z; dn[0] += w0;
        agx[1] += w1 * xv.x; agy[1] += w1 * xv.y; agz[1] += w1 * xv.z; dn[1] += w1;
        agx[2] += w2 * xv.x; agy[2] += w2 * xv.y; agz[2] += w2 * xv.z; dn[2] += w2;
        agx[3] += w3 * xv.x; agy[3] += w3 * xv.y; agz[3] += w3 * xv.z; dn[3] += w3;
    }

#pragma unroll
    for (int h = 0; h < 4; ++h) {
        int j = h * 16 + sl;
        float inv = 1.f / (dn[h] + 1e-16f);
        float o = (agx[h] * W1[j] + agy[h] * W1[64 + j] + agz[h] * W1[128 + j]) * inv + b1[j];
        x1[(size_t)node * 64 + j] = (o > 0.f) ? o : 0.f;
    }
}

// ---------------- Layer 2: GATv2Conv(64, 16, heads=2) ----------------

// 64 nodes per 256-thread block; thread = 4-node x 4-col register tile of [hl|hr].
// k4 loop unroll capped at 2: full unroll hoisted 64 weight float4s -> 252 VGPR, 8.9% occupancy (r10).
__global__ __launch_bounds__(256) void k_l2_transform(const float* __restrict__ x1,
                                                      const float* __restrict__ W2l, const float* __restrict__ b2l,
                                                      const float* __restrict__ W2r, const float* __restrict__ b2r,
                                                      unsigned short* __restrict__ hlb, float* __restrict__ hr, int N) {
    __shared__ float xs[64 * 68];   // row stride 68: per-wave broadcast rows hit banks {0,4,8,12}
    int t = threadIdx.x;
    int node0 = blockIdx.x * 64;
    int nrem = N - node0; if (nrem > 64) nrem = 64;
    const float4* xg = (const float4*)x1;
#pragma unroll
    for (int it = 0; it < 4; ++it) {
        int id = it * 256 + t;
        int row = id >> 4, c4 = id & 15;
        float4 v = make_float4(0.f, 0.f, 0.f, 0.f);
        if (row < nrem) v = xg[(size_t)(node0 + row) * 16 + c4];
        *(float4*)&xs[row * 68 + c4 * 4] = v;
    }
    __syncthreads();
    int nt = t >> 4;
    int jt = t & 15;
    int jq = jt & 7;
    int jc = jq * 4;
    const float4* W4 = (const float4*)((jt < 8) ? W2l : W2r);
    const float4* B4 = (const float4*)((jt < 8) ? b2l : b2r);
    float4 bb = B4[jq];
    float4 acc[4];
#pragma unroll
    for (int i = 0; i < 4; ++i) acc[i] = bb;
#pragma unroll 2
    for (int k4 = 0; k4 < 16; ++k4) {
        float4 w0 = W4[(k4 * 4 + 0) * 8 + jq];
        float4 w1 = W4[(k4 * 4 + 1) * 8 + jq];
        float4 w2 = W4[(k4 * 4 + 2) * 8 + jq];
        float4 w3 = W4[(k4 * 4 + 3) * 8 + jq];
#pragma unroll
        for (int i = 0; i < 4; ++i) {
            float4 xv = *(const float4*)&xs[(nt + i * 16) * 68 + k4 * 4];
            acc[i].x += xv.x * w0.x + xv.y * w1.x + xv.z * w2.x + xv.w * w3.x;
            acc[i].y += xv.x * w0.y + xv.y * w1.y + xv.z * w2.y + xv.w * w3.y;
            acc[i].z += xv.x * w0.z + xv.y * w1.z + xv.z * w2.z + xv.w * w3.z;
            acc[i].w += xv.x * w0.w + xv.y * w1.w + xv.z * w2.w + xv.w * w3.w;
        }
    }
#pragma unroll
    for (int i = 0; i < 4; ++i) {
        int row = nt + i * 16;
        if (row < nrem) {
            size_t node = node0 + row;
            if (jt < 8) {
                uint2 p;
                p.x = (unsigned)f2us(acc[i].x) | ((unsigned)f2us(acc[i].y) << 16);
                p.y = (unsigned)f2us(acc[i].z) | ((unsigned)f2us(acc[i].w) << 16);
                *(uint2*)&hlb[node * 32 + jc] = p;
            } else {
                *(float4*)&hr[node * 32 + jc] = acc[i];
            }
        }
    }
}

// Edge-parallel: 16 lanes per node, lane = edge slot. Full 64B hl row per edge (4x uint4),
// both head logits computed in-register (zero per-edge shfl); one butterfly per node.
__global__ __launch_bounds__(256) void k_l2_agg(const unsigned short* __restrict__ hlb, const float* __restrict__ hr,
                                                const float* __restrict__ att2, const float* __restrict__ b2,
                                                const int* __restrict__ off, const int* __restrict__ csr,
                                                float* __restrict__ x2, int N) {
    int tid = threadIdx.x;
    int node = blockIdx.x * 16 + (tid >> 4);
    if (node >= N) return;
    int sl = tid & 15;

    // hr row in registers (constant-indexed via full unroll)
    float hrd[32];
    {
        const float4* hr4 = (const float4*)(hr + (size_t)node * 32);
#pragma unroll
        for (int q = 0; q < 8; ++q) {
            float4 v = hr4[q];
            hrd[4 * q + 0] = v.x; hrd[4 * q + 1] = v.y;
            hrd[4 * q + 2] = v.z; hrd[4 * q + 3] = v.w;
        }
    }

    float accA[16], accB[16];
#pragma unroll
    for (int i = 0; i < 16; ++i) { accA[i] = 0.f; accB[i] = 0.f; }
    float den0 = 0.f, den1 = 0.f;

    int e0 = off[node], e1 = off[node + 1];
    for (int jj = e0 + sl; jj < e1; jj += 16) {
        int s = csr[jj];
        const uint4* hp = (const uint4*)(hlb + (size_t)s * 32);
        uint4 u0 = hp[0], u1 = hp[1], u2 = hp[2], u3 = hp[3];
        unsigned int uu[16] = {u0.x, u0.y, u0.z, u0.w, u1.x, u1.y, u1.z, u1.w,
                               u2.x, u2.y, u2.z, u2.w, u3.x, u3.y, u3.z, u3.w};
        float t0 = 0.f, t1 = 0.f;
#pragma unroll
        for (int q = 0; q < 8; ++q) {
            float lo = __uint_as_float(uu[q] << 16);
            float hi = __uint_as_float(uu[q] & 0xFFFF0000u);
            float el = lo + hrd[2 * q];     el = fmaxf(el, 0.2f * el);
            float eh = hi + hrd[2 * q + 1]; eh = fmaxf(eh, 0.2f * eh);
            t0 += att2[2 * q] * el + att2[2 * q + 1] * eh;
        }
#pragma unroll
        for (int q = 8; q < 16; ++q) {
            float lo = __uint_as_float(uu[q] << 16);
            float hi = __uint_as_float(uu[q] & 0xFFFF0000u);
            float el = lo + hrd[2 * q];     el = fmaxf(el, 0.2f * el);
            float eh = hi + hrd[2 * q + 1]; eh = fmaxf(eh, 0.2f * eh);
            t1 += att2[2 * q] * el + att2[2 * q + 1] * eh;
        }
        float w0 = __expf(t0), w1 = __expf(t1);
        den0 += w0; den1 += w1;
#pragma unroll
        for (int q = 0; q < 8; ++q) {
            accA[2 * q]     += w0 * __uint_as_float(uu[q] << 16);
            accA[2 * q + 1] += w0 * __uint_as_float(uu[q] & 0xFFFF0000u);
        }
#pragma unroll
        for (int q = 8; q < 16; ++q) {
            accB[2 * (q - 8)]     += w1 * __uint_as_float(uu[q] << 16);
            accB[2 * (q - 8) + 1] += w1 * __uint_as_float(uu[q] & 0xFFFF0000u);
        }
    }

    // butterfly-reduce 16+16 accs and 2 dens across the 16-lane group
#pragma unroll
    for (int d = 8; d >= 1; d >>= 1) {
#pragma unroll
        for (int i = 0; i < 16; ++i) {
            if (i < d) {
                { float a = accA[i], b = accA[i + d];
                  float send = (sl & d) ? a : b;
                  float recv = __shfl_xor(send, d);
                  accA[i] = ((sl & d) ? b : a) + recv; }
                { float a = accB[i], b = accB[i + d];
                  float send = (sl & d) ? a : b;
                  float recv = __shfl_xor(send, d);
                  accB[i] = ((sl & d) ? b : a) + recv; }
            }
        }
        den0 += __shfl_xor(den0, d);
        den1 += __shfl_xor(den1, d);
    }
    float sumA = accA[0];   // channel sl (head 0)
    float sumB = accB[0];   // channel 16+sl (head 1)

    // self-loop (cooperative: lane sl holds channels sl and 16+sl)
    float hr0 = hr[(size_t)node * 32 + sl];
    float hr1 = hr[(size_t)node * 32 + 16 + sl];
    float hl0 = us2f(hlb[(size_t)node * 32 + sl]);
    float hl1 = us2f(hlb[(size_t)node * 32 + 16 + sl]);
    float ea = hl0 + hr0; ea = fmaxf(ea, 0.2f * ea);
    float eb = hl1 + hr1; eb = fmaxf(eb, 0.2f * eb);
    float p0 = att2[sl] * ea;
    float p1 = att2[16 + sl] * eb;
    p0 += __shfl_xor(p0, 1); p0 += __shfl_xor(p0, 2); p0 += __shfl_xor(p0, 4); p0 += __shfl_xor(p0, 8);
    p1 += __shfl_xor(p1, 1); p1 += __shfl_xor(p1, 2); p1 += __shfl_xor(p1, 4); p1 += __shfl_xor(p1, 8);
    float w0 = __expf(p0), w1 = __expf(p1);
    sumA += w0 * hl0; den0 += w0;
    sumB += w1 * hl1; den1 += w1;

    x2[(size_t)node * 32 + sl]      = sumA / (den0 + 1e-16f) + b2[sl];
    x2[(size_t)node * 32 + 16 + sl] = sumB / (den1 + 1e-16f) + b2[16 + sl];
}

// ---------------- Layer 3: TransformerConv(32, 7, heads=1) ----------------

// pack Wq/Wsk/Wk/Wv -> Wcat[32][32] whose output row is {q0..6,0,sk0..6,0,k0..6,0,v0..6,0}
__global__ __launch_bounds__(1024) void k_l3_wcat(const float* __restrict__ Wq, const float* __restrict__ bq,
                                                  const float* __restrict__ Wk, const float* __restrict__ bk,
                                                  const float* __restrict__ Wv, const float* __restrict__ bv,
                                                  const float* __restrict__ Ws, const float* __restrict__ bs,
                                                  float* __restrict__ Wcat, float* __restrict__ bcat) {
    int t = threadIdx.x;
    int c = t & 31, g = c >> 3, cc = c & 7;
    const float* Wg = (g == 0) ? Wq : (g == 1) ? Ws : (g == 2) ? Wk : Wv;
    const float* Bg = (g == 0) ? bq : (g == 1) ? bs : (g == 2) ? bk : bv;
    int kk = t >> 5;
    Wcat[t] = (cc < 7) ? Wg[kk * 7 + cc] : 0.f;
    if (t < 32) bcat[t] = (cc < 7) ? Bg[cc] : 0.f;
}

// 128 nodes per 256-thread block; thread = 4-node x 4-col tile; cols map to QS|KV directly.
// k4 unroll capped at 2 (see k_l2_transform note).
__global__ __launch_bounds__(256) void k_l3_transform(const float* __restrict__ x2,
                                                      const float4* __restrict__ Wc4, const float4* __restrict__ bc4,
                                                      float* __restrict__ QS, float* __restrict__ KV, int N) {
    __shared__ float xs[128 * 36];
    int t = threadIdx.x;
    int node0 = blockIdx.x * 128;
    int nrem = N - node0; if (nrem > 128) nrem = 128;
    const float4* xg = (const float4*)x2;
#pragma unroll
    for (int it = 0; it < 4; ++it) {
        int id = it * 256 + t;
        int row = id >> 3, c4 = id & 7;
        float4 v = make_float4(0.f, 0.f, 0.f, 0.f);
        if (row < nrem) v = xg[(size_t)(node0 + row) * 8 + c4];
        *(float4*)&xs[row * 36 + c4 * 4] = v;
    }
    __syncthreads();
    int nt = t >> 3;
    int jt = t & 7;
    float4 bb = bc4[jt];
    float4 acc[4];
#pragma unroll
    for (int i = 0; i < 4; ++i) acc[i] = bb;
#pragma unroll 2
    for (int k4 = 0; k4 < 8; ++k4) {
        float4 w0 = Wc4[(k4 * 4 + 0) * 8 + jt];
        float4 w1 = Wc4[(k4 * 4 + 1) * 8 + jt];
        float4 w2 = Wc4[(k4 * 4 + 2) * 8 + jt];
        float4 w3 = Wc4[(k4 * 4 + 3) * 8 + jt];
#pragma unroll
        for (int i = 0; i < 4; ++i) {
            float4 xv = *(const float4*)&xs[(nt + i * 32) * 36 + k4 * 4];
            acc[i].x += xv.x * w0.x + xv.y * w1.x + xv.z * w2.x + xv.w * w3.x;
            acc[i].y += xv.x * w0.y + xv.y * w1.y + xv.z * w2.y + xv.w * w3.y;
            acc[i].z += xv.x * w0.z + xv.y * w1.z + xv.z * w2.z + xv.w * w3.z;
            acc[i].w += xv.x * w0.w + xv.y * w1.w + xv.z * w2.w + xv.w * w3.w;
        }
    }
#pragma unroll
    for (int i = 0; i < 4; ++i) {
        int row = nt + i * 32;
        if (row < nrem) {
            size_t node = node0 + row;
            float* dst = (jt < 4) ? (QS + node * 16 + jt * 4) : (KV + node * 16 + (jt - 4) * 4);
            *(float4*)dst = acc[i];
        }
    }
}

// Edge-parallel: 8 lanes per node, lane = edge slot; K|V row per edge (4x float4),
// dot in-register, exactly 8 reduction values (7 acc + den) butterflied over 8 lanes.
__global__ __launch_bounds__(256) void k_l3_agg(const float* __restrict__ QS, const float* __restrict__ KV,
                                                const int* __restrict__ off, const int* __restrict__ csr,
                                                float* __restrict__ out, int N) {
    int tid = threadIdx.x;
    int node = blockIdx.x * 32 + (tid >> 3);
    if (node >= N) return;
    int sl = tid & 7;
    int lane = tid & 63;
    const float scale = 0.3779644730092272f;  // 1/sqrt(7)
    const float4* q4 = (const float4*)(QS + (size_t)node * 16);
    float4 qa = q4[0], qb = q4[1];           // qb.w is pad
    qa.x *= scale; qa.y *= scale; qa.z *= scale; qa.w *= scale;
    qb.x *= scale; qb.y *= scale; qb.z *= scale; qb.w = 0.f;

    float v[8];
#pragma unroll
    for (int i = 0; i < 8; ++i) v[i] = 0.f;

    int e0 = off[node], e1 = off[node + 1];
    for (int jj = e0 + sl; jj < e1; jj += 8) {
        int s = csr[jj];
        const float4* kp = (const float4*)(KV + (size_t)s * 16);
        float4 k0 = kp[0], k1 = kp[1], v0 = kp[2], v1 = kp[3];
        float t = qa.x * k0.x + qa.y * k0.y + qa.z * k0.z + qa.w * k0.w
                + qb.x * k1.x + qb.y * k1.y + qb.z * k1.z;
        float w = __expf(t);
        v[0] += w * v0.x; v[1] += w * v0.y; v[2] += w * v0.z; v[3] += w * v0.w;
        v[4] += w * v1.x; v[5] += w * v1.y; v[6] += w * v1.z; v[7] += w;
    }
#pragma unroll
    for (int d = 4; d >= 1; d >>= 1) {
#pragma unroll
        for (int i = 0; i < 8; ++i) {
            if (i < d) {
                float a = v[i], b = v[i + d];
                float send = (sl & d) ? a : b;
                float recv = __shfl_xor(send, d);
                v[i] = ((sl & d) ? b : a) + recv;
            }
        }
    }
    float r = v[0];                                // value index sl
    float den = __shfl(r, (lane & 56) + 7);        // value 7 = denominator
    if (sl < 7) out[(size_t)node * 7 + sl] = r / (den + 1e-16f)
                                             + QS[(size_t)node * 16 + 8 + sl];
}

// ---------------- launcher ----------------

extern "C" void kernel_launch(void* const* d_in, const int* in_sizes, int n_in,
                              void* d_out, int out_size, void* d_ws, size_t ws_size,
                              hipStream_t stream) {
    const int* ei = (const int*)d_in[1];
    float* out = (float*)d_out;

    int N = in_sizes[0] / 3;
    int E = in_sizes[1] / 2;
    int NB = (N + 1023) >> 10;   // assumed <= 256 (N <= 262144)

    char* ws = (char*)d_ws;
    size_t o = 0;
    auto take = [&](size_t bytes) -> char* {
        char* p = ws + o;
        o = (o + bytes + 255) & ~(size_t)255;
        return p;
    };
    int*   flags   = (int*)take(64);
    int total_f = 0;
    for (int i = 0; i < 20; ++i) if (i != 1) total_f += in_sizes[i];
    float* canon   = (float*)take((size_t)total_f * 4);
    float* Wcat    = (float*)take(32 * 32 * 4);
    float* bcat    = (float*)take(32 * 4);
    int*   csr_off = (int*)take((size_t)(N + 1) * 4);
    int*   bcnt    = (int*)take(256 * 4);
    int*   bbase   = (int*)take(257 * 4);
    int*   bcur    = (int*)take(256 * 4);
    int*   csr     = (int*)take((size_t)E * 4);
    float* bufA    = (float*)take((size_t)N * 64 * 4);  // x4 -> hlb|hr -> QS|KV
    float* as1     = (float*)take((size_t)N * 4 * 4);
    float* ad1     = (float*)take((size_t)N * 4 * 4);
    float* bufB    = (float*)take((size_t)N * 64 * 4);  // bkt -> x1 -> x2
    (void)ws_size; (void)n_in; (void)out_size;

    CvtArgs ca;
    const float* cp[20];
    {
        int off_ = 0, k = 0;
        for (int i = 0; i < 20; ++i) {
            if (i == 1) { cp[i] = nullptr; continue; }
            ca.p[k] = d_in[i];
            ca.sz[k] = in_sizes[i];
            cp[i] = canon + off_;
            off_ += in_sizes[i];
            ++k;
        }
    }

    hipMemsetAsync(bcnt, 0, 256 * 4, stream);
    k_detect<<<1, 256, 0, stream>>>((const unsigned short*)d_in[0], ei, flags);
    k_convert<<<(total_f + 255) / 256, 256, 0, stream>>>(ca, flags, canon, total_f);
    k_l3_wcat<<<1, 1024, 0, stream>>>(cp[12], cp[13], cp[14], cp[15], cp[16], cp[17],
                                      cp[18], cp[19], Wcat, bcat);

    int2* bkt = (int2*)bufB;
    int gb = (E + 4095) / 4096;
    k_bhist<<<gb, 1024, 0, stream>>>(ei, flags, bcnt, E, NB);
    k_bscan<<<1, 256, 0, stream>>>(bcnt, bbase, bcur, csr_off, NB, N, E);
    k_bscatter<<<gb, 1024, 0, stream>>>(ei, flags, bcur, bkt, E, NB);
    k_bbuild<<<NB, 1024, 0, stream>>>(bkt, bbase, csr_off, csr, N);

    float4* x4 = (float4*)bufA;                                  // N*16B = 1.6 MB, L2-resident
    k_l1_transform<<<(N + 3) / 4, 256, 0, stream>>>(cp[0], cp[2], cp[3], cp[4], x4, as1, ad1, N);
    float* x1 = bufB;
    k_l1_agg<<<(N + 15) / 16, 256, 0, stream>>>(x4, (const float4*)as1, (const float4*)ad1,
                                                csr_off, csr, cp[2], cp[5], x1, N);

    unsigned short* hlb = (unsigned short*)bufA;                 // N*32 bf16 = 6.4 MB
    float* hr = bufA + (size_t)N * 16;
    k_l2_transform<<<(N + 63) / 64, 256, 0, stream>>>(x1, cp[6], cp[7], cp[8], cp[9], hlb, hr, N);
    float* x2 = bufB;
    k_l2_agg<<<(N + 15) / 16, 256, 0, stream>>>(hlb, hr, cp[10], cp[11], csr_off, csr, x2, N);

    float* QS = bufA;                                            // N*16 floats
    float* KV = bufA + (size_t)N * 16;                           // N*16 floats
    k_l3_transform<<<(N + 127) / 128, 256, 0, stream>>>(x2, (const float4*)Wcat, (const float4*)bcat,
                                                        QS, KV, N);
    k_l3_agg<<<(N + 31) / 32, 256, 0, stream>>>(QS, KV, csr_off, csr, out, N);
}

// Round 12
// 289.808 us; speedup vs baseline: 1.7295x; 1.0499x over previous
//
#include <hip/hip_runtime.h>
#include <hip/hip_bf16.h>

typedef __hip_bfloat16 bf16;

static __device__ __forceinline__ float us2f(unsigned short u) {
    union { unsigned int i; float f; } c; c.i = ((unsigned int)u) << 16; return c.f;
}
static __device__ __forceinline__ unsigned short f2us(float f) {
    union { float f; unsigned int i; } c; c.f = f;
    unsigned int r = c.i + 0x7FFF + ((c.i >> 16) & 1);   // round-to-nearest-even
    return (unsigned short)(r >> 16);
}

// ---------------- dtype probe + canonicalization ----------------

__global__ __launch_bounds__(256) void k_detect(const unsigned short* __restrict__ xr,
                                                const int* __restrict__ er,
                                                int* __restrict__ flags) {
    __shared__ int sbad, snz;
    int tid = threadIdx.x;
    if (tid == 0) { sbad = 0; snz = 0; }
    __syncthreads();
    int bad = 0, nz = 0;
    for (int i = tid; i < 1024; i += 256) {
        unsigned short w = xr[2 * i];
        int ex = (w >> 7) & 0xFF;
        if (ex < 110 || ex > 135) bad++;
        if (er[2 * i + 1] != 0) nz++;
    }
    atomicAdd(&sbad, bad);
    atomicAdd(&snz, nz);
    __syncthreads();
    if (tid == 0) {
        flags[0] = (sbad > 256) ? 1 : 0;
        flags[1] = (snz < 512) ? 1 : 0;
    }
}

struct CvtArgs { const void* p[19]; int sz[19]; };

__global__ __launch_bounds__(256) void k_convert(CvtArgs a, const int* __restrict__ flags,
                                                 float* __restrict__ dst, int total) {
    int t = blockIdx.x * 256 + threadIdx.x;
    if (t >= total) return;
    int isf32 = flags[0];
    int base = 0, seg = -1, off = 0;
#pragma unroll
    for (int i = 0; i < 19; i++) {
        if (seg < 0 && t < base + a.sz[i]) { seg = i; off = t - base; }
        base += a.sz[i];
    }
    const void* p = a.p[seg];
    float v = isf32 ? ((const float*)p)[off] : __bfloat162float(((const bf16*)p)[off]);
    dst[t] = v;
}

static __device__ __forceinline__ int ld_edge(const int* er, size_t i, int idx64) {
    return idx64 ? er[2 * i] : er[i];
}

// ---------------- bucketed CSR build (fixed-capacity buckets, no hist/scan) ----------------
// bucket b = dst >> 10 (1024 nodes per bucket), NB <= 256 assumed (N <= 262144).
// bkt and csr are bucket-strided with capacity C; bcur (zero-init) doubles as bucket count.

__global__ __launch_bounds__(1024) void k_bscatter(const int* __restrict__ er, const int* __restrict__ flags,
                                                   int* __restrict__ bcur, int2* __restrict__ bkt,
                                                   int E, int NB, int C) {
    __shared__ int cnt[256];
    __shared__ int res[256];
    int tid = threadIdx.x;
    if (tid < 256) cnt[tid] = 0;
    __syncthreads();
    int idx64 = flags[1];
    int base = blockIdx.x * 4096 + tid;
    int sv[4], dv[4], bv[4];
    bool val[4];
#pragma unroll
    for (int k = 0; k < 4; ++k) {
        int e = base + k * 1024;
        val[k] = (e < E);
        if (val[k]) {
            sv[k] = ld_edge(er, (size_t)e, idx64);
            dv[k] = ld_edge(er, (size_t)E + e, idx64);
            bv[k] = dv[k] >> 10;
            atomicAdd(&cnt[bv[k]], 1);
        }
    }
    __syncthreads();
    if (tid < NB) {
        int c = cnt[tid];
        res[tid] = c ? atomicAdd(&bcur[tid], c) : 0;
        cnt[tid] = 0;
    }
    __syncthreads();
#pragma unroll
    for (int k = 0; k < 4; ++k) {
        if (val[k]) {
            int r = res[bv[k]] + atomicAdd(&cnt[bv[k]], 1);
            if (r < C) bkt[(size_t)bv[k] * C + r] = make_int2(sv[k], dv[k]);
        }
    }
}

// per bucket: indeg count + scan -> off2 (start,end); scatter src -> bucket-strided csr
__global__ __launch_bounds__(1024) void k_bbuild(const int2* __restrict__ bkt, const int* __restrict__ bcur,
                                                 int2* __restrict__ off2, int* __restrict__ csr, int N, int C) {
    __shared__ int sm[1024];
    int b = blockIdx.x, tid = threadIdx.x;
    int node0 = b << 10;
    size_t base = (size_t)b * C;
    int m = bcur[b]; if (m > C) m = C;
    sm[tid] = 0;
    __syncthreads();
    const int2* bp = bkt + base;
    for (int i = tid; i < m; i += 1024) atomicAdd(&sm[bp[i].y - node0], 1);
    __syncthreads();
    int v = sm[tid];
    for (int d = 1; d < 1024; d <<= 1) {
        int t = (tid >= d) ? sm[tid - d] : 0;
        __syncthreads();
        sm[tid] += t;
        __syncthreads();
    }
    int excl = sm[tid] - v;
    int node = node0 + tid;
    if (node < N) off2[node] = make_int2((int)base + excl, (int)base + excl + v);
    __syncthreads();
    sm[tid] = excl;
    __syncthreads();
    for (int i = tid; i < m; i += 1024) {
        int2 sd = bp[i];
        int r = atomicAdd(&sm[sd.y - node0], 1);
        csr[base + r] = sd.x;
    }
}

// ---------------- Layer 1: GATConv(3, 16, heads=4) ----------------

__global__ __launch_bounds__(256) void k_l1_transform(const float* __restrict__ x, const float* __restrict__ W1,
                                                      const float* __restrict__ att_s, const float* __restrict__ att_d,
                                                      float4* __restrict__ x4, float* __restrict__ as1,
                                                      float* __restrict__ ad1, int N) {
    int tid = threadIdx.x;
    int node = blockIdx.x * 4 + (tid >> 6);
    if (node >= N) return;
    int lane = tid & 63;
    float x0 = x[node * 3 + 0];
    float x1 = x[node * 3 + 1];
    float x2 = x[node * 3 + 2];
    float h = x0 * W1[lane] + x1 * W1[64 + lane] + x2 * W1[128 + lane];
    if (lane == 0) x4[node] = make_float4(x0, x1, x2, 0.f);
    float ts = h * att_s[lane];
    float td = h * att_d[lane];
    for (int m = 8; m >= 1; m >>= 1) { ts += __shfl_xor(ts, m); td += __shfl_xor(td, m); }
    if ((lane & 15) == 0) {
        as1[node * 4 + (lane >> 4)] = ts;
        ad1[node * 4 + (lane >> 4)] = td;
    }
}

// Edge-parallel: 16 lanes per node; accumulate per-head weighted x-3vec + denom, butterfly-reduce.
__global__ __launch_bounds__(256) void k_l1_agg(const float4* __restrict__ x4, const float4* __restrict__ as4,
                                                const float4* __restrict__ ad4p, const int2* __restrict__ off2,
                                                const int* __restrict__ csr, const float* __restrict__ W1,
                                                const float* __restrict__ b1,
                                                float* __restrict__ x1, int N) {
    int tid = threadIdx.x;
    int node = blockIdx.x * 16 + (tid >> 4);
    if (node >= N) return;
    int sl = tid & 15;
    int lane = tid & 63;
    int lb = lane & 48;

    float4 ad = ad4p[node];
    int2 ee = off2[node];
    int e0 = ee.x, e1 = ee.y;

    float v[16];
#pragma unroll
    for (int i = 0; i < 16; ++i) v[i] = 0.f;

    for (int jj = e0 + sl; jj < e1; jj += 16) {
        int s = csr[jj];
        float4 a = as4[s];
        float4 xv = x4[s];
        float z0 = a.x + ad.x, z1 = a.y + ad.y, z2 = a.z + ad.z, z3 = a.w + ad.w;
        z0 = (z0 > 0.f) ? z0 : 0.2f * z0;
        z1 = (z1 > 0.f) ? z1 : 0.2f * z1;
        z2 = (z2 > 0.f) ? z2 : 0.2f * z2;
        z3 = (z3 > 0.f) ? z3 : 0.2f * z3;
        float w0 = __expf(z0), w1 = __expf(z1), w2 = __expf(z2), w3 = __expf(z3);
        v[0] += w0 * xv.x; v[1] += w0 * xv.y; v[2]  += w0 * xv.z; v[3]  += w0;
        v[4] += w1 * xv.x; v[5] += w1 * xv.y; v[6]  += w1 * xv.z; v[7]  += w1;
        v[8] += w2 * xv.x; v[9] += w2 * xv.y; v[10] += w2 * xv.z; v[11] += w2;
        v[12] += w3 * xv.x; v[13] += w3 * xv.y; v[14] += w3 * xv.z; v[15] += w3;
    }

#pragma unroll
    for (int d = 8; d >= 1; d >>= 1) {
#pragma unroll
        for (int i = 0; i < 16; ++i) {
            if (i < d) {
                float a = v[i], b = v[i + d];
                float send = (sl & d) ? a : b;
                float recv = __shfl_xor(send, d);
                v[i] = ((sl & d) ? b : a) + recv;
            }
        }
    }
    float r = v[0];

    float agx[4], agy[4], agz[4], dn[4];
#pragma unroll
    for (int h = 0; h < 4; ++h) {
        agx[h] = __shfl(r, lb + 4 * h + 0);
        agy[h] = __shfl(r, lb + 4 * h + 1);
        agz[h] = __shfl(r, lb + 4 * h + 2);
        dn[h]  = __shfl(r, lb + 4 * h + 3);
    }

    {
        float4 a = as4[node];
        float4 xv = x4[node];
        float z0 = a.x + ad.x, z1 = a.y + ad.y, z2 = a.z + ad.z, z3 = a.w + ad.w;
        z0 = (z0 > 0.f) ? z0 : 0.2f * z0;
        z1 = (z1 > 0.f) ? z1 : 0.2f * z1;
        z2 = (z2 > 0.f) ? z2 : 0.2f * z2;
        z3 = (z3 > 0.f) ? z3 : 0.2f * z3;
        float w0 = __expf(z0), w1 = __expf(z1), w2 = __expf(z2), w3 = __expf(z3);
        agx[0] += w0 * xv.x; agy[0] += w0 * xv.y; agz[0] += w0 * xv.z; dn[0] += w0;
        agx[1] += w1 * xv.x; agy[1] += w1 * xv.y; agz[1] += w1 * xv.z; dn[1] += w1;
        agx[2] += w2 * xv.x; agy[2] += w2 * xv.y; agz[2] += w2 * xv.z; dn[2] += w2;
        agx[3] += w3 * xv.x; agy[3] += w3 * xv.y; agz[3] += w3 * xv.z; dn[3] += w3;
    }

#pragma unroll
    for (int h = 0; h < 4; ++h) {
        int j = h * 16 + sl;
        float inv = 1.f / (dn[h] + 1e-16f);
        float o = (agx[h] * W1[j] + agy[h] * W1[64 + j] + agz[h] * W1[128 + j]) * inv + b1[j];
        x1[(size_t)node * 64 + j] = (o > 0.f) ? o : 0.f;
    }
}

// ---------------- Layer 2: GATv2Conv(64, 16, heads=2) ----------------

// 64 nodes per 256-thread block; thread = 4-node x 4-col register tile of [hl|hr].
// k4 loop unroll capped at 2: full unroll hoisted 64 weight float4s -> 252 VGPR, 8.9% occupancy (r10).
__global__ __launch_bounds__(256) void k_l2_transform(const float* __restrict__ x1,
                                                      const float* __restrict__ W2l, const float* __restrict__ b2l,
                                                      const float* __restrict__ W2r, const float* __restrict__ b2r,
                                                      unsigned short* __restrict__ hlb, float* __restrict__ hr, int N) {
    __shared__ float xs[64 * 68];   // row stride 68: per-wave broadcast rows hit banks {0,4,8,12}
    int t = threadIdx.x;
    int node0 = blockIdx.x * 64;
    int nrem = N - node0; if (nrem > 64) nrem = 64;
    const float4* xg = (const float4*)x1;
#pragma unroll
    for (int it = 0; it < 4; ++it) {
        int id = it * 256 + t;
        int row = id >> 4, c4 = id & 15;
        float4 v = make_float4(0.f, 0.f, 0.f, 0.f);
        if (row < nrem) v = xg[(size_t)(node0 + row) * 16 + c4];
        *(float4*)&xs[row * 68 + c4 * 4] = v;
    }
    __syncthreads();
    int nt = t >> 4;
    int jt = t & 15;
    int jq = jt & 7;
    int jc = jq * 4;
    const float4* W4 = (const float4*)((jt < 8) ? W2l : W2r);
    const float4* B4 = (const float4*)((jt < 8) ? b2l : b2r);
    float4 bb = B4[jq];
    float4 acc[4];
#pragma unroll
    for (int i = 0; i < 4; ++i) acc[i] = bb;
#pragma unroll 2
    for (int k4 = 0; k4 < 16; ++k4) {
        float4 w0 = W4[(k4 * 4 + 0) * 8 + jq];
        float4 w1 = W4[(k4 * 4 + 1) * 8 + jq];
        float4 w2 = W4[(k4 * 4 + 2) * 8 + jq];
        float4 w3 = W4[(k4 * 4 + 3) * 8 + jq];
#pragma unroll
        for (int i = 0; i < 4; ++i) {
            float4 xv = *(const float4*)&xs[(nt + i * 16) * 68 + k4 * 4];
            acc[i].x += xv.x * w0.x + xv.y * w1.x + xv.z * w2.x + xv.w * w3.x;
            acc[i].y += xv.x * w0.y + xv.y * w1.y + xv.z * w2.y + xv.w * w3.y;
            acc[i].z += xv.x * w0.z + xv.y * w1.z + xv.z * w2.z + xv.w * w3.z;
            acc[i].w += xv.x * w0.w + xv.y * w1.w + xv.z * w2.w + xv.w * w3.w;
        }
    }
#pragma unroll
    for (int i = 0; i < 4; ++i) {
        int row = nt + i * 16;
        if (row < nrem) {
            size_t node = node0 + row;
            if (jt < 8) {
                uint2 p;
                p.x = (unsigned)f2us(acc[i].x) | ((unsigned)f2us(acc[i].y) << 16);
                p.y = (unsigned)f2us(acc[i].z) | ((unsigned)f2us(acc[i].w) << 16);
                *(uint2*)&hlb[node * 32 + jc] = p;
            } else {
                *(float4*)&hr[node * 32 + jc] = acc[i];
            }
        }
    }
}

// Edge-parallel: 16 lanes per node, lane = edge slot. Full 64B hl row per edge (4x uint4),
// both head logits computed in-register (zero per-edge shfl); one butterfly per node.
__global__ __launch_bounds__(256) void k_l2_agg(const unsigned short* __restrict__ hlb, const float* __restrict__ hr,
                                                const float* __restrict__ att2, const float* __restrict__ b2,
                                                const int2* __restrict__ off2, const int* __restrict__ csr,
                                                float* __restrict__ x2, int N) {
    int tid = threadIdx.x;
    int node = blockIdx.x * 16 + (tid >> 4);
    if (node >= N) return;
    int sl = tid & 15;

    // hr row in registers (constant-indexed via full unroll)
    float hrd[32];
    {
        const float4* hr4 = (const float4*)(hr + (size_t)node * 32);
#pragma unroll
        for (int q = 0; q < 8; ++q) {
            float4 v = hr4[q];
            hrd[4 * q + 0] = v.x; hrd[4 * q + 1] = v.y;
            hrd[4 * q + 2] = v.z; hrd[4 * q + 3] = v.w;
        }
    }

    float accA[16], accB[16];
#pragma unroll
    for (int i = 0; i < 16; ++i) { accA[i] = 0.f; accB[i] = 0.f; }
    float den0 = 0.f, den1 = 0.f;

    int2 ee = off2[node];
    int e0 = ee.x, e1 = ee.y;
    for (int jj = e0 + sl; jj < e1; jj += 16) {
        int s = csr[jj];
        const uint4* hp = (const uint4*)(hlb + (size_t)s * 32);
        uint4 u0 = hp[0], u1 = hp[1], u2 = hp[2], u3 = hp[3];
        unsigned int uu[16] = {u0.x, u0.y, u0.z, u0.w, u1.x, u1.y, u1.z, u1.w,
                               u2.x, u2.y, u2.z, u2.w, u3.x, u3.y, u3.z, u3.w};
        float t0 = 0.f, t1 = 0.f;
#pragma unroll
        for (int q = 0; q < 8; ++q) {
            float lo = __uint_as_float(uu[q] << 16);
            float hi = __uint_as_float(uu[q] & 0xFFFF0000u);
            float el = lo + hrd[2 * q];     el = fmaxf(el, 0.2f * el);
            float eh = hi + hrd[2 * q + 1]; eh = fmaxf(eh, 0.2f * eh);
            t0 += att2[2 * q] * el + att2[2 * q + 1] * eh;
        }
#pragma unroll
        for (int q = 8; q < 16; ++q) {
            float lo = __uint_as_float(uu[q] << 16);
            float hi = __uint_as_float(uu[q] & 0xFFFF0000u);
            float el = lo + hrd[2 * q];     el = fmaxf(el, 0.2f * el);
            float eh = hi + hrd[2 * q + 1]; eh = fmaxf(eh, 0.2f * eh);
            t1 += att2[2 * q] * el + att2[2 * q + 1] * eh;
        }
        float w0 = __expf(t0), w1 = __expf(t1);
        den0 += w0; den1 += w1;
#pragma unroll
        for (int q = 0; q < 8; ++q) {
            accA[2 * q]     += w0 * __uint_as_float(uu[q] << 16);
            accA[2 * q + 1] += w0 * __uint_as_float(uu[q] & 0xFFFF0000u);
        }
#pragma unroll
        for (int q = 8; q < 16; ++q) {
            accB[2 * (q - 8)]     += w1 * __uint_as_float(uu[q] << 16);
            accB[2 * (q - 8) + 1] += w1 * __uint_as_float(uu[q] & 0xFFFF0000u);
        }
    }

    // butterfly-reduce 16+16 accs and 2 dens across the 16-lane group
#pragma unroll
    for (int d = 8; d >= 1; d >>= 1) {
#pragma unroll
        for (int i = 0; i < 16; ++i) {
            if (i < d) {
                { float a = accA[i], b = accA[i + d];
                  float send = (sl & d) ? a : b;
                  float recv = __shfl_xor(send, d);
                  accA[i] = ((sl & d) ? b : a) + recv; }
                { float a = accB[i], b = accB[i + d];
                  float send = (sl & d) ? a : b;
                  float recv = __shfl_xor(send, d);
                  accB[i] = ((sl & d) ? b : a) + recv; }
            }
        }
        den0 += __shfl_xor(den0, d);
        den1 += __shfl_xor(den1, d);
    }
    float sumA = accA[0];   // channel sl (head 0)
    float sumB = accB[0];   // channel 16+sl (head 1)

    // self-loop (cooperative: lane sl holds channels sl and 16+sl)
    float hr0 = hr[(size_t)node * 32 + sl];
    float hr1 = hr[(size_t)node * 32 + 16 + sl];
    float hl0 = us2f(hlb[(size_t)node * 32 + sl]);
    float hl1 = us2f(hlb[(size_t)node * 32 + 16 + sl]);
    float ea = hl0 + hr0; ea = fmaxf(ea, 0.2f * ea);
    float eb = hl1 + hr1; eb = fmaxf(eb, 0.2f * eb);
    float p0 = att2[sl] * ea;
    float p1 = att2[16 + sl] * eb;
    p0 += __shfl_xor(p0, 1); p0 += __shfl_xor(p0, 2); p0 += __shfl_xor(p0, 4); p0 += __shfl_xor(p0, 8);
    p1 += __shfl_xor(p1, 1); p1 += __shfl_xor(p1, 2); p1 += __shfl_xor(p1, 4); p1 += __shfl_xor(p1, 8);
    float w0 = __expf(p0), w1 = __expf(p1);
    sumA += w0 * hl0; den0 += w0;
    sumB += w1 * hl1; den1 += w1;

    x2[(size_t)node * 32 + sl]      = sumA / (den0 + 1e-16f) + b2[sl];
    x2[(size_t)node * 32 + 16 + sl] = sumB / (den1 + 1e-16f) + b2[16 + sl];
}

// ---------------- Layer 3: TransformerConv(32, 7, heads=1) ----------------

// pack Wq/Wsk/Wk/Wv -> Wcat[32][32] whose output row is {q0..6,0,sk0..6,0,k0..6,0,v0..6,0}
__global__ __launch_bounds__(1024) void k_l3_wcat(const float* __restrict__ Wq, const float* __restrict__ bq,
                                                  const float* __restrict__ Wk, const float* __restrict__ bk,
                                                  const float* __restrict__ Wv, const float* __restrict__ bv,
                                                  const float* __restrict__ Ws, const float* __restrict__ bs,
                                                  float* __restrict__ Wcat, float* __restrict__ bcat) {
    int t = threadIdx.x;
    int c = t & 31, g = c >> 3, cc = c & 7;
    const float* Wg = (g == 0) ? Wq : (g == 1) ? Ws : (g == 2) ? Wk : Wv;
    const float* Bg = (g == 0) ? bq : (g == 1) ? bs : (g == 2) ? bk : bv;
    int kk = t >> 5;
    Wcat[t] = (cc < 7) ? Wg[kk * 7 + cc] : 0.f;
    if (t < 32) bcat[t] = (cc < 7) ? Bg[cc] : 0.f;
}

// 128 nodes per 256-thread block; thread = 4-node x 4-col tile; cols map to QS|KV directly.
// k4 unroll capped at 2 (see k_l2_transform note).
__global__ __launch_bounds__(256) void k_l3_transform(const float* __restrict__ x2,
                                                      const float4* __restrict__ Wc4, const float4* __restrict__ bc4,
                                                      float* __restrict__ QS, float* __restrict__ KV, int N) {
    __shared__ float xs[128 * 36];
    int t = threadIdx.x;
    int node0 = blockIdx.x * 128;
    int nrem = N - node0; if (nrem > 128) nrem = 128;
    const float4* xg = (const float4*)x2;
#pragma unroll
    for (int it = 0; it < 4; ++it) {
        int id = it * 256 + t;
        int row = id >> 3, c4 = id & 7;
        float4 v = make_float4(0.f, 0.f, 0.f, 0.f);
        if (row < nrem) v = xg[(size_t)(node0 + row) * 8 + c4];
        *(float4*)&xs[row * 36 + c4 * 4] = v;
    }
    __syncthreads();
    int nt = t >> 3;
    int jt = t & 7;
    float4 bb = bc4[jt];
    float4 acc[4];
#pragma unroll
    for (int i = 0; i < 4; ++i) acc[i] = bb;
#pragma unroll 2
    for (int k4 = 0; k4 < 8; ++k4) {
        float4 w0 = Wc4[(k4 * 4 + 0) * 8 + jt];
        float4 w1 = Wc4[(k4 * 4 + 1) * 8 + jt];
        float4 w2 = Wc4[(k4 * 4 + 2) * 8 + jt];
        float4 w3 = Wc4[(k4 * 4 + 3) * 8 + jt];
#pragma unroll
        for (int i = 0; i < 4; ++i) {
            float4 xv = *(const float4*)&xs[(nt + i * 32) * 36 + k4 * 4];
            acc[i].x += xv.x * w0.x + xv.y * w1.x + xv.z * w2.x + xv.w * w3.x;
            acc[i].y += xv.x * w0.y + xv.y * w1.y + xv.z * w2.y + xv.w * w3.y;
            acc[i].z += xv.x * w0.z + xv.y * w1.z + xv.z * w2.z + xv.w * w3.z;
            acc[i].w += xv.x * w0.w + xv.y * w1.w + xv.z * w2.w + xv.w * w3.w;
        }
    }
#pragma unroll
    for (int i = 0; i < 4; ++i) {
        int row = nt + i * 32;
        if (row < nrem) {
            size_t node = node0 + row;
            float* dst = (jt < 4) ? (QS + node * 16 + jt * 4) : (KV + node * 16 + (jt - 4) * 4);
            *(float4*)dst = acc[i];
        }
    }
}

// Edge-parallel: 8 lanes per node, lane = edge slot; K|V row per edge (4x float4),
// dot in-register, exactly 8 reduction values (7 acc + den) butterflied over 8 lanes.
__global__ __launch_bounds__(256) void k_l3_agg(const float* __restrict__ QS, const float* __restrict__ KV,
                                                const int2* __restrict__ off2, const int* __restrict__ csr,
                                                float* __restrict__ out, int N) {
    int tid = threadIdx.x;
    int node = blockIdx.x * 32 + (tid >> 3);
    if (node >= N) return;
    int sl = tid & 7;
    int lane = tid & 63;
    const float scale = 0.3779644730092272f;  // 1/sqrt(7)
    const float4* q4 = (const float4*)(QS + (size_t)node * 16);
    float4 qa = q4[0], qb = q4[1];           // qb.w is pad
    qa.x *= scale; qa.y *= scale; qa.z *= scale; qa.w *= scale;
    qb.x *= scale; qb.y *= scale; qb.z *= scale; qb.w = 0.f;

    float v[8];
#pragma unroll
    for (int i = 0; i < 8; ++i) v[i] = 0.f;

    int2 ee = off2[node];
    int e0 = ee.x, e1 = ee.y;
    for (int jj = e0 + sl; jj < e1; jj += 8) {
        int s = csr[jj];
        const float4* kp = (const float4*)(KV + (size_t)s * 16);
        float4 k0 = kp[0], k1 = kp[1], v0 = kp[2], v1 = kp[3];
        float t = qa.x * k0.x + qa.y * k0.y + qa.z * k0.z + qa.w * k0.w
                + qb.x * k1.x + qb.y * k1.y + qb.z * k1.z;
        float w = __expf(t);
        v[0] += w * v0.x; v[1] += w * v0.y; v[2] += w * v0.z; v[3] += w * v0.w;
        v[4] += w * v1.x; v[5] += w * v1.y; v[6] += w * v1.z; v[7] += w;
    }
#pragma unroll
    for (int d = 4; d >= 1; d >>= 1) {
#pragma unroll
        for (int i = 0; i < 8; ++i) {
            if (i < d) {
                float a = v[i], b = v[i + d];
                float send = (sl & d) ? a : b;
                float recv = __shfl_xor(send, d);
                v[i] = ((sl & d) ? b : a) + recv;
            }
        }
    }
    float r = v[0];                                // value index sl
    float den = __shfl(r, (lane & 56) + 7);        // value 7 = denominator
    if (sl < 7) out[(size_t)node * 7 + sl] = r / (den + 1e-16f)
                                             + QS[(size_t)node * 16 + 8 + sl];
}

// ---------------- launcher ----------------

extern "C" void kernel_launch(void* const* d_in, const int* in_sizes, int n_in,
                              void* d_out, int out_size, void* d_ws, size_t ws_size,
                              hipStream_t stream) {
    const int* ei = (const int*)d_in[1];
    float* out = (float*)d_out;

    int N = in_sizes[0] / 3;
    int E = in_sizes[1] / 2;
    int NB = (N + 1023) >> 10;   // assumed <= 256 (N <= 262144)
    int C = (E + NB - 1) / NB + 4096;   // fixed bucket capacity (mean + huge slack for random dst)

    char* ws = (char*)d_ws;
    size_t o = 0;
    auto take = [&](size_t bytes) -> char* {
        char* p = ws + o;
        o = (o + bytes + 255) & ~(size_t)255;
        return p;
    };
    int*   flags   = (int*)take(64);
    int total_f = 0;
    for (int i = 0; i < 20; ++i) if (i != 1) total_f += in_sizes[i];
    float* canon   = (float*)take((size_t)total_f * 4);
    float* Wcat    = (float*)take(32 * 32 * 4);
    float* bcat    = (float*)take(32 * 4);
    int2*  off2    = (int2*)take((size_t)N * 8);
    int*   bcur    = (int*)take(256 * 4);
    int*   csr     = (int*)take((size_t)NB * C * 4);
    float* bufA    = (float*)take((size_t)N * 64 * 4);  // x4 -> hlb|hr -> QS|KV
    float* as1     = (float*)take((size_t)N * 4 * 4);
    float* ad1     = (float*)take((size_t)N * 4 * 4);
    float* bufB    = (float*)take((size_t)N * 64 * 4);  // bkt -> x1 -> x2
    (void)ws_size; (void)n_in; (void)out_size;

    CvtArgs ca;
    const float* cp[20];
    {
        int off_ = 0, k = 0;
        for (int i = 0; i < 20; ++i) {
            if (i == 1) { cp[i] = nullptr; continue; }
            ca.p[k] = d_in[i];
            ca.sz[k] = in_sizes[i];
            cp[i] = canon + off_;
            off_ += in_sizes[i];
            ++k;
        }
    }

    hipMemsetAsync(bcur, 0, 256 * 4, stream);
    k_detect<<<1, 256, 0, stream>>>((const unsigned short*)d_in[0], ei, flags);
    k_convert<<<(total_f + 255) / 256, 256, 0, stream>>>(ca, flags, canon, total_f);
    k_l3_wcat<<<1, 1024, 0, stream>>>(cp[12], cp[13], cp[14], cp[15], cp[16], cp[17],
                                      cp[18], cp[19], Wcat, bcat);

    // bkt aliases bufB (NB*C*8 B ~= 16 MB <= N*256 B); x1 written only after k_bbuild
    int2* bkt = (int2*)bufB;
    int gb = (E + 4095) / 4096;
    k_bscatter<<<gb, 1024, 0, stream>>>(ei, flags, bcur, bkt, E, NB, C);
    k_bbuild<<<NB, 1024, 0, stream>>>(bkt, bcur, off2, csr, N, C);

    float4* x4 = (float4*)bufA;                                  // N*16B = 1.6 MB, L2-resident
    k_l1_transform<<<(N + 3) / 4, 256, 0, stream>>>(cp[0], cp[2], cp[3], cp[4], x4, as1, ad1, N);
    float* x1 = bufB;
    k_l1_agg<<<(N + 15) / 16, 256, 0, stream>>>(x4, (const float4*)as1, (const float4*)ad1,
                                                off2, csr, cp[2], cp[5], x1, N);

    unsigned short* hlb = (unsigned short*)bufA;                 // N*32 bf16 = 6.4 MB
    float* hr = bufA + (size_t)N * 16;
    k_l2_transform<<<(N + 63) / 64, 256, 0, stream>>>(x1, cp[6], cp[7], cp[8], cp[9], hlb, hr, N);
    float* x2 = bufB;
    k_l2_agg<<<(N + 15) / 16, 256, 0, stream>>>(hlb, hr, cp[10], cp[11], off2, csr, x2, N);

    float* QS = bufA;                                            // N*16 floats
    float* KV = bufA + (size_t)N * 16;                           // N*16 floats
    k_l3_transform<<<(N + 127) / 128, 256, 0, stream>>>(x2, (const float4*)Wcat, (const float4*)bcat,
                                                        QS, KV, N);
    k_l3_agg<<<(N + 31) / 32, 256, 0, stream>>>(QS, KV, off2, csr, out, N);
}

// Round 13
// 279.514 us; speedup vs baseline: 1.7932x; 1.0368x over previous
//
#include <hip/hip_runtime.h>
#include <hip/hip_bf16.h>

typedef __hip_bfloat16 bf16;

static __device__ __forceinline__ float us2f(unsigned short u) {
    union { unsigned int i; float f; } c; c.i = ((unsigned int)u) << 16; return c.f;
}
static __device__ __forceinline__ unsigned short f2us(float f) {
    union { float f; unsigned int i; } c; c.f = f;
    unsigned int r = c.i + 0x7FFF + ((c.i >> 16) & 1);   // round-to-nearest-even
    return (unsigned short)(r >> 16);
}

// wave-0 probe: is the float input stored as f32 (vs bf16)? (see r1 analysis)
static __device__ __forceinline__ int probe_isf32(const unsigned short* xr, int* sflag) {
    int tid = threadIdx.x;
    if (tid < 64) {
        int bad = 0;
        for (int i = tid; i < 1024; i += 64) {
            int ex = (xr[2 * i] >> 7) & 0xFF;
            if (ex < 110 || ex > 135) bad++;
        }
#pragma unroll
        for (int m = 32; m >= 1; m >>= 1) bad += __shfl_xor(bad, m);
        if (tid == 0) *sflag = (bad > 256) ? 1 : 0;
    }
    __syncthreads();
    return *sflag;
}

static __device__ __forceinline__ int ld_edge(const int* er, size_t i, int idx64) {
    return idx64 ? er[2 * i] : er[i];
}

// ---------------- canonicalization + Wcat pack (fused; flags derived in-kernel) ----------------

struct CvtArgs { const void* p[19]; int sz[19]; };

static __device__ __forceinline__ float cvt_elem(const void* p, int off, int isf32) {
    return isf32 ? ((const float*)p)[off] : __bfloat162float(((const bf16*)p)[off]);
}

// blocks 0..nbconv-1: convert all float inputs to f32 canon.
// block nbconv: build Wcat[32][32] (row -> {q0..6,0,sk0..6,0,k0..6,0,v0..6,0}) + bcat from raw inputs.
__global__ __launch_bounds__(256) void k_convert(CvtArgs a, float* __restrict__ dst, int total,
                                                 int nbconv, float* __restrict__ Wcat,
                                                 float* __restrict__ bcat) {
    __shared__ int sflag;
    int isf32 = probe_isf32((const unsigned short*)a.p[0], &sflag);
    int tid = threadIdx.x;
    if ((int)blockIdx.x == nbconv) {
        // Wq=p[11] bq=p[12] Wk=p[13] bk=p[14] Wv=p[15] bv=p[16] Wsk=p[17] bsk=p[18]
#pragma unroll
        for (int t4 = 0; t4 < 4; ++t4) {
            int idx = t4 * 256 + tid;           // 0..1023
            int c = idx & 31, g = c >> 3, cc = c & 7, kk = idx >> 5;
            const void* Wg = (g == 0) ? a.p[11] : (g == 1) ? a.p[17] : (g == 2) ? a.p[13] : a.p[15];
            Wcat[idx] = (cc < 7) ? cvt_elem(Wg, kk * 7 + cc, isf32) : 0.f;
        }
        if (tid < 32) {
            int g = tid >> 3, cc = tid & 7;
            const void* Bg = (g == 0) ? a.p[12] : (g == 1) ? a.p[18] : (g == 2) ? a.p[14] : a.p[16];
            bcat[tid] = (cc < 7) ? cvt_elem(Bg, cc, isf32) : 0.f;
        }
        return;
    }
    int t = blockIdx.x * 256 + tid;
    if (t >= total) return;
    int base = 0, seg = -1, off = 0;
#pragma unroll
    for (int i = 0; i < 19; i++) {
        if (seg < 0 && t < base + a.sz[i]) { seg = i; off = t - base; }
        base += a.sz[i];
    }
    dst[t] = cvt_elem(a.p[seg], off, isf32);
}

// ---------------- bucketed CSR build (fixed-capacity buckets; packed bkt) ----------------
// bucket b = dst >> 10; bkt entry = (src << 10) | (dst & 1023)  [src <= 2^18, so 28 bits]

__global__ __launch_bounds__(1024) void k_bscatter(const int* __restrict__ er,
                                                   int* __restrict__ bcur, int* __restrict__ bkt,
                                                   int E, int NB, int C) {
    __shared__ int cnt[256];
    __shared__ int res[256];
    __shared__ int sflag;
    int tid = threadIdx.x;
    // wave-0 probe: int64 storage iff high words of first edges are 0
    if (tid < 64) {
        int lim = (E < 1024) ? E : 1024;
        int nz = 0;
        for (int i = tid; i < lim; i += 64) if (er[2 * i + 1] != 0) nz++;
#pragma unroll
        for (int m = 32; m >= 1; m >>= 1) nz += __shfl_xor(nz, m);
        if (tid == 0) sflag = (nz < ((E < 1024 ? E : 1024) >> 1)) ? 1 : 0;
    }
    if (tid < 256) cnt[tid] = 0;
    __syncthreads();
    int idx64 = sflag;
    int base = blockIdx.x * 4096 + tid;
    int pk[4], bv[4];
    bool val[4];
#pragma unroll
    for (int k = 0; k < 4; ++k) {
        int e = base + k * 1024;
        val[k] = (e < E);
        if (val[k]) {
            int s = ld_edge(er, (size_t)e, idx64);
            int d = ld_edge(er, (size_t)E + e, idx64);
            bv[k] = d >> 10;
            pk[k] = (s << 10) | (d & 1023);
            atomicAdd(&cnt[bv[k]], 1);
        }
    }
    __syncthreads();
    if (tid < NB) {
        int c = cnt[tid];
        res[tid] = c ? atomicAdd(&bcur[tid], c) : 0;
        cnt[tid] = 0;
    }
    __syncthreads();
#pragma unroll
    for (int k = 0; k < 4; ++k) {
        if (val[k]) {
            int r = res[bv[k]] + atomicAdd(&cnt[bv[k]], 1);
            if (r < C) bkt[(size_t)bv[k] * C + r] = pk[k];
        }
    }
}

// per bucket: indeg count + scan -> off2 (start,end); scatter src -> bucket-strided csr
__global__ __launch_bounds__(1024) void k_bbuild(const int* __restrict__ bkt, const int* __restrict__ bcur,
                                                 int2* __restrict__ off2, int* __restrict__ csr, int N, int C) {
    __shared__ int sm[1024];
    int b = blockIdx.x, tid = threadIdx.x;
    size_t base = (size_t)b * C;
    int m = bcur[b]; if (m > C) m = C;
    sm[tid] = 0;
    __syncthreads();
    const int* bp = bkt + base;
    for (int i = tid; i < m; i += 1024) atomicAdd(&sm[bp[i] & 1023], 1);
    __syncthreads();
    int v = sm[tid];
    for (int d = 1; d < 1024; d <<= 1) {
        int t = (tid >= d) ? sm[tid - d] : 0;
        __syncthreads();
        sm[tid] += t;
        __syncthreads();
    }
    int excl = sm[tid] - v;
    int node = (b << 10) + tid;
    if (node < N) off2[node] = make_int2((int)base + excl, (int)base + excl + v);
    __syncthreads();
    sm[tid] = excl;
    __syncthreads();
    for (int i = tid; i < m; i += 1024) {
        int p = bp[i];
        int r = atomicAdd(&sm[p & 1023], 1);
        csr[base + r] = p >> 10;
    }
}

// ---------------- Layer 1: GATConv(3, 16, heads=4) ----------------

__global__ __launch_bounds__(256) void k_l1_transform(const float* __restrict__ x, const float* __restrict__ W1,
                                                      const float* __restrict__ att_s, const float* __restrict__ att_d,
                                                      float4* __restrict__ x4, float* __restrict__ as1,
                                                      float* __restrict__ ad1, int N) {
    int tid = threadIdx.x;
    int node = blockIdx.x * 4 + (tid >> 6);
    if (node >= N) return;
    int lane = tid & 63;
    float x0 = x[node * 3 + 0];
    float x1 = x[node * 3 + 1];
    float x2 = x[node * 3 + 2];
    float h = x0 * W1[lane] + x1 * W1[64 + lane] + x2 * W1[128 + lane];
    if (lane == 0) x4[node] = make_float4(x0, x1, x2, 0.f);
    float ts = h * att_s[lane];
    float td = h * att_d[lane];
    for (int m = 8; m >= 1; m >>= 1) { ts += __shfl_xor(ts, m); td += __shfl_xor(td, m); }
    if ((lane & 15) == 0) {
        as1[node * 4 + (lane >> 4)] = ts;
        ad1[node * 4 + (lane >> 4)] = td;
    }
}

// Edge-parallel: 16 lanes per node; accumulate per-head weighted x-3vec + denom, butterfly-reduce.
__global__ __launch_bounds__(256) void k_l1_agg(const float4* __restrict__ x4, const float4* __restrict__ as4,
                                                const float4* __restrict__ ad4p, const int2* __restrict__ off2,
                                                const int* __restrict__ csr, const float* __restrict__ W1,
                                                const float* __restrict__ b1,
                                                float* __restrict__ x1, int N) {
    int tid = threadIdx.x;
    int node = blockIdx.x * 16 + (tid >> 4);
    if (node >= N) return;
    int sl = tid & 15;
    int lane = tid & 63;
    int lb = lane & 48;

    float4 ad = ad4p[node];
    int2 ee = off2[node];
    int e0 = ee.x, e1 = ee.y;

    float v[16];
#pragma unroll
    for (int i = 0; i < 16; ++i) v[i] = 0.f;

    for (int jj = e0 + sl; jj < e1; jj += 16) {
        int s = csr[jj];
        float4 a = as4[s];
        float4 xv = x4[s];
        float z0 = a.x + ad.x, z1 = a.y + ad.y, z2 = a.z + ad.z, z3 = a.w + ad.w;
        z0 = (z0 > 0.f) ? z0 : 0.2f * z0;
        z1 = (z1 > 0.f) ? z1 : 0.2f * z1;
        z2 = (z2 > 0.f) ? z2 : 0.2f * z2;
        z3 = (z3 > 0.f) ? z3 : 0.2f * z3;
        float w0 = __expf(z0), w1 = __expf(z1), w2 = __expf(z2), w3 = __expf(z3);
        v[0] += w0 * xv.x; v[1] += w0 * xv.y; v[2]  += w0 * xv.z; v[3]  += w0;
        v[4] += w1 * xv.x; v[5] += w1 * xv.y; v[6]  += w1 * xv.z; v[7]  += w1;
        v[8] += w2 * xv.x; v[9] += w2 * xv.y; v[10] += w2 * xv.z; v[11] += w2;
        v[12] += w3 * xv.x; v[13] += w3 * xv.y; v[14] += w3 * xv.z; v[15] += w3;
    }

#pragma unroll
    for (int d = 8; d >= 1; d >>= 1) {
#pragma unroll
        for (int i = 0; i < 16; ++i) {
            if (i < d) {
                float a = v[i], b = v[i + d];
                float send = (sl & d) ? a : b;
                float recv = __shfl_xor(send, d);
                v[i] = ((sl & d) ? b : a) + recv;
            }
        }
    }
    float r = v[0];

    float agx[4], agy[4], agz[4], dn[4];
#pragma unroll
    for (int h = 0; h < 4; ++h) {
        agx[h] = __shfl(r, lb + 4 * h + 0);
        agy[h] = __shfl(r, lb + 4 * h + 1);
        agz[h] = __shfl(r, lb + 4 * h + 2);
        dn[h]  = __shfl(r, lb + 4 * h + 3);
    }

    {
        float4 a = as4[node];
        float4 xv = x4[node];
        float z0 = a.x + ad.x, z1 = a.y + ad.y, z2 = a.z + ad.z, z3 = a.w + ad.w;
        z0 = (z0 > 0.f) ? z0 : 0.2f * z0;
        z1 = (z1 > 0.f) ? z1 : 0.2f * z1;
        z2 = (z2 > 0.f) ? z2 : 0.2f * z2;
        z3 = (z3 > 0.f) ? z3 : 0.2f * z3;
        float w0 = __expf(z0), w1 = __expf(z1), w2 = __expf(z2), w3 = __expf(z3);
        agx[0] += w0 * xv.x; agy[0] += w0 * xv.y; agz[0] += w0 * xv.z; dn[0] += w0;
        agx[1] += w1 * xv.x; agy[1] += w1 * xv.y; agz[1] += w1 * xv.z; dn[1] += w1;
        agx[2] += w2 * xv.x; agy[2] += w2 * xv.y; agz[2] += w2 * xv.z; dn[2] += w2;
        agx[3] += w3 * xv.x; agy[3] += w3 * xv.y; agz[3] += w3 * xv.z; dn[3] += w3;
    }

#pragma unroll
    for (int h = 0; h < 4; ++h) {
        int j = h * 16 + sl;
        float inv = 1.f / (dn[h] + 1e-16f);
        float o = (agx[h] * W1[j] + agy[h] * W1[64 + j] + agz[h] * W1[128 + j]) * inv + b1[j];
        x1[(size_t)node * 64 + j] = (o > 0.f) ? o : 0.f;
    }
}

// ---------------- Layer 2: GATv2Conv(64, 16, heads=2) ----------------

// 64 nodes per 256-thread block; thread = 4-node x 4-col register tile of [hl|hr].
// k4 loop unroll capped at 2: full unroll hoisted 64 weight float4s -> 252 VGPR, 8.9% occupancy (r10).
__global__ __launch_bounds__(256) void k_l2_transform(const float* __restrict__ x1,
                                                      const float* __restrict__ W2l, const float* __restrict__ b2l,
                                                      const float* __restrict__ W2r, const float* __restrict__ b2r,
                                                      unsigned short* __restrict__ hlb, float* __restrict__ hr, int N) {
    __shared__ float xs[64 * 68];   // row stride 68: per-wave broadcast rows hit banks {0,4,8,12}
    int t = threadIdx.x;
    int node0 = blockIdx.x * 64;
    int nrem = N - node0; if (nrem > 64) nrem = 64;
    const float4* xg = (const float4*)x1;
#pragma unroll
    for (int it = 0; it < 4; ++it) {
        int id = it * 256 + t;
        int row = id >> 4, c4 = id & 15;
        float4 v = make_float4(0.f, 0.f, 0.f, 0.f);
        if (row < nrem) v = xg[(size_t)(node0 + row) * 16 + c4];
        *(float4*)&xs[row * 68 + c4 * 4] = v;
    }
    __syncthreads();
    int nt = t >> 4;
    int jt = t & 15;
    int jq = jt & 7;
    int jc = jq * 4;
    const float4* W4 = (const float4*)((jt < 8) ? W2l : W2r);
    const float4* B4 = (const float4*)((jt < 8) ? b2l : b2r);
    float4 bb = B4[jq];
    float4 acc[4];
#pragma unroll
    for (int i = 0; i < 4; ++i) acc[i] = bb;
#pragma unroll 2
    for (int k4 = 0; k4 < 16; ++k4) {
        float4 w0 = W4[(k4 * 4 + 0) * 8 + jq];
        float4 w1 = W4[(k4 * 4 + 1) * 8 + jq];
        float4 w2 = W4[(k4 * 4 + 2) * 8 + jq];
        float4 w3 = W4[(k4 * 4 + 3) * 8 + jq];
#pragma unroll
        for (int i = 0; i < 4; ++i) {
            float4 xv = *(const float4*)&xs[(nt + i * 16) * 68 + k4 * 4];
            acc[i].x += xv.x * w0.x + xv.y * w1.x + xv.z * w2.x + xv.w * w3.x;
            acc[i].y += xv.x * w0.y + xv.y * w1.y + xv.z * w2.y + xv.w * w3.y;
            acc[i].z += xv.x * w0.z + xv.y * w1.z + xv.z * w2.z + xv.w * w3.z;
            acc[i].w += xv.x * w0.w + xv.y * w1.w + xv.z * w2.w + xv.w * w3.w;
        }
    }
#pragma unroll
    for (int i = 0; i < 4; ++i) {
        int row = nt + i * 16;
        if (row < nrem) {
            size_t node = node0 + row;
            if (jt < 8) {
                uint2 p;
                p.x = (unsigned)f2us(acc[i].x) | ((unsigned)f2us(acc[i].y) << 16);
                p.y = (unsigned)f2us(acc[i].z) | ((unsigned)f2us(acc[i].w) << 16);
                *(uint2*)&hlb[node * 32 + jc] = p;
            } else {
                *(float4*)&hr[node * 32 + jc] = acc[i];
            }
        }
    }
}

// Edge-parallel: 16 lanes per node, lane = edge slot. Full 64B hl row per edge (4x uint4),
// both head logits computed in-register (zero per-edge shfl); one butterfly per node.
__global__ __launch_bounds__(256) void k_l2_agg(const unsigned short* __restrict__ hlb, const float* __restrict__ hr,
                                                const float* __restrict__ att2, const float* __restrict__ b2,
                                                const int2* __restrict__ off2, const int* __restrict__ csr,
                                                float* __restrict__ x2, int N) {
    int tid = threadIdx.x;
    int node = blockIdx.x * 16 + (tid >> 4);
    if (node >= N) return;
    int sl = tid & 15;

    float hrd[32];
    {
        const float4* hr4 = (const float4*)(hr + (size_t)node * 32);
#pragma unroll
        for (int q = 0; q < 8; ++q) {
            float4 v = hr4[q];
            hrd[4 * q + 0] = v.x; hrd[4 * q + 1] = v.y;
            hrd[4 * q + 2] = v.z; hrd[4 * q + 3] = v.w;
        }
    }

    float accA[16], accB[16];
#pragma unroll
    for (int i = 0; i < 16; ++i) { accA[i] = 0.f; accB[i] = 0.f; }
    float den0 = 0.f, den1 = 0.f;

    int2 ee = off2[node];
    int e0 = ee.x, e1 = ee.y;
    for (int jj = e0 + sl; jj < e1; jj += 16) {
        int s = csr[jj];
        const uint4* hp = (const uint4*)(hlb + (size_t)s * 32);
        uint4 u0 = hp[0], u1 = hp[1], u2 = hp[2], u3 = hp[3];
        unsigned int uu[16] = {u0.x, u0.y, u0.z, u0.w, u1.x, u1.y, u1.z, u1.w,
                               u2.x, u2.y, u2.z, u2.w, u3.x, u3.y, u3.z, u3.w};
        float t0 = 0.f, t1 = 0.f;
#pragma unroll
        for (int q = 0; q < 8; ++q) {
            float lo = __uint_as_float(uu[q] << 16);
            float hi = __uint_as_float(uu[q] & 0xFFFF0000u);
            float el = lo + hrd[2 * q];     el = fmaxf(el, 0.2f * el);
            float eh = hi + hrd[2 * q + 1]; eh = fmaxf(eh, 0.2f * eh);
            t0 += att2[2 * q] * el + att2[2 * q + 1] * eh;
        }
#pragma unroll
        for (int q = 8; q < 16; ++q) {
            float lo = __uint_as_float(uu[q] << 16);
            float hi = __uint_as_float(uu[q] & 0xFFFF0000u);
            float el = lo + hrd[2 * q];     el = fmaxf(el, 0.2f * el);
            float eh = hi + hrd[2 * q + 1]; eh = fmaxf(eh, 0.2f * eh);
            t1 += att2[2 * q] * el + att2[2 * q + 1] * eh;
        }
        float w0 = __expf(t0), w1 = __expf(t1);
        den0 += w0; den1 += w1;
#pragma unroll
        for (int q = 0; q < 8; ++q) {
            accA[2 * q]     += w0 * __uint_as_float(uu[q] << 16);
            accA[2 * q + 1] += w0 * __uint_as_float(uu[q] & 0xFFFF0000u);
        }
#pragma unroll
        for (int q = 8; q < 16; ++q) {
            accB[2 * (q - 8)]     += w1 * __uint_as_float(uu[q] << 16);
            accB[2 * (q - 8) + 1] += w1 * __uint_as_float(uu[q] & 0xFFFF0000u);
        }
    }

#pragma unroll
    for (int d = 8; d >= 1; d >>= 1) {
#pragma unroll
        for (int i = 0; i < 16; ++i) {
            if (i < d) {
                { float a = accA[i], b = accA[i + d];
                  float send = (sl & d) ? a : b;
                  float recv = __shfl_xor(send, d);
                  accA[i] = ((sl & d) ? b : a) + recv; }
                { float a = accB[i], b = accB[i + d];
                  float send = (sl & d) ? a : b;
                  float recv = __shfl_xor(send, d);
                  accB[i] = ((sl & d) ? b : a) + recv; }
            }
        }
        den0 += __shfl_xor(den0, d);
        den1 += __shfl_xor(den1, d);
    }
    float sumA = accA[0];
    float sumB = accB[0];

    // self-loop (cooperative: lane sl holds channels sl and 16+sl)
    float hr0 = hr[(size_t)node * 32 + sl];
    float hr1 = hr[(size_t)node * 32 + 16 + sl];
    float hl0 = us2f(hlb[(size_t)node * 32 + sl]);
    float hl1 = us2f(hlb[(size_t)node * 32 + 16 + sl]);
    float ea = hl0 + hr0; ea = fmaxf(ea, 0.2f * ea);
    float eb = hl1 + hr1; eb = fmaxf(eb, 0.2f * eb);
    float p0 = att2[sl] * ea;
    float p1 = att2[16 + sl] * eb;
    p0 += __shfl_xor(p0, 1); p0 += __shfl_xor(p0, 2); p0 += __shfl_xor(p0, 4); p0 += __shfl_xor(p0, 8);
    p1 += __shfl_xor(p1, 1); p1 += __shfl_xor(p1, 2); p1 += __shfl_xor(p1, 4); p1 += __shfl_xor(p1, 8);
    float w0 = __expf(p0), w1 = __expf(p1);
    sumA += w0 * hl0; den0 += w0;
    sumB += w1 * hl1; den1 += w1;

    x2[(size_t)node * 32 + sl]      = sumA / (den0 + 1e-16f) + b2[sl];
    x2[(size_t)node * 32 + 16 + sl] = sumB / (den1 + 1e-16f) + b2[16 + sl];
}

// ---------------- Layer 3: TransformerConv(32, 7, heads=1) ----------------

// 128 nodes per 256-thread block; thread = 4-node x 4-col tile; cols map to QS|KV directly.
// k4 unroll capped at 2 (see k_l2_transform note).
__global__ __launch_bounds__(256) void k_l3_transform(const float* __restrict__ x2,
                                                      const float4* __restrict__ Wc4, const float4* __restrict__ bc4,
                                                      float* __restrict__ QS, float* __restrict__ KV, int N) {
    __shared__ float xs[128 * 36];
    int t = threadIdx.x;
    int node0 = blockIdx.x * 128;
    int nrem = N - node0; if (nrem > 128) nrem = 128;
    const float4* xg = (const float4*)x2;
#pragma unroll
    for (int it = 0; it < 4; ++it) {
        int id = it * 256 + t;
        int row = id >> 3, c4 = id & 7;
        float4 v = make_float4(0.f, 0.f, 0.f, 0.f);
        if (row < nrem) v = xg[(size_t)(node0 + row) * 8 + c4];
        *(float4*)&xs[row * 36 + c4 * 4] = v;
    }
    __syncthreads();
    int nt = t >> 3;
    int jt = t & 7;
    float4 bb = bc4[jt];
    float4 acc[4];
#pragma unroll
    for (int i = 0; i < 4; ++i) acc[i] = bb;
#pragma unroll 2
    for (int k4 = 0; k4 < 8; ++k4) {
        float4 w0 = Wc4[(k4 * 4 + 0) * 8 + jt];
        float4 w1 = Wc4[(k4 * 4 + 1) * 8 + jt];
        float4 w2 = Wc4[(k4 * 4 + 2) * 8 + jt];
        float4 w3 = Wc4[(k4 * 4 + 3) * 8 + jt];
#pragma unroll
        for (int i = 0; i < 4; ++i) {
            float4 xv = *(const float4*)&xs[(nt + i * 32) * 36 + k4 * 4];
            acc[i].x += xv.x * w0.x + xv.y * w1.x + xv.z * w2.x + xv.w * w3.x;
            acc[i].y += xv.x * w0.y + xv.y * w1.y + xv.z * w2.y + xv.w * w3.y;
            acc[i].z += xv.x * w0.z + xv.y * w1.z + xv.z * w2.z + xv.w * w3.z;
            acc[i].w += xv.x * w0.w + xv.y * w1.w + xv.z * w2.w + xv.w * w3.w;
        }
    }
#pragma unroll
    for (int i = 0; i < 4; ++i) {
        int row = nt + i * 32;
        if (row < nrem) {
            size_t node = node0 + row;
            float* dst = (jt < 4) ? (QS + node * 16 + jt * 4) : (KV + node * 16 + (jt - 4) * 4);
            *(float4*)dst = acc[i];
        }
    }
}

// Edge-parallel: 8 lanes per node, lane = edge slot; K|V row per edge (4x float4),
// dot in-register, exactly 8 reduction values (7 acc + den) butterflied over 8 lanes.
__global__ __launch_bounds__(256) void k_l3_agg(const float* __restrict__ QS, const float* __restrict__ KV,
                                                const int2* __restrict__ off2, const int* __restrict__ csr,
                                                float* __restrict__ out, int N) {
    int tid = threadIdx.x;
    int node = blockIdx.x * 32 + (tid >> 3);
    if (node >= N) return;
    int sl = tid & 7;
    int lane = tid & 63;
    const float scale = 0.3779644730092272f;  // 1/sqrt(7)
    const float4* q4 = (const float4*)(QS + (size_t)node * 16);
    float4 qa = q4[0], qb = q4[1];
    qa.x *= scale; qa.y *= scale; qa.z *= scale; qa.w *= scale;
    qb.x *= scale; qb.y *= scale; qb.z *= scale; qb.w = 0.f;

    float v[8];
#pragma unroll
    for (int i = 0; i < 8; ++i) v[i] = 0.f;

    int2 ee = off2[node];
    int e0 = ee.x, e1 = ee.y;
    for (int jj = e0 + sl; jj < e1; jj += 8) {
        int s = csr[jj];
        const float4* kp = (const float4*)(KV + (size_t)s * 16);
        float4 k0 = kp[0], k1 = kp[1], v0 = kp[2], v1 = kp[3];
        float t = qa.x * k0.x + qa.y * k0.y + qa.z * k0.z + qa.w * k0.w
                + qb.x * k1.x + qb.y * k1.y + qb.z * k1.z;
        float w = __expf(t);
        v[0] += w * v0.x; v[1] += w * v0.y; v[2] += w * v0.z; v[3] += w * v0.w;
        v[4] += w * v1.x; v[5] += w * v1.y; v[6] += w * v1.z; v[7] += w;
    }
#pragma unroll
    for (int d = 4; d >= 1; d >>= 1) {
#pragma unroll
        for (int i = 0; i < 8; ++i) {
            if (i < d) {
                float a = v[i], b = v[i + d];
                float send = (sl & d) ? a : b;
                float recv = __shfl_xor(send, d);
                v[i] = ((sl & d) ? b : a) + recv;
            }
        }
    }
    float r = v[0];
    float den = __shfl(r, (lane & 56) + 7);
    if (sl < 7) out[(size_t)node * 7 + sl] = r / (den + 1e-16f)
                                             + QS[(size_t)node * 16 + 8 + sl];
}

// ---------------- launcher ----------------

extern "C" void kernel_launch(void* const* d_in, const int* in_sizes, int n_in,
                              void* d_out, int out_size, void* d_ws, size_t ws_size,
                              hipStream_t stream) {
    const int* ei = (const int*)d_in[1];
    float* out = (float*)d_out;

    int N = in_sizes[0] / 3;
    int E = in_sizes[1] / 2;
    int NB = (N + 1023) >> 10;   // assumed <= 256 (N <= 262144)
    int C = (E + NB - 1) / NB + 4096;   // fixed bucket capacity (mean + huge slack for random dst)

    char* ws = (char*)d_ws;
    size_t o = 0;
    auto take = [&](size_t bytes) -> char* {
        char* p = ws + o;
        o = (o + bytes + 255) & ~(size_t)255;
        return p;
    };
    int total_f = 0;
    for (int i = 0; i < 20; ++i) if (i != 1) total_f += in_sizes[i];
    float* canon   = (float*)take((size_t)total_f * 4);
    float* Wcat    = (float*)take(32 * 32 * 4);
    float* bcat    = (float*)take(32 * 4);
    int2*  off2    = (int2*)take((size_t)N * 8);
    int*   bcur    = (int*)take(256 * 4);
    int*   csr     = (int*)take((size_t)NB * C * 4);
    float* bufA    = (float*)take((size_t)N * 64 * 4);  // x4 -> hlb|hr -> QS|KV
    float* as1     = (float*)take((size_t)N * 4 * 4);
    float* ad1     = (float*)take((size_t)N * 4 * 4);
    float* bufB    = (float*)take((size_t)N * 64 * 4);  // bkt -> x1 -> x2
    (void)ws_size; (void)n_in; (void)out_size;

    CvtArgs ca;
    const float* cp[20];
    {
        int off_ = 0, k = 0;
        for (int i = 0; i < 20; ++i) {
            if (i == 1) { cp[i] = nullptr; continue; }
            ca.p[k] = d_in[i];
            ca.sz[k] = in_sizes[i];
            cp[i] = canon + off_;
            off_ += in_sizes[i];
            ++k;
        }
    }

    hipMemsetAsync(bcur, 0, 256 * 4, stream);
    int nbconv = (total_f + 255) / 256;
    k_convert<<<nbconv + 1, 256, 0, stream>>>(ca, canon, total_f, nbconv, Wcat, bcat);

    // bkt aliases bufB (NB*C*4 B ~= 8 MB <= N*256 B); x1 written only after k_bbuild
    int* bkt = (int*)bufB;
    int gb = (E + 4095) / 4096;
    k_bscatter<<<gb, 1024, 0, stream>>>(ei, bcur, bkt, E, NB, C);
    k_bbuild<<<NB, 1024, 0, stream>>>(bkt, bcur, off2, csr, N, C);

    float4* x4 = (float4*)bufA;                                  // N*16B = 1.6 MB, L2-resident
    k_l1_transform<<<(N + 3) / 4, 256, 0, stream>>>(cp[0], cp[2], cp[3], cp[4], x4, as1, ad1, N);
    float* x1 = bufB;
    k_l1_agg<<<(N + 15) / 16, 256, 0, stream>>>(x4, (const float4*)as1, (const float4*)ad1,
                                                off2, csr, cp[2], cp[5], x1, N);

    unsigned short* hlb = (unsigned short*)bufA;                 // N*32 bf16 = 6.4 MB
    float* hr = bufA + (size_t)N * 16;
    k_l2_transform<<<(N + 63) / 64, 256, 0, stream>>>(x1, cp[6], cp[7], cp[8], cp[9], hlb, hr, N);
    float* x2 = bufB;
    k_l2_agg<<<(N + 15) / 16, 256, 0, stream>>>(hlb, hr, cp[10], cp[11], off2, csr, x2, N);

    float* QS = bufA;                                            // N*16 floats
    float* KV = bufA + (size_t)N * 16;                           // N*16 floats
    k_l3_transform<<<(N + 127) / 128, 256, 0, stream>>>(x2, (const float4*)Wcat, (const float4*)bcat,
                                                        QS, KV, N);
    k_l3_agg<<<(N + 31) / 32, 256, 0, stream>>>(QS, KV, off2, csr, out, N);
}

// Round 14
// 271.272 us; speedup vs baseline: 1.8477x; 1.0304x over previous
//
#include <hip/hip_runtime.h>
#include <hip/hip_bf16.h>

typedef __hip_bfloat16 bf16;

static __device__ __forceinline__ float us2f(unsigned short u) {
    union { unsigned int i; float f; } c; c.i = ((unsigned int)u) << 16; return c.f;
}
static __device__ __forceinline__ unsigned short f2us(float f) {
    union { float f; unsigned int i; } c; c.f = f;
    unsigned int r = c.i + 0x7FFF + ((c.i >> 16) & 1);   // round-to-nearest-even
    return (unsigned short)(r >> 16);
}

// wave-0 probe: is the float input stored as f32 (vs bf16)? (see r1 analysis)
static __device__ __forceinline__ int probe_isf32(const unsigned short* xr, int* sflag) {
    int tid = threadIdx.x;
    if (tid < 64) {
        int bad = 0;
        for (int i = tid; i < 1024; i += 64) {
            int ex = (xr[2 * i] >> 7) & 0xFF;
            if (ex < 110 || ex > 135) bad++;
        }
#pragma unroll
        for (int m = 32; m >= 1; m >>= 1) bad += __shfl_xor(bad, m);
        if (tid == 0) *sflag = (bad > 256) ? 1 : 0;
    }
    __syncthreads();
    return *sflag;
}

static __device__ __forceinline__ int ld_edge(const int* er, size_t i, int idx64) {
    return idx64 ? er[2 * i] : er[i];
}

// ---------------- canonicalization + Wcat pack + bcur zero (fused) ----------------

struct CvtArgs { const void* p[19]; int sz[19]; };

static __device__ __forceinline__ float cvt_elem(const void* p, int off, int isf32) {
    return isf32 ? ((const float*)p)[off] : __bfloat162float(((const bf16*)p)[off]);
}

// blocks 0..nbconv-1: convert all float inputs to f32 canon.
// block nbconv: build Wcat[32][32] + bcat from raw inputs, and zero bcur.
__global__ __launch_bounds__(256) void k_convert(CvtArgs a, float* __restrict__ dst, int total,
                                                 int nbconv, float* __restrict__ Wcat,
                                                 float* __restrict__ bcat, int* __restrict__ bcur) {
    __shared__ int sflag;
    int isf32 = probe_isf32((const unsigned short*)a.p[0], &sflag);
    int tid = threadIdx.x;
    if ((int)blockIdx.x == nbconv) {
        // Wq=p[11] bq=p[12] Wk=p[13] bk=p[14] Wv=p[15] bv=p[16] Wsk=p[17] bsk=p[18]
#pragma unroll
        for (int t4 = 0; t4 < 4; ++t4) {
            int idx = t4 * 256 + tid;           // 0..1023
            int c = idx & 31, g = c >> 3, cc = c & 7, kk = idx >> 5;
            const void* Wg = (g == 0) ? a.p[11] : (g == 1) ? a.p[17] : (g == 2) ? a.p[13] : a.p[15];
            Wcat[idx] = (cc < 7) ? cvt_elem(Wg, kk * 7 + cc, isf32) : 0.f;
        }
        if (tid < 32) {
            int g = tid >> 3, cc = tid & 7;
            const void* Bg = (g == 0) ? a.p[12] : (g == 1) ? a.p[18] : (g == 2) ? a.p[14] : a.p[16];
            bcat[tid] = (cc < 7) ? cvt_elem(Bg, cc, isf32) : 0.f;
        }
        bcur[tid] = 0;
        return;
    }
    int t = blockIdx.x * 256 + tid;
    if (t >= total) return;
    int base = 0, seg = -1, off = 0;
#pragma unroll
    for (int i = 0; i < 19; i++) {
        if (seg < 0 && t < base + a.sz[i]) { seg = i; off = t - base; }
        base += a.sz[i];
    }
    dst[t] = cvt_elem(a.p[seg], off, isf32);
}

// ---------------- bucketed CSR build (fixed-capacity buckets; packed bkt) ----------------
// bucket b = dst >> 10; bkt entry = (src << 10) | (dst & 1023)  [src <= 2^18, so 28 bits]

__global__ __launch_bounds__(1024) void k_bscatter(const int* __restrict__ er,
                                                   int* __restrict__ bcur, int* __restrict__ bkt,
                                                   int E, int NB, int C) {
    __shared__ int cnt[256];
    __shared__ int res[256];
    __shared__ int sflag;
    int tid = threadIdx.x;
    if (tid < 64) {
        int lim = (E < 1024) ? E : 1024;
        int nz = 0;
        for (int i = tid; i < lim; i += 64) if (er[2 * i + 1] != 0) nz++;
#pragma unroll
        for (int m = 32; m >= 1; m >>= 1) nz += __shfl_xor(nz, m);
        if (tid == 0) sflag = (nz < ((E < 1024 ? E : 1024) >> 1)) ? 1 : 0;
    }
    if (tid < 256) cnt[tid] = 0;
    __syncthreads();
    int idx64 = sflag;
    int base = blockIdx.x * 4096 + tid;
    int pk[4], bv[4];
    bool val[4];
#pragma unroll
    for (int k = 0; k < 4; ++k) {
        int e = base + k * 1024;
        val[k] = (e < E);
        if (val[k]) {
            int s = ld_edge(er, (size_t)e, idx64);
            int d = ld_edge(er, (size_t)E + e, idx64);
            bv[k] = d >> 10;
            pk[k] = (s << 10) | (d & 1023);
            atomicAdd(&cnt[bv[k]], 1);
        }
    }
    __syncthreads();
    if (tid < NB) {
        int c = cnt[tid];
        res[tid] = c ? atomicAdd(&bcur[tid], c) : 0;
        cnt[tid] = 0;
    }
    __syncthreads();
#pragma unroll
    for (int k = 0; k < 4; ++k) {
        if (val[k]) {
            int r = res[bv[k]] + atomicAdd(&cnt[bv[k]], 1);
            if (r < C) bkt[(size_t)bv[k] * C + r] = pk[k];
        }
    }
}

// per bucket: indeg count + scan -> off2 (start,end); scatter src -> bucket-strided csr
__global__ __launch_bounds__(1024) void k_bbuild(const int* __restrict__ bkt, const int* __restrict__ bcur,
                                                 int2* __restrict__ off2, int* __restrict__ csr, int N, int C) {
    __shared__ int sm[1024];
    int b = blockIdx.x, tid = threadIdx.x;
    size_t base = (size_t)b * C;
    int m = bcur[b]; if (m > C) m = C;
    sm[tid] = 0;
    __syncthreads();
    const int* bp = bkt + base;
    for (int i = tid; i < m; i += 1024) atomicAdd(&sm[bp[i] & 1023], 1);
    __syncthreads();
    int v = sm[tid];
    for (int d = 1; d < 1024; d <<= 1) {
        int t = (tid >= d) ? sm[tid - d] : 0;
        __syncthreads();
        sm[tid] += t;
        __syncthreads();
    }
    int excl = sm[tid] - v;
    int node = (b << 10) + tid;
    if (node < N) off2[node] = make_int2((int)base + excl, (int)base + excl + v);
    __syncthreads();
    sm[tid] = excl;
    __syncthreads();
    for (int i = tid; i < m; i += 1024) {
        int p = bp[i];
        int r = atomicAdd(&sm[p & 1023], 1);
        csr[base + r] = p >> 10;
    }
}

// ---------------- Layer 1: GATConv(3, 16, heads=4) ----------------

__global__ __launch_bounds__(256) void k_l1_transform(const float* __restrict__ x, const float* __restrict__ W1,
                                                      const float* __restrict__ att_s, const float* __restrict__ att_d,
                                                      float4* __restrict__ x4, float* __restrict__ as1,
                                                      float* __restrict__ ad1, int N) {
    int tid = threadIdx.x;
    int node = blockIdx.x * 4 + (tid >> 6);
    if (node >= N) return;
    int lane = tid & 63;
    float x0 = x[node * 3 + 0];
    float x1 = x[node * 3 + 1];
    float x2 = x[node * 3 + 2];
    float h = x0 * W1[lane] + x1 * W1[64 + lane] + x2 * W1[128 + lane];
    if (lane == 0) x4[node] = make_float4(x0, x1, x2, 0.f);
    float ts = h * att_s[lane];
    float td = h * att_d[lane];
    for (int m = 8; m >= 1; m >>= 1) { ts += __shfl_xor(ts, m); td += __shfl_xor(td, m); }
    if ((lane & 15) == 0) {
        as1[node * 4 + (lane >> 4)] = ts;
        ad1[node * 4 + (lane >> 4)] = td;
    }
}

// Edge-parallel: 16 lanes per node; accumulate per-head weighted x-3vec + denom, butterfly-reduce.
__global__ __launch_bounds__(256) void k_l1_agg(const float4* __restrict__ x4, const float4* __restrict__ as4,
                                                const float4* __restrict__ ad4p, const int2* __restrict__ off2,
                                                const int* __restrict__ csr, const float* __restrict__ W1,
                                                const float* __restrict__ b1,
                                                float* __restrict__ x1, int N) {
    int tid = threadIdx.x;
    int node = blockIdx.x * 16 + (tid >> 4);
    if (node >= N) return;
    int sl = tid & 15;
    int lane = tid & 63;
    int lb = lane & 48;

    float4 ad = ad4p[node];
    int2 ee = off2[node];
    int e0 = ee.x, e1 = ee.y;

    float v[16];
#pragma unroll
    for (int i = 0; i < 16; ++i) v[i] = 0.f;

    for (int jj = e0 + sl; jj < e1; jj += 16) {
        int s = csr[jj];
        float4 a = as4[s];
        float4 xv = x4[s];
        float z0 = a.x + ad.x, z1 = a.y + ad.y, z2 = a.z + ad.z, z3 = a.w + ad.w;
        z0 = (z0 > 0.f) ? z0 : 0.2f * z0;
        z1 = (z1 > 0.f) ? z1 : 0.2f * z1;
        z2 = (z2 > 0.f) ? z2 : 0.2f * z2;
        z3 = (z3 > 0.f) ? z3 : 0.2f * z3;
        float w0 = __expf(z0), w1 = __expf(z1), w2 = __expf(z2), w3 = __expf(z3);
        v[0] += w0 * xv.x; v[1] += w0 * xv.y; v[2]  += w0 * xv.z; v[3]  += w0;
        v[4] += w1 * xv.x; v[5] += w1 * xv.y; v[6]  += w1 * xv.z; v[7]  += w1;
        v[8] += w2 * xv.x; v[9] += w2 * xv.y; v[10] += w2 * xv.z; v[11] += w2;
        v[12] += w3 * xv.x; v[13] += w3 * xv.y; v[14] += w3 * xv.z; v[15] += w3;
    }

#pragma unroll
    for (int d = 8; d >= 1; d >>= 1) {
#pragma unroll
        for (int i = 0; i < 16; ++i) {
            if (i < d) {
                float a = v[i], b = v[i + d];
                float send = (sl & d) ? a : b;
                float recv = __shfl_xor(send, d);
                v[i] = ((sl & d) ? b : a) + recv;
            }
        }
    }
    float r = v[0];

    float agx[4], agy[4], agz[4], dn[4];
#pragma unroll
    for (int h = 0; h < 4; ++h) {
        agx[h] = __shfl(r, lb + 4 * h + 0);
        agy[h] = __shfl(r, lb + 4 * h + 1);
        agz[h] = __shfl(r, lb + 4 * h + 2);
        dn[h]  = __shfl(r, lb + 4 * h + 3);
    }

    {
        float4 a = as4[node];
        float4 xv = x4[node];
        float z0 = a.x + ad.x, z1 = a.y + ad.y, z2 = a.z + ad.z, z3 = a.w + ad.w;
        z0 = (z0 > 0.f) ? z0 : 0.2f * z0;
        z1 = (z1 > 0.f) ? z1 : 0.2f * z1;
        z2 = (z2 > 0.f) ? z2 : 0.2f * z2;
        z3 = (z3 > 0.f) ? z3 : 0.2f * z3;
        float w0 = __expf(z0), w1 = __expf(z1), w2 = __expf(z2), w3 = __expf(z3);
        agx[0] += w0 * xv.x; agy[0] += w0 * xv.y; agz[0] += w0 * xv.z; dn[0] += w0;
        agx[1] += w1 * xv.x; agy[1] += w1 * xv.y; agz[1] += w1 * xv.z; dn[1] += w1;
        agx[2] += w2 * xv.x; agy[2] += w2 * xv.y; agz[2] += w2 * xv.z; dn[2] += w2;
        agx[3] += w3 * xv.x; agy[3] += w3 * xv.y; agz[3] += w3 * xv.z; dn[3] += w3;
    }

#pragma unroll
    for (int h = 0; h < 4; ++h) {
        int j = h * 16 + sl;
        float inv = 1.f / (dn[h] + 1e-16f);
        float o = (agx[h] * W1[j] + agy[h] * W1[64 + j] + agz[h] * W1[128 + j]) * inv + b1[j];
        x1[(size_t)node * 64 + j] = (o > 0.f) ? o : 0.f;
    }
}

// ---------------- Layer 2: GATv2Conv(64, 16, heads=2) ----------------

// 64 nodes per 256-thread block; thread = 4-node x 4-col register tile of [hl|hr].
// k4 loop unroll capped at 2: full unroll hoisted 64 weight float4s -> 252 VGPR, 8.9% occupancy (r10).
__global__ __launch_bounds__(256) void k_l2_transform(const float* __restrict__ x1,
                                                      const float* __restrict__ W2l, const float* __restrict__ b2l,
                                                      const float* __restrict__ W2r, const float* __restrict__ b2r,
                                                      unsigned short* __restrict__ hlb, float* __restrict__ hr, int N) {
    __shared__ float xs[64 * 68];   // row stride 68: per-wave broadcast rows hit banks {0,4,8,12}
    int t = threadIdx.x;
    int node0 = blockIdx.x * 64;
    int nrem = N - node0; if (nrem > 64) nrem = 64;
    const float4* xg = (const float4*)x1;
#pragma unroll
    for (int it = 0; it < 4; ++it) {
        int id = it * 256 + t;
        int row = id >> 4, c4 = id & 15;
        float4 v = make_float4(0.f, 0.f, 0.f, 0.f);
        if (row < nrem) v = xg[(size_t)(node0 + row) * 16 + c4];
        *(float4*)&xs[row * 68 + c4 * 4] = v;
    }
    __syncthreads();
    int nt = t >> 4;
    int jt = t & 15;
    int jq = jt & 7;
    int jc = jq * 4;
    const float4* W4 = (const float4*)((jt < 8) ? W2l : W2r);
    const float4* B4 = (const float4*)((jt < 8) ? b2l : b2r);
    float4 bb = B4[jq];
    float4 acc[4];
#pragma unroll
    for (int i = 0; i < 4; ++i) acc[i] = bb;
#pragma unroll 2
    for (int k4 = 0; k4 < 16; ++k4) {
        float4 w0 = W4[(k4 * 4 + 0) * 8 + jq];
        float4 w1 = W4[(k4 * 4 + 1) * 8 + jq];
        float4 w2 = W4[(k4 * 4 + 2) * 8 + jq];
        float4 w3 = W4[(k4 * 4 + 3) * 8 + jq];
#pragma unroll
        for (int i = 0; i < 4; ++i) {
            float4 xv = *(const float4*)&xs[(nt + i * 16) * 68 + k4 * 4];
            acc[i].x += xv.x * w0.x + xv.y * w1.x + xv.z * w2.x + xv.w * w3.x;
            acc[i].y += xv.x * w0.y + xv.y * w1.y + xv.z * w2.y + xv.w * w3.y;
            acc[i].z += xv.x * w0.z + xv.y * w1.z + xv.z * w2.z + xv.w * w3.z;
            acc[i].w += xv.x * w0.w + xv.y * w1.w + xv.z * w2.w + xv.w * w3.w;
        }
    }
#pragma unroll
    for (int i = 0; i < 4; ++i) {
        int row = nt + i * 16;
        if (row < nrem) {
            size_t node = node0 + row;
            if (jt < 8) {
                uint2 p;
                p.x = (unsigned)f2us(acc[i].x) | ((unsigned)f2us(acc[i].y) << 16);
                p.y = (unsigned)f2us(acc[i].z) | ((unsigned)f2us(acc[i].w) << 16);
                *(uint2*)&hlb[node * 32 + jc] = p;
            } else {
                *(float4*)&hr[node * 32 + jc] = acc[i];
            }
        }
    }
}

// Edge-parallel: 16 lanes per node, lane = edge slot. Full 64B hl row per edge (4x uint4),
// both head logits computed in-register (zero per-edge shfl); one butterfly per node.
__global__ __launch_bounds__(256) void k_l2_agg(const unsigned short* __restrict__ hlb, const float* __restrict__ hr,
                                                const float* __restrict__ att2, const float* __restrict__ b2,
                                                const int2* __restrict__ off2, const int* __restrict__ csr,
                                                float* __restrict__ x2, int N) {
    int tid = threadIdx.x;
    int node = blockIdx.x * 16 + (tid >> 4);
    if (node >= N) return;
    int sl = tid & 15;

    float hrd[32];
    {
        const float4* hr4 = (const float4*)(hr + (size_t)node * 32);
#pragma unroll
        for (int q = 0; q < 8; ++q) {
            float4 v = hr4[q];
            hrd[4 * q + 0] = v.x; hrd[4 * q + 1] = v.y;
            hrd[4 * q + 2] = v.z; hrd[4 * q + 3] = v.w;
        }
    }

    float accA[16], accB[16];
#pragma unroll
    for (int i = 0; i < 16; ++i) { accA[i] = 0.f; accB[i] = 0.f; }
    float den0 = 0.f, den1 = 0.f;

    int2 ee = off2[node];
    int e0 = ee.x, e1 = ee.y;
    for (int jj = e0 + sl; jj < e1; jj += 16) {
        int s = csr[jj];
        const uint4* hp = (const uint4*)(hlb + (size_t)s * 32);
        uint4 u0 = hp[0], u1 = hp[1], u2 = hp[2], u3 = hp[3];
        unsigned int uu[16] = {u0.x, u0.y, u0.z, u0.w, u1.x, u1.y, u1.z, u1.w,
                               u2.x, u2.y, u2.z, u2.w, u3.x, u3.y, u3.z, u3.w};
        float t0 = 0.f, t1 = 0.f;
#pragma unroll
        for (int q = 0; q < 8; ++q) {
            float lo = __uint_as_float(uu[q] << 16);
            float hi = __uint_as_float(uu[q] & 0xFFFF0000u);
            float el = lo + hrd[2 * q];     el = fmaxf(el, 0.2f * el);
            float eh = hi + hrd[2 * q + 1]; eh = fmaxf(eh, 0.2f * eh);
            t0 += att2[2 * q] * el + att2[2 * q + 1] * eh;
        }
#pragma unroll
        for (int q = 8; q < 16; ++q) {
            float lo = __uint_as_float(uu[q] << 16);
            float hi = __uint_as_float(uu[q] & 0xFFFF0000u);
            float el = lo + hrd[2 * q];     el = fmaxf(el, 0.2f * el);
            float eh = hi + hrd[2 * q + 1]; eh = fmaxf(eh, 0.2f * eh);
            t1 += att2[2 * q] * el + att2[2 * q + 1] * eh;
        }
        float w0 = __expf(t0), w1 = __expf(t1);
        den0 += w0; den1 += w1;
#pragma unroll
        for (int q = 0; q < 8; ++q) {
            accA[2 * q]     += w0 * __uint_as_float(uu[q] << 16);
            accA[2 * q + 1] += w0 * __uint_as_float(uu[q] & 0xFFFF0000u);
        }
#pragma unroll
        for (int q = 8; q < 16; ++q) {
            accB[2 * (q - 8)]     += w1 * __uint_as_float(uu[q] << 16);
            accB[2 * (q - 8) + 1] += w1 * __uint_as_float(uu[q] & 0xFFFF0000u);
        }
    }

#pragma unroll
    for (int d = 8; d >= 1; d >>= 1) {
#pragma unroll
        for (int i = 0; i < 16; ++i) {
            if (i < d) {
                { float a = accA[i], b = accA[i + d];
                  float send = (sl & d) ? a : b;
                  float recv = __shfl_xor(send, d);
                  accA[i] = ((sl & d) ? b : a) + recv; }
                { float a = accB[i], b = accB[i + d];
                  float send = (sl & d) ? a : b;
                  float recv = __shfl_xor(send, d);
                  accB[i] = ((sl & d) ? b : a) + recv; }
            }
        }
        den0 += __shfl_xor(den0, d);
        den1 += __shfl_xor(den1, d);
    }
    float sumA = accA[0];
    float sumB = accB[0];

    // self-loop (cooperative: lane sl holds channels sl and 16+sl)
    float hr0 = hr[(size_t)node * 32 + sl];
    float hr1 = hr[(size_t)node * 32 + 16 + sl];
    float hl0 = us2f(hlb[(size_t)node * 32 + sl]);
    float hl1 = us2f(hlb[(size_t)node * 32 + 16 + sl]);
    float ea = hl0 + hr0; ea = fmaxf(ea, 0.2f * ea);
    float eb = hl1 + hr1; eb = fmaxf(eb, 0.2f * eb);
    float p0 = att2[sl] * ea;
    float p1 = att2[16 + sl] * eb;
    p0 += __shfl_xor(p0, 1); p0 += __shfl_xor(p0, 2); p0 += __shfl_xor(p0, 4); p0 += __shfl_xor(p0, 8);
    p1 += __shfl_xor(p1, 1); p1 += __shfl_xor(p1, 2); p1 += __shfl_xor(p1, 4); p1 += __shfl_xor(p1, 8);
    float w0 = __expf(p0), w1 = __expf(p1);
    sumA += w0 * hl0; den0 += w0;
    sumB += w1 * hl1; den1 += w1;

    x2[(size_t)node * 32 + sl]      = sumA / (den0 + 1e-16f) + b2[sl];
    x2[(size_t)node * 32 + 16 + sl] = sumB / (den1 + 1e-16f) + b2[16 + sl];
}

// ---------------- Layer 3: TransformerConv(32, 7, heads=1) ----------------

// 128 nodes per 256-thread block; thread = 4-node x 4-col tile.
// Cols jt<4 -> QS (f32); jt>=4 -> KVb (bf16-packed 32B row = {K0..6,0,V0..6,0}).
__global__ __launch_bounds__(256) void k_l3_transform(const float* __restrict__ x2,
                                                      const float4* __restrict__ Wc4, const float4* __restrict__ bc4,
                                                      float* __restrict__ QS, unsigned short* __restrict__ KVb, int N) {
    __shared__ float xs[128 * 36];
    int t = threadIdx.x;
    int node0 = blockIdx.x * 128;
    int nrem = N - node0; if (nrem > 128) nrem = 128;
    const float4* xg = (const float4*)x2;
#pragma unroll
    for (int it = 0; it < 4; ++it) {
        int id = it * 256 + t;
        int row = id >> 3, c4 = id & 7;
        float4 v = make_float4(0.f, 0.f, 0.f, 0.f);
        if (row < nrem) v = xg[(size_t)(node0 + row) * 8 + c4];
        *(float4*)&xs[row * 36 + c4 * 4] = v;
    }
    __syncthreads();
    int nt = t >> 3;
    int jt = t & 7;
    float4 bb = bc4[jt];
    float4 acc[4];
#pragma unroll
    for (int i = 0; i < 4; ++i) acc[i] = bb;
#pragma unroll 2
    for (int k4 = 0; k4 < 8; ++k4) {
        float4 w0 = Wc4[(k4 * 4 + 0) * 8 + jt];
        float4 w1 = Wc4[(k4 * 4 + 1) * 8 + jt];
        float4 w2 = Wc4[(k4 * 4 + 2) * 8 + jt];
        float4 w3 = Wc4[(k4 * 4 + 3) * 8 + jt];
#pragma unroll
        for (int i = 0; i < 4; ++i) {
            float4 xv = *(const float4*)&xs[(nt + i * 32) * 36 + k4 * 4];
            acc[i].x += xv.x * w0.x + xv.y * w1.x + xv.z * w2.x + xv.w * w3.x;
            acc[i].y += xv.x * w0.y + xv.y * w1.y + xv.z * w2.y + xv.w * w3.y;
            acc[i].z += xv.x * w0.z + xv.y * w1.z + xv.z * w2.z + xv.w * w3.z;
            acc[i].w += xv.x * w0.w + xv.y * w1.w + xv.z * w2.w + xv.w * w3.w;
        }
    }
#pragma unroll
    for (int i = 0; i < 4; ++i) {
        int row = nt + i * 32;
        if (row < nrem) {
            size_t node = node0 + row;
            if (jt < 4) {
                *(float4*)(QS + node * 16 + jt * 4) = acc[i];
            } else {
                uint2 p;
                p.x = (unsigned)f2us(acc[i].x) | ((unsigned)f2us(acc[i].y) << 16);
                p.y = (unsigned)f2us(acc[i].z) | ((unsigned)f2us(acc[i].w) << 16);
                *(uint2*)&KVb[node * 16 + (size_t)(jt - 4) * 4] = p;
            }
        }
    }
}

// Edge-parallel: 8 lanes per node, lane = edge slot; bf16 K|V row per edge (2x uint4 = 32B,
// KVb table 3.2MB -> per-XCD L2-resident); dot in f32; 8 values (7 acc + den) butterflied.
__global__ __launch_bounds__(256) void k_l3_agg(const float* __restrict__ QS, const unsigned short* __restrict__ KVb,
                                                const int2* __restrict__ off2, const int* __restrict__ csr,
                                                float* __restrict__ out, int N) {
    int tid = threadIdx.x;
    int node = blockIdx.x * 32 + (tid >> 3);
    if (node >= N) return;
    int sl = tid & 7;
    int lane = tid & 63;
    const float scale = 0.3779644730092272f;  // 1/sqrt(7)
    const float4* q4 = (const float4*)(QS + (size_t)node * 16);
    float4 qa = q4[0], qb = q4[1];
    qa.x *= scale; qa.y *= scale; qa.z *= scale; qa.w *= scale;
    qb.x *= scale; qb.y *= scale; qb.z *= scale; qb.w = 0.f;

    float v[8];
#pragma unroll
    for (int i = 0; i < 8; ++i) v[i] = 0.f;

    int2 ee = off2[node];
    int e0 = ee.x, e1 = ee.y;
    for (int jj = e0 + sl; jj < e1; jj += 8) {
        int s = csr[jj];
        const uint4* kp = (const uint4*)(KVb + (size_t)s * 16);
        uint4 uk = kp[0], uv = kp[1];
        float k0 = __uint_as_float(uk.x << 16),        k1 = __uint_as_float(uk.x & 0xFFFF0000u);
        float k2 = __uint_as_float(uk.y << 16),        k3 = __uint_as_float(uk.y & 0xFFFF0000u);
        float k4 = __uint_as_float(uk.z << 16),        k5 = __uint_as_float(uk.z & 0xFFFF0000u);
        float k6 = __uint_as_float(uk.w << 16);
        float t = qa.x * k0 + qa.y * k1 + qa.z * k2 + qa.w * k3
                + qb.x * k4 + qb.y * k5 + qb.z * k6;
        float w = __expf(t);
        v[0] += w * __uint_as_float(uv.x << 16);
        v[1] += w * __uint_as_float(uv.x & 0xFFFF0000u);
        v[2] += w * __uint_as_float(uv.y << 16);
        v[3] += w * __uint_as_float(uv.y & 0xFFFF0000u);
        v[4] += w * __uint_as_float(uv.z << 16);
        v[5] += w * __uint_as_float(uv.z & 0xFFFF0000u);
        v[6] += w * __uint_as_float(uv.w << 16);
        v[7] += w;
    }
#pragma unroll
    for (int d = 4; d >= 1; d >>= 1) {
#pragma unroll
        for (int i = 0; i < 8; ++i) {
            if (i < d) {
                float a = v[i], b = v[i + d];
                float send = (sl & d) ? a : b;
                float recv = __shfl_xor(send, d);
                v[i] = ((sl & d) ? b : a) + recv;
            }
        }
    }
    float r = v[0];
    float den = __shfl(r, (lane & 56) + 7);
    if (sl < 7) out[(size_t)node * 7 + sl] = r / (den + 1e-16f)
                                             + QS[(size_t)node * 16 + 8 + sl];
}

// ---------------- launcher ----------------

extern "C" void kernel_launch(void* const* d_in, const int* in_sizes, int n_in,
                              void* d_out, int out_size, void* d_ws, size_t ws_size,
                              hipStream_t stream) {
    const int* ei = (const int*)d_in[1];
    float* out = (float*)d_out;

    int N = in_sizes[0] / 3;
    int E = in_sizes[1] / 2;
    int NB = (N + 1023) >> 10;   // assumed <= 256 (N <= 262144)
    int C = (E + NB - 1) / NB + 4096;   // fixed bucket capacity (mean + huge slack for random dst)

    char* ws = (char*)d_ws;
    size_t o = 0;
    auto take = [&](size_t bytes) -> char* {
        char* p = ws + o;
        o = (o + bytes + 255) & ~(size_t)255;
        return p;
    };
    int total_f = 0;
    for (int i = 0; i < 20; ++i) if (i != 1) total_f += in_sizes[i];
    float* canon   = (float*)take((size_t)total_f * 4);
    float* Wcat    = (float*)take(32 * 32 * 4);
    float* bcat    = (float*)take(32 * 4);
    int2*  off2    = (int2*)take((size_t)N * 8);
    int*   bcur    = (int*)take(256 * 4);
    int*   csr     = (int*)take((size_t)NB * C * 4);
    float* bufA    = (float*)take((size_t)N * 64 * 4);  // x4 -> hlb|hr -> QS|KVb
    float* as1     = (float*)take((size_t)N * 4 * 4);
    float* ad1     = (float*)take((size_t)N * 4 * 4);
    float* bufB    = (float*)take((size_t)N * 64 * 4);  // bkt -> x1 -> x2
    (void)ws_size; (void)n_in; (void)out_size;

    CvtArgs ca;
    const float* cp[20];
    {
        int off_ = 0, k = 0;
        for (int i = 0; i < 20; ++i) {
            if (i == 1) { cp[i] = nullptr; continue; }
            ca.p[k] = d_in[i];
            ca.sz[k] = in_sizes[i];
            cp[i] = canon + off_;
            off_ += in_sizes[i];
            ++k;
        }
    }

    int nbconv = (total_f + 255) / 256;
    k_convert<<<nbconv + 1, 256, 0, stream>>>(ca, canon, total_f, nbconv, Wcat, bcat, bcur);

    // bkt aliases bufB (NB*C*4 B ~= 8 MB <= N*256 B); x1 written only after k_bbuild
    int* bkt = (int*)bufB;
    int gb = (E + 4095) / 4096;
    k_bscatter<<<gb, 1024, 0, stream>>>(ei, bcur, bkt, E, NB, C);
    k_bbuild<<<NB, 1024, 0, stream>>>(bkt, bcur, off2, csr, N, C);

    float4* x4 = (float4*)bufA;                                  // N*16B = 1.6 MB, L2-resident
    k_l1_transform<<<(N + 3) / 4, 256, 0, stream>>>(cp[0], cp[2], cp[3], cp[4], x4, as1, ad1, N);
    float* x1 = bufB;
    k_l1_agg<<<(N + 15) / 16, 256, 0, stream>>>(x4, (const float4*)as1, (const float4*)ad1,
                                                off2, csr, cp[2], cp[5], x1, N);

    unsigned short* hlb = (unsigned short*)bufA;                 // N*32 bf16 = 6.4 MB
    float* hr = bufA + (size_t)N * 16;
    k_l2_transform<<<(N + 63) / 64, 256, 0, stream>>>(x1, cp[6], cp[7], cp[8], cp[9], hlb, hr, N);
    float* x2 = bufB;
    k_l2_agg<<<(N + 15) / 16, 256, 0, stream>>>(hlb, hr, cp[10], cp[11], off2, csr, x2, N);

    float* QS = bufA;                                            // N*16 floats
    unsigned short* KVb = (unsigned short*)(bufA + (size_t)N * 16);  // N*16 bf16 = 3.2 MB (L2-resident)
    k_l3_transform<<<(N + 127) / 128, 256, 0, stream>>>(x2, (const float4*)Wcat, (const float4*)bcat,
                                                        QS, KVb, N);
    k_l3_agg<<<(N + 31) / 32, 256, 0, stream>>>(QS, KVb, off2, csr, out, N);
}